// Round 7
// baseline (532.998 us; speedup 1.0000x reference)
//
#include <hip/hip_runtime.h>
#include <math.h>
#include <stdint.h>

#define B_      2
#define S_      2048
#define HID_    2048
#define H_      16
#define D_NOPE_ 128
#define D_ROPE_ 64
#define D_V_    128
#define R_      512
#define D_Q_    192
#define NTOK    (B_ * S_)
#define EPS_    1e-6f

typedef __attribute__((ext_vector_type(8))) short bf16x8;
typedef __attribute__((ext_vector_type(4))) float f32x4;

__device__ __forceinline__ short f2bf(float x) {
    union { float f; unsigned u; } un; un.f = x;
    unsigned r = (un.u + 0x7fffu + ((un.u >> 16) & 1u)) >> 16;
    return (short)r;
}
__device__ __forceinline__ float bf2f(short s) {
    union { unsigned u; float f; } un;
    un.u = ((unsigned)(unsigned short)s) << 16;
    return un.f;
}

__device__ __forceinline__ void async_ld16(const short* gsrc, short* ldst) {
    __builtin_amdgcn_global_load_lds(
        (const __attribute__((address_space(1))) void*)gsrc,
        (__attribute__((address_space(3))) void*)ldst, 16, 0, 0);
}

// ---------------------------------------------------------------------------
// cast f32 -> bf16
// ---------------------------------------------------------------------------
__global__ __launch_bounds__(256) void castk(const float* __restrict__ in, short* __restrict__ out) {
    int i = blockIdx.x * 256 + threadIdx.x;
    float4 v = ((const float4*)in)[i];
    ushort4 o;
    o.x = (unsigned short)f2bf(v.x); o.y = (unsigned short)f2bf(v.y);
    o.z = (unsigned short)f2bf(v.z); o.w = (unsigned short)f2bf(v.w);
    ((ushort4*)out)[i] = o;
}

// ---------------------------------------------------------------------------
// W[K][Nreal] f32 -> WT[Npad][K] bf16 (rows >= Nreal zero-filled).
// ---------------------------------------------------------------------------
__global__ __launch_bounds__(256) void transpose_cast(const float* __restrict__ W,
                                                      short* __restrict__ WT,
                                                      int K, int Nreal) {
    __shared__ float T[32][33];
    const int n0 = blockIdx.x * 32, k0 = blockIdx.y * 32;
    const int t = threadIdx.x;
    const int r = t >> 3, c4 = (t & 7) * 4;
    float4 v = make_float4(0.f, 0.f, 0.f, 0.f);
    if (n0 < Nreal) v = *(const float4*)&W[(size_t)(k0 + r) * Nreal + n0 + c4];
    T[r][c4 + 0] = v.x; T[r][c4 + 1] = v.y; T[r][c4 + 2] = v.z; T[r][c4 + 3] = v.w;
    __syncthreads();
    const int n = t >> 3, k4 = (t & 7) * 4;
    ushort4 o;
    o.x = (unsigned short)f2bf(T[k4 + 0][n]);
    o.y = (unsigned short)f2bf(T[k4 + 1][n]);
    o.z = (unsigned short)f2bf(T[k4 + 2][n]);
    o.w = (unsigned short)f2bf(T[k4 + 3][n]);
    *(ushort4*)&WT[(size_t)(n0 + n) * K + k0 + k4] = o;
}

// ---------------------------------------------------------------------------
// MFMA GEMM: C[M][N] = A[M][K](bf16) @ BT[N][K](bf16). 128x128 tile, 4 waves.
// ---------------------------------------------------------------------------
template <int OUTBF>
__global__ __launch_bounds__(256) void gemm_mfma(const short* __restrict__ A,
                                                 const short* __restrict__ BT,
                                                 void* __restrict__ C,
                                                 int M, int N, int K) {
    __shared__ short As[128 * 32];
    __shared__ short Bs[128 * 32];
    const int tid = threadIdx.x;
    const int lane = tid & 63, w = tid >> 6;
    const int brow = blockIdx.y * 128, bcol = blockIdx.x * 128;

    const int o0 = w * 1024 + lane * 16;
    const int r0 = o0 >> 6, q0p = (o0 >> 4) & 3;
    const int o1 = o0 + 4096;
    const int r1 = o1 >> 6, q1p = (o1 >> 4) & 3;
    const int s0 = r0 * K + 8 * (q0p ^ ((r0 >> 1) & 3));
    const int s1 = r1 * K + 8 * (q1p ^ ((r1 >> 1) & 3));
    const short* Ab = A + (size_t)brow * K;
    const short* Bb = BT + (size_t)bcol * K;
    short* AsU0 = &As[w * 512]; short* AsU1 = &As[w * 512 + 2048];
    short* BsU0 = &Bs[w * 512]; short* BsU1 = &Bs[w * 512 + 2048];

    const int wr = w >> 1, wc = w & 1;
    const int c16 = lane & 15, g = lane >> 4;
    const int qph = (g ^ ((c16 >> 1) & 3)) * 8;

    f32x4 zero = {0.f, 0.f, 0.f, 0.f};
    f32x4 acc[4][4];
#pragma unroll
    for (int i = 0; i < 4; ++i)
#pragma unroll
        for (int j = 0; j < 4; ++j) acc[i][j] = zero;

    for (int k0 = 0; k0 < K; k0 += 32) {
        async_ld16(Ab + s0 + k0, AsU0);
        async_ld16(Ab + s1 + k0, AsU1);
        async_ld16(Bb + s0 + k0, BsU0);
        async_ld16(Bb + s1 + k0, BsU1);
        __syncthreads();
        bf16x8 af[4], bf[4];
#pragma unroll
        for (int i = 0; i < 4; ++i) {
            af[i] = *(const bf16x8*)&As[(wr * 64 + i * 16 + c16) * 32 + qph];
            bf[i] = *(const bf16x8*)&Bs[(wc * 64 + i * 16 + c16) * 32 + qph];
        }
#pragma unroll
        for (int mi = 0; mi < 4; ++mi)
#pragma unroll
            for (int ni = 0; ni < 4; ++ni)
                acc[mi][ni] = __builtin_amdgcn_mfma_f32_16x16x32_bf16(af[mi], bf[ni], acc[mi][ni], 0, 0, 0);
        __syncthreads();
    }

#pragma unroll
    for (int mi = 0; mi < 4; ++mi)
#pragma unroll
        for (int ni = 0; ni < 4; ++ni)
#pragma unroll
            for (int reg = 0; reg < 4; ++reg) {
                int row = brow + wr * 64 + mi * 16 + 4 * g + reg;
                int col = bcol + wc * 64 + ni * 16 + c16;
                if (OUTBF) ((short*)C)[(size_t)row * N + col] = f2bf(acc[mi][ni][reg]);
                else       ((float*)C)[(size_t)row * N + col] = acc[mi][ni][reg];
            }
}

// ---------------------------------------------------------------------------
// In-place RoPE on q_pe region of bf16 q.
// ---------------------------------------------------------------------------
__global__ __launch_bounds__(256) void rope_q_ip(short* __restrict__ qb,
                                                 const float* __restrict__ cosT,
                                                 const float* __restrict__ sinT,
                                                 const int* __restrict__ pid) {
    int gidx = blockIdx.x * 256 + threadIdx.x;
    int i = gidx & 31;
    int h = (gidx >> 5) & (H_ - 1);
    int tok = gidx >> 9;
    int pos = pid[tok];
    float c = cosT[pos * 32 + i];
    float s = sinT[pos * 32 + i];
    short* base = qb + (size_t)tok * (H_ * D_Q_) + h * D_Q_ + D_NOPE_;
    float x1 = bf2f(base[i]);
    float x2 = bf2f(base[i + 32]);
    base[i]      = f2bf(x1 * c - x2 * s);
    base[i + 32] = f2bf(x2 * c + x1 * s);
}

// ---------------------------------------------------------------------------
// LayerNorm(512) + RoPE(k_pe). ckv stride 640. Outputs bf16.
// ---------------------------------------------------------------------------
__global__ __launch_bounds__(256) void ln_rope(const float* __restrict__ ckv,
                                               const float* __restrict__ gam,
                                               const float* __restrict__ bet,
                                               const float* __restrict__ cosT,
                                               const float* __restrict__ sinT,
                                               const int* __restrict__ pid,
                                               short* __restrict__ kvcn,
                                               short* __restrict__ kpe) {
    const int tok = blockIdx.x, tid = threadIdx.x;
    const float* x = ckv + (size_t)tok * 640;
    float v0 = x[tid], v1 = x[tid + 256];
    float s = v0 + v1, sq = v0 * v0 + v1 * v1;
#pragma unroll
    for (int m = 1; m < 64; m <<= 1) { s += __shfl_xor(s, m); sq += __shfl_xor(sq, m); }
    __shared__ float ws[8];
    int wid = tid >> 6, lane = tid & 63;
    if (lane == 0) { ws[wid] = s; ws[4 + wid] = sq; }
    __syncthreads();
    s = ws[0] + ws[1] + ws[2] + ws[3];
    sq = ws[4] + ws[5] + ws[6] + ws[7];
    float mean = s * (1.f / 512.f);
    float var = sq * (1.f / 512.f) - mean * mean;
    float rstd = rsqrtf(var + EPS_);
    kvcn[(size_t)tok * 512 + tid]       = f2bf((v0 - mean) * rstd * gam[tid] + bet[tid]);
    kvcn[(size_t)tok * 512 + tid + 256] = f2bf((v1 - mean) * rstd * gam[tid + 256] + bet[tid + 256]);
    if (tid < 32) {
        int pos = pid[tok];
        float c = cosT[pos * 32 + tid], sn = sinT[pos * 32 + tid];
        float x1 = x[512 + tid], x2 = x[512 + 32 + tid];
        kpe[(size_t)tok * 64 + tid]      = f2bf(x1 * c - x2 * sn);
        kpe[(size_t)tok * 64 + 32 + tid] = f2bf(x2 * c + x1 * sn);
    }
}

// ---------------------------------------------------------------------------
// V transpose: kvb[token][h][128..255] -> Vt[b][h][d][s].
// ---------------------------------------------------------------------------
__global__ __launch_bounds__(256) void transpose_v(const short* __restrict__ kvb,
                                                   short* __restrict__ Vt) {
    __shared__ short T[64][72];
    const int s0 = blockIdx.x * 64, d0 = blockIdx.y * 64, bh = blockIdx.z;
    const int b = bh >> 4, h = bh & 15;
    const int t = threadIdx.x;
    const int r = t >> 3, c8 = (t & 7) * 8;
#pragma unroll
    for (int i = 0; i < 2; ++i) {
        int rr = r + 32 * i;
        bf16x8 v = *(const bf16x8*)&kvb[((size_t)(b * 2048 + s0 + rr) * 16 + h) * 256 + 128 + d0 + c8];
        *(bf16x8*)&T[rr][c8] = v;
    }
    __syncthreads();
#pragma unroll
    for (int i = 0; i < 2; ++i) {
        int d = r + 32 * i;
        bf16x8 o;
#pragma unroll
        for (int j = 0; j < 8; ++j) o[j] = T[c8 + j][d];
        *(bf16x8*)&Vt[((size_t)(b * 16 + h) * 128 + d0 + d) * 2048 + s0 + c8] = o;
    }
}

// ---------------------------------------------------------------------------
// MFMA flash attention. K LDS-staged (dbuf, swizzled); V fragments loaded
// to REGISTERS at loop top (latency hidden under QK+softmax; L1 shares the
// tile across the block's 4 waves). LDS 42K -> 3 blocks/CU (12 waves).
// Softmax: raw-score max, scale folded into exp2-FMA, row-sum reduce
// deferred to epilogue. Grid: 1024 blocks, XCD-pinned (b,h).
// ---------------------------------------------------------------------------
__global__ __launch_bounds__(256, 3) void flash_mfma(const short* __restrict__ qb,
                                                     const short* __restrict__ kvb,
                                                     const short* __restrict__ kpe,
                                                     const short* __restrict__ Vt,
                                                     short* __restrict__ attno) {
    __shared__ short Ks[2][64 * 128];
    __shared__ short P[4][16][72];

    const int flat = blockIdx.x;
    const int xcd = flat & 7, idx = flat >> 3;
    const int bh = xcd + 8 * (idx >> 5);
    const int qt = 31 - (idx & 31);
    const int b = bh >> 4, h = bh & 15;
    const int q0 = qt * 64;

    const int tid = threadIdx.x, lane = tid & 63, w = tid >> 6;
    const int c16 = lane & 15, g = lane >> 4, g8 = g * 8;
    const float SC2 = 0.10412063f;   // 1/sqrt(192) * log2(e)

    const int qrow = q0 + w * 16;
    const size_t qbase = ((size_t)(b * 2048 + qrow + c16) * 16 + h) * 192 + g8;
    bf16x8 qf[6];
#pragma unroll
    for (int ks = 0; ks < 6; ++ks) qf[ks] = *(const bf16x8*)(qb + qbase + 32 * ks);

    f32x4 zero = {0.f, 0.f, 0.f, 0.f};
    f32x4 acc[8];
#pragma unroll
    for (int i = 0; i < 8; ++i) acc[i] = zero;
    float mreg[4] = {-INFINITY, -INFINITY, -INFINITY, -INFINITY};
    float lreg[4] = {0.f, 0.f, 0.f, 0.f};

    // ---- staging bases (single running pointer; rnd strides are uniform) ----
    const int o = w * 1024 + lane * 16;
    const int rK = o >> 8, ccK = ((o >> 4) & 15) ^ (rK & 7);
    const short* kBase = kvb + ((size_t)((b * 2048 + rK) * 16 + h)) * 256 + ccK * 8;
    const short* vRun  = Vt + ((size_t)((b * 16 + h) * 128 + c16)) * 2048 + g8;
    const short* peRun = kpe + (size_t)(b * 2048 + c16) * 64 + g8;

#define STAGE_K(BUF)                                                              \
    {                                                                             \
        _Pragma("unroll")                                                         \
        for (int rnd = 0; rnd < 4; ++rnd)                                         \
            async_ld16(kBase + (size_t)rnd * 16 * 4096,                           \
                       &Ks[BUF][(rnd * 4096 + w * 1024) >> 1]);                   \
        kBase += (size_t)64 * 4096;                                               \
    }

    const int nt = qt + 1;
    STAGE_K(0);
    __syncthreads();
    int cur = 0;

    for (int kt = 0; kt < nt; ++kt) {
        const int k0 = kt * 64;

        // V fragments -> registers, issued ~1200 cyc before PV consumes them
        bf16x8 vf[2][8];
#pragma unroll
        for (int ks = 0; ks < 2; ++ks)
#pragma unroll
            for (int nb = 0; nb < 8; ++nb)
                vf[ks][nb] = *(const bf16x8*)(vRun + (size_t)nb * 16 * 2048 + ks * 32);
        vRun += 64;

        if (kt + 1 < nt) STAGE_K(cur ^ 1);

        f32x4 sc[4];
#pragma unroll
        for (int i = 0; i < 4; ++i) sc[i] = zero;

        // QK^T nope from LDS (swizzled reads)
        __builtin_amdgcn_s_setprio(1);
#pragma unroll
        for (int ks = 0; ks < 4; ++ks)
#pragma unroll
            for (int nb = 0; nb < 4; ++nb) {
                int row = nb * 16 + c16;
                bf16x8 kf = *(const bf16x8*)&Ks[cur][row * 128 + (((g + 4 * ks) ^ (row & 7)) << 3)];
                sc[nb] = __builtin_amdgcn_mfma_f32_16x16x32_bf16(qf[ks], kf, sc[nb], 0, 0, 0);
            }
        // pe part from global (kpe tiny, L2-hot)
#pragma unroll
        for (int ks = 0; ks < 2; ++ks)
#pragma unroll
            for (int nb = 0; nb < 4; ++nb) {
                bf16x8 kf = *(const bf16x8*)(peRun + (size_t)nb * 16 * 64 + ks * 32);
                sc[nb] = __builtin_amdgcn_mfma_f32_16x16x32_bf16(qf[4 + ks], kf, sc[nb], 0, 0, 0);
            }
        __builtin_amdgcn_s_setprio(0);
        peRun += 64 * 64;

        // causal mask on RAW scores (last tile only)
        if (kt == nt - 1) {
#pragma unroll
            for (int nb = 0; nb < 4; ++nb)
#pragma unroll
                for (int reg = 0; reg < 4; ++reg) {
                    int col = k0 + nb * 16 + c16;
                    int row = qrow + 4 * g + reg;
                    if (col > row) sc[nb][reg] = -INFINITY;
                }
        }

        // row max on raw scores (4 dependent shuffle rounds)
        float rmax[4];
#pragma unroll
        for (int reg = 0; reg < 4; ++reg)
            rmax[reg] = fmaxf(fmaxf(sc[0][reg], sc[1][reg]), fmaxf(sc[2][reg], sc[3][reg]));
#pragma unroll
        for (int m = 1; m < 16; m <<= 1)
#pragma unroll
            for (int reg = 0; reg < 4; ++reg)
                rmax[reg] = fmaxf(rmax[reg], __shfl_xor(rmax[reg], m));

        // defer-rescale (T13): only pay the O(32) rescale when max grew > 8
        float grow = rmax[0] * SC2 - mreg[0];
#pragma unroll
        for (int reg = 1; reg < 4; ++reg) grow = fmaxf(grow, rmax[reg] * SC2 - mreg[reg]);
        if (__any(grow > 8.f)) {
#pragma unroll
            for (int reg = 0; reg < 4; ++reg) {
                float mnew = fmaxf(mreg[reg], rmax[reg] * SC2);
                float alpha = exp2f(mreg[reg] - mnew);
                mreg[reg] = mnew;
                lreg[reg] *= alpha;
#pragma unroll
                for (int nb = 0; nb < 8; ++nb) acc[nb][reg] *= alpha;
            }
        }

        // p = 2^(s*SC2 - m); per-lane partial row sum (cross-lane reduce deferred)
#pragma unroll
        for (int reg = 0; reg < 4; ++reg) {
            float p0 = exp2f(fmaf(sc[0][reg], SC2, -mreg[reg]));
            float p1 = exp2f(fmaf(sc[1][reg], SC2, -mreg[reg]));
            float p2 = exp2f(fmaf(sc[2][reg], SC2, -mreg[reg]));
            float p3 = exp2f(fmaf(sc[3][reg], SC2, -mreg[reg]));
            sc[0][reg] = p0; sc[1][reg] = p1; sc[2][reg] = p2; sc[3][reg] = p3;
            lreg[reg] += (p0 + p1) + (p2 + p3);
        }

        // P -> LDS (C/D layout -> A layout)
#pragma unroll
        for (int nb = 0; nb < 4; ++nb)
#pragma unroll
            for (int reg = 0; reg < 4; ++reg)
                P[w][4 * g + reg][nb * 16 + c16] = f2bf(sc[nb][reg]);

        // PV from V registers
        __builtin_amdgcn_s_setprio(1);
#pragma unroll
        for (int ks = 0; ks < 2; ++ks) {
            bf16x8 pf = *(const bf16x8*)&P[w][c16][ks * 32 + g8];
#pragma unroll
            for (int nb = 0; nb < 8; ++nb)
                acc[nb] = __builtin_amdgcn_mfma_f32_16x16x32_bf16(pf, vf[ks][nb], acc[nb], 0, 0, 0);
        }
        __builtin_amdgcn_s_setprio(0);

        __syncthreads();   // drains K stage + all waves done with Ks[cur]/P
        cur ^= 1;
    }
#undef STAGE_K

    // epilogue: finish the deferred row-sum reduce (4 rounds), normalize, store
#pragma unroll
    for (int m = 1; m < 16; m <<= 1)
#pragma unroll
        for (int reg = 0; reg < 4; ++reg)
            lreg[reg] += __shfl_xor(lreg[reg], m);
    float inv[4];
#pragma unroll
    for (int reg = 0; reg < 4; ++reg) inv[reg] = 1.f / lreg[reg];
#pragma unroll
    for (int nb = 0; nb < 8; ++nb)
#pragma unroll
        for (int reg = 0; reg < 4; ++reg)
            attno[((size_t)(b * 2048 + qrow + 4 * g + reg) * 16 + h) * 128 + nb * 16 + c16] =
                f2bf(acc[nb][reg] * inv[reg]);
}

// ---------------------------------------------------------------------------
extern "C" void kernel_launch(void* const* d_in, const int* in_sizes, int n_in,
                              void* d_out, int out_size, void* d_ws, size_t ws_size,
                              hipStream_t stream) {
    const float* hidden = (const float*)d_in[0];
    const float* cosT   = (const float*)d_in[1];
    const float* sinT   = (const float*)d_in[2];
    const int*   pid    = (const int*)d_in[3];
    const float* Wq     = (const float*)d_in[4];
    const float* Wkv_a  = (const float*)d_in[5];
    const float* ln_g   = (const float*)d_in[6];
    const float* ln_b   = (const float*)d_in[7];
    const float* Wkv_b  = (const float*)d_in[8];
    const float* Wo     = (const float*)d_in[9];
    float* out = (float*)d_out;

    char* p = (char*)d_ws;
    short* hid_bf = (short*)p;               p += (size_t)NTOK * 2048 * 2;
    short* WqT    = (short*)p;               p += (size_t)3072 * 2048 * 2;
    short* WkaT   = (short*)p;               p += (size_t)640 * 2048 * 2;
    short* WkbT   = (short*)p;               p += (size_t)4096 * 512 * 2;
    short* WoT    = (short*)p;               p += (size_t)2048 * 2048 * 2;
    char*  big    = p;                       p += (size_t)NTOK * 3072 * 4;
    short* qbuf   = (short*)p;               p += (size_t)NTOK * 3072 * 2;
    short* kvcn   = (short*)p;               p += (size_t)NTOK * 512 * 2;
    short* kpe    = (short*)p;               p += (size_t)NTOK * 64 * 2;
    short* kvb    = (short*)p;               p += (size_t)NTOK * 4096 * 2;

    float* ckv   = (float*)big;
    short* Vt    = (short*)(big + (size_t)NTOK * 640 * 4);
    short* attno = (short*)(big + (size_t)NTOK * 640 * 4 + (size_t)2 * 16 * 128 * 2048 * 2);

    castk<<<8192, 256, 0, stream>>>(hidden, hid_bf);
    transpose_cast<<<dim3(96, 64), 256, 0, stream>>>(Wq, WqT, 2048, 3072);
    transpose_cast<<<dim3(20, 64), 256, 0, stream>>>(Wkv_a, WkaT, 2048, 576);
    transpose_cast<<<dim3(128, 16), 256, 0, stream>>>(Wkv_b, WkbT, 512, 4096);
    transpose_cast<<<dim3(64, 64), 256, 0, stream>>>(Wo, WoT, 2048, 2048);

    gemm_mfma<1><<<dim3(24, 32), 256, 0, stream>>>(hid_bf, WqT, qbuf, 4096, 3072, 2048);
    rope_q_ip<<<(NTOK * H_ * 32) / 256, 256, 0, stream>>>(qbuf, cosT, sinT, pid);
    gemm_mfma<0><<<dim3(5, 32), 256, 0, stream>>>(hid_bf, WkaT, ckv, 4096, 640, 2048);
    ln_rope<<<NTOK, 256, 0, stream>>>(ckv, ln_g, ln_b, cosT, sinT, pid, kvcn, kpe);
    gemm_mfma<1><<<dim3(32, 32), 256, 0, stream>>>(kvcn, WkbT, kvb, 4096, 4096, 512);
    transpose_v<<<dim3(32, 2, 32), 256, 0, stream>>>(kvb, Vt);
    flash_mfma<<<1024, 256, 0, stream>>>(qbuf, kvb, kpe, Vt, attno);
    gemm_mfma<0><<<dim3(16, 32), 256, 0, stream>>>(attno, WoT, out, 4096, 2048, 2048);
}

// Round 8
// 356.070 us; speedup vs baseline: 1.4969x; 1.4969x over previous
//
#include <hip/hip_runtime.h>
#include <math.h>
#include <stdint.h>

#define B_      2
#define S_      2048
#define HID_    2048
#define H_      16
#define D_NOPE_ 128
#define D_ROPE_ 64
#define D_V_    128
#define R_      512
#define D_Q_    192
#define NTOK    (B_ * S_)
#define EPS_    1e-6f

typedef __attribute__((ext_vector_type(8))) short bf16x8;
typedef __attribute__((ext_vector_type(4))) float f32x4;

__device__ __forceinline__ short f2bf(float x) {
    union { float f; unsigned u; } un; un.f = x;
    unsigned r = (un.u + 0x7fffu + ((un.u >> 16) & 1u)) >> 16;
    return (short)r;
}
__device__ __forceinline__ float bf2f(short s) {
    union { unsigned u; float f; } un;
    un.u = ((unsigned)(unsigned short)s) << 16;
    return un.f;
}

__device__ __forceinline__ void async_ld16(const short* gsrc, short* ldst) {
    __builtin_amdgcn_global_load_lds(
        (const __attribute__((address_space(1))) void*)gsrc,
        (__attribute__((address_space(3))) void*)ldst, 16, 0, 0);
}

// ---------------------------------------------------------------------------
// cast f32 -> bf16
// ---------------------------------------------------------------------------
__global__ __launch_bounds__(256) void castk(const float* __restrict__ in, short* __restrict__ out) {
    int i = blockIdx.x * 256 + threadIdx.x;
    float4 v = ((const float4*)in)[i];
    ushort4 o;
    o.x = (unsigned short)f2bf(v.x); o.y = (unsigned short)f2bf(v.y);
    o.z = (unsigned short)f2bf(v.z); o.w = (unsigned short)f2bf(v.w);
    ((ushort4*)out)[i] = o;
}

// ---------------------------------------------------------------------------
// W[K][Nreal] f32 -> WT[Npad][K] bf16 (rows >= Nreal zero-filled).
// ---------------------------------------------------------------------------
__global__ __launch_bounds__(256) void transpose_cast(const float* __restrict__ W,
                                                      short* __restrict__ WT,
                                                      int K, int Nreal) {
    __shared__ float T[32][33];
    const int n0 = blockIdx.x * 32, k0 = blockIdx.y * 32;
    const int t = threadIdx.x;
    const int r = t >> 3, c4 = (t & 7) * 4;
    float4 v = make_float4(0.f, 0.f, 0.f, 0.f);
    if (n0 < Nreal) v = *(const float4*)&W[(size_t)(k0 + r) * Nreal + n0 + c4];
    T[r][c4 + 0] = v.x; T[r][c4 + 1] = v.y; T[r][c4 + 2] = v.z; T[r][c4 + 3] = v.w;
    __syncthreads();
    const int n = t >> 3, k4 = (t & 7) * 4;
    ushort4 o;
    o.x = (unsigned short)f2bf(T[k4 + 0][n]);
    o.y = (unsigned short)f2bf(T[k4 + 1][n]);
    o.z = (unsigned short)f2bf(T[k4 + 2][n]);
    o.w = (unsigned short)f2bf(T[k4 + 3][n]);
    *(ushort4*)&WT[(size_t)(n0 + n) * K + k0 + k4] = o;
}

// ---------------------------------------------------------------------------
// MFMA GEMM: C[M][N] = A[M][K](bf16) @ BT[N][K](bf16). 128x128 tile, 4 waves.
// ---------------------------------------------------------------------------
template <int OUTBF>
__global__ __launch_bounds__(256) void gemm_mfma(const short* __restrict__ A,
                                                 const short* __restrict__ BT,
                                                 void* __restrict__ C,
                                                 int M, int N, int K) {
    __shared__ short As[128 * 32];
    __shared__ short Bs[128 * 32];
    const int tid = threadIdx.x;
    const int lane = tid & 63, w = tid >> 6;
    const int brow = blockIdx.y * 128, bcol = blockIdx.x * 128;

    const int o0 = w * 1024 + lane * 16;
    const int r0 = o0 >> 6, q0p = (o0 >> 4) & 3;
    const int o1 = o0 + 4096;
    const int r1 = o1 >> 6, q1p = (o1 >> 4) & 3;
    const int s0 = r0 * K + 8 * (q0p ^ ((r0 >> 1) & 3));
    const int s1 = r1 * K + 8 * (q1p ^ ((r1 >> 1) & 3));
    const short* Ab = A + (size_t)brow * K;
    const short* Bb = BT + (size_t)bcol * K;
    short* AsU0 = &As[w * 512]; short* AsU1 = &As[w * 512 + 2048];
    short* BsU0 = &Bs[w * 512]; short* BsU1 = &Bs[w * 512 + 2048];

    const int wr = w >> 1, wc = w & 1;
    const int c16 = lane & 15, g = lane >> 4;
    const int qph = (g ^ ((c16 >> 1) & 3)) * 8;

    f32x4 zero = {0.f, 0.f, 0.f, 0.f};
    f32x4 acc[4][4];
#pragma unroll
    for (int i = 0; i < 4; ++i)
#pragma unroll
        for (int j = 0; j < 4; ++j) acc[i][j] = zero;

    for (int k0 = 0; k0 < K; k0 += 32) {
        async_ld16(Ab + s0 + k0, AsU0);
        async_ld16(Ab + s1 + k0, AsU1);
        async_ld16(Bb + s0 + k0, BsU0);
        async_ld16(Bb + s1 + k0, BsU1);
        __syncthreads();
        bf16x8 af[4], bf[4];
#pragma unroll
        for (int i = 0; i < 4; ++i) {
            af[i] = *(const bf16x8*)&As[(wr * 64 + i * 16 + c16) * 32 + qph];
            bf[i] = *(const bf16x8*)&Bs[(wc * 64 + i * 16 + c16) * 32 + qph];
        }
#pragma unroll
        for (int mi = 0; mi < 4; ++mi)
#pragma unroll
            for (int ni = 0; ni < 4; ++ni)
                acc[mi][ni] = __builtin_amdgcn_mfma_f32_16x16x32_bf16(af[mi], bf[ni], acc[mi][ni], 0, 0, 0);
        __syncthreads();
    }

#pragma unroll
    for (int mi = 0; mi < 4; ++mi)
#pragma unroll
        for (int ni = 0; ni < 4; ++ni)
#pragma unroll
            for (int reg = 0; reg < 4; ++reg) {
                int row = brow + wr * 64 + mi * 16 + 4 * g + reg;
                int col = bcol + wc * 64 + ni * 16 + c16;
                if (OUTBF) ((short*)C)[(size_t)row * N + col] = f2bf(acc[mi][ni][reg]);
                else       ((float*)C)[(size_t)row * N + col] = acc[mi][ni][reg];
            }
}

// ---------------------------------------------------------------------------
// In-place RoPE on q_pe region of bf16 q.
// ---------------------------------------------------------------------------
__global__ __launch_bounds__(256) void rope_q_ip(short* __restrict__ qb,
                                                 const float* __restrict__ cosT,
                                                 const float* __restrict__ sinT,
                                                 const int* __restrict__ pid) {
    int gidx = blockIdx.x * 256 + threadIdx.x;
    int i = gidx & 31;
    int h = (gidx >> 5) & (H_ - 1);
    int tok = gidx >> 9;
    int pos = pid[tok];
    float c = cosT[pos * 32 + i];
    float s = sinT[pos * 32 + i];
    short* base = qb + (size_t)tok * (H_ * D_Q_) + h * D_Q_ + D_NOPE_;
    float x1 = bf2f(base[i]);
    float x2 = bf2f(base[i + 32]);
    base[i]      = f2bf(x1 * c - x2 * s);
    base[i + 32] = f2bf(x2 * c + x1 * s);
}

// ---------------------------------------------------------------------------
// LayerNorm(512) + RoPE(k_pe). ckv stride 640. Outputs bf16.
// ---------------------------------------------------------------------------
__global__ __launch_bounds__(256) void ln_rope(const float* __restrict__ ckv,
                                               const float* __restrict__ gam,
                                               const float* __restrict__ bet,
                                               const float* __restrict__ cosT,
                                               const float* __restrict__ sinT,
                                               const int* __restrict__ pid,
                                               short* __restrict__ kvcn,
                                               short* __restrict__ kpe) {
    const int tok = blockIdx.x, tid = threadIdx.x;
    const float* x = ckv + (size_t)tok * 640;
    float v0 = x[tid], v1 = x[tid + 256];
    float s = v0 + v1, sq = v0 * v0 + v1 * v1;
#pragma unroll
    for (int m = 1; m < 64; m <<= 1) { s += __shfl_xor(s, m); sq += __shfl_xor(sq, m); }
    __shared__ float ws[8];
    int wid = tid >> 6, lane = tid & 63;
    if (lane == 0) { ws[wid] = s; ws[4 + wid] = sq; }
    __syncthreads();
    s = ws[0] + ws[1] + ws[2] + ws[3];
    sq = ws[4] + ws[5] + ws[6] + ws[7];
    float mean = s * (1.f / 512.f);
    float var = sq * (1.f / 512.f) - mean * mean;
    float rstd = rsqrtf(var + EPS_);
    kvcn[(size_t)tok * 512 + tid]       = f2bf((v0 - mean) * rstd * gam[tid] + bet[tid]);
    kvcn[(size_t)tok * 512 + tid + 256] = f2bf((v1 - mean) * rstd * gam[tid + 256] + bet[tid + 256]);
    if (tid < 32) {
        int pos = pid[tok];
        float c = cosT[pos * 32 + tid], sn = sinT[pos * 32 + tid];
        float x1 = x[512 + tid], x2 = x[512 + 32 + tid];
        kpe[(size_t)tok * 64 + tid]      = f2bf(x1 * c - x2 * sn);
        kpe[(size_t)tok * 64 + 32 + tid] = f2bf(x2 * c + x1 * sn);
    }
}

// ---------------------------------------------------------------------------
// V transpose: kvb[token][h][128..255] -> Vt[b][h][d][s].
// ---------------------------------------------------------------------------
__global__ __launch_bounds__(256) void transpose_v(const short* __restrict__ kvb,
                                                   short* __restrict__ Vt) {
    __shared__ short T[64][72];
    const int s0 = blockIdx.x * 64, d0 = blockIdx.y * 64, bh = blockIdx.z;
    const int b = bh >> 4, h = bh & 15;
    const int t = threadIdx.x;
    const int r = t >> 3, c8 = (t & 7) * 8;
#pragma unroll
    for (int i = 0; i < 2; ++i) {
        int rr = r + 32 * i;
        bf16x8 v = *(const bf16x8*)&kvb[((size_t)(b * 2048 + s0 + rr) * 16 + h) * 256 + 128 + d0 + c8];
        *(bf16x8*)&T[rr][c8] = v;
    }
    __syncthreads();
#pragma unroll
    for (int i = 0; i < 2; ++i) {
        int d = r + 32 * i;
        bf16x8 o;
#pragma unroll
        for (int j = 0; j < 8; ++j) o[j] = T[c8 + j][d];
        *(bf16x8*)&Vt[((size_t)(b * 16 + h) * 128 + d0 + d) * 2048 + s0 + c8] = o;
    }
}

// ---------------------------------------------------------------------------
// MFMA flash attention. K+V LDS-staged (dbuf, swizzled source, rule 21).
// COMPLEMENTARY PAIRING: each block processes q-tiles {pair, 31-pair}
// sequentially -> uniform 33 K-tile iterations per block, 512 blocks =
// exactly 2 resident per CU, zero tail. XCD-pinned (b,h).
// Softmax: raw max, exp2-FMA, defer-rescale (T13), row-sum deferred.
// ---------------------------------------------------------------------------
__global__ __launch_bounds__(256) void flash_mfma(const short* __restrict__ qb,
                                                  const short* __restrict__ kvb,
                                                  const short* __restrict__ kpe,
                                                  const short* __restrict__ Vt,
                                                  short* __restrict__ attno) {
    __shared__ short Ks[2][64 * 128];
    __shared__ short Vs[2][128 * 64];
    __shared__ short P[4][16][72];

    const int flat = blockIdx.x;              // 0..511
    const int xcd = flat & 7, idx = flat >> 3;
    const int bh = xcd + 8 * (idx >> 4);      // all 16 pairs of a bh on one XCD
    const int pair = idx & 15;
    const int b = bh >> 4, h = bh & 15;

    const int tid = threadIdx.x, lane = tid & 63, w = tid >> 6;
    const int c16 = lane & 15, g = lane >> 4, g8 = g * 8;
    const float SC2 = 0.10412063f;   // 1/sqrt(192) * log2(e)

#define STAGE_TILES(BUF, K0)                                                          \
    {                                                                                 \
        _Pragma("unroll")                                                             \
        for (int rnd = 0; rnd < 4; ++rnd) {                                           \
            int o = rnd * 4096 + w * 1024 + lane * 16;                                \
            int r = o >> 8, qs = (o >> 4) & 15;                                       \
            int cc = qs ^ (r & 7);                                                    \
            const short* src = kvb + ((size_t)((b * 2048 + (K0) + r) * 16 + h)) * 256 \
                               + cc * 8;                                              \
            async_ld16(src, &Ks[BUF][(rnd * 4096 + w * 1024) >> 1]);                  \
        }                                                                             \
        _Pragma("unroll")                                                             \
        for (int rnd = 0; rnd < 4; ++rnd) {                                           \
            int o = rnd * 4096 + w * 1024 + lane * 16;                                \
            int r = o >> 7, qs = (o >> 4) & 7;                                        \
            int cc = qs ^ (r & 7);                                                    \
            const short* src = Vt + ((size_t)((b * 16 + h) * 128 + r)) * 2048 + (K0)  \
                               + cc * 8;                                              \
            async_ld16(src, &Vs[BUF][(rnd * 4096 + w * 1024) >> 1]);                  \
        }                                                                             \
    }

    f32x4 zero = {0.f, 0.f, 0.f, 0.f};

    for (int half = 0; half < 2; ++half) {
        const int qt = half ? (31 - pair) : pair;
        const int q0 = qt * 64;
        const int qrow = q0 + w * 16;

        const size_t qbase = ((size_t)(b * 2048 + qrow + c16) * 16 + h) * 192 + g8;
        bf16x8 qf[6];
#pragma unroll
        for (int ks = 0; ks < 6; ++ks) qf[ks] = *(const bf16x8*)(qb + qbase + 32 * ks);

        f32x4 acc[8];
#pragma unroll
        for (int i = 0; i < 8; ++i) acc[i] = zero;
        float mreg[4] = {-INFINITY, -INFINITY, -INFINITY, -INFINITY};
        float lreg[4] = {0.f, 0.f, 0.f, 0.f};

        const int nt = qt + 1;
        STAGE_TILES(0, 0);
        __syncthreads();
        int cur = 0;

        for (int kt = 0; kt < nt; ++kt) {
            const int k0 = kt * 64;
            if (kt + 1 < nt) STAGE_TILES(cur ^ 1, k0 + 64);

            f32x4 sc[4];
#pragma unroll
            for (int i = 0; i < 4; ++i) sc[i] = zero;

            // QK^T nope from LDS (swizzled reads)
            __builtin_amdgcn_s_setprio(1);
#pragma unroll
            for (int ks = 0; ks < 4; ++ks)
#pragma unroll
                for (int nb = 0; nb < 4; ++nb) {
                    int row = nb * 16 + c16;
                    bf16x8 kf = *(const bf16x8*)&Ks[cur][row * 128 + (((g + 4 * ks) ^ (row & 7)) << 3)];
                    sc[nb] = __builtin_amdgcn_mfma_f32_16x16x32_bf16(qf[ks], kf, sc[nb], 0, 0, 0);
                }
            // pe part from global (kpe tiny, shared across heads -> L2-hot)
            const size_t pb = (size_t)(b * 2048 + k0 + c16) * 64 + g8;
#pragma unroll
            for (int ks = 0; ks < 2; ++ks)
#pragma unroll
                for (int nb = 0; nb < 4; ++nb) {
                    bf16x8 kf = *(const bf16x8*)(kpe + pb + (size_t)nb * 16 * 64 + ks * 32);
                    sc[nb] = __builtin_amdgcn_mfma_f32_16x16x32_bf16(qf[4 + ks], kf, sc[nb], 0, 0, 0);
                }
            __builtin_amdgcn_s_setprio(0);

            // causal mask on RAW scores (last tile of this q-tile only)
            if (kt == nt - 1) {
#pragma unroll
                for (int nb = 0; nb < 4; ++nb)
#pragma unroll
                    for (int reg = 0; reg < 4; ++reg) {
                        int col = k0 + nb * 16 + c16;
                        int row = qrow + 4 * g + reg;
                        if (col > row) sc[nb][reg] = -INFINITY;
                    }
            }

            // row max (raw), 4 dependent shuffle rounds
            float rmax[4];
#pragma unroll
            for (int reg = 0; reg < 4; ++reg)
                rmax[reg] = fmaxf(fmaxf(sc[0][reg], sc[1][reg]), fmaxf(sc[2][reg], sc[3][reg]));
#pragma unroll
            for (int m = 1; m < 16; m <<= 1)
#pragma unroll
                for (int reg = 0; reg < 4; ++reg)
                    rmax[reg] = fmaxf(rmax[reg], __shfl_xor(rmax[reg], m));

            // defer-rescale (T13, THR=8 in log2 domain)
            float grow = rmax[0] * SC2 - mreg[0];
#pragma unroll
            for (int reg = 1; reg < 4; ++reg) grow = fmaxf(grow, rmax[reg] * SC2 - mreg[reg]);
            if (__any(grow > 8.f)) {
#pragma unroll
                for (int reg = 0; reg < 4; ++reg) {
                    float mnew = fmaxf(mreg[reg], rmax[reg] * SC2);
                    float alpha = exp2f(mreg[reg] - mnew);
                    mreg[reg] = mnew;
                    lreg[reg] *= alpha;
#pragma unroll
                    for (int nb = 0; nb < 8; ++nb) acc[nb][reg] *= alpha;
                }
            }

            // p = 2^(s*SC2 - m); per-lane partial row sum (reduce deferred)
#pragma unroll
            for (int reg = 0; reg < 4; ++reg) {
                float p0 = exp2f(fmaf(sc[0][reg], SC2, -mreg[reg]));
                float p1 = exp2f(fmaf(sc[1][reg], SC2, -mreg[reg]));
                float p2 = exp2f(fmaf(sc[2][reg], SC2, -mreg[reg]));
                float p3 = exp2f(fmaf(sc[3][reg], SC2, -mreg[reg]));
                sc[0][reg] = p0; sc[1][reg] = p1; sc[2][reg] = p2; sc[3][reg] = p3;
                lreg[reg] += (p0 + p1) + (p2 + p3);
            }

            // P -> LDS (C/D layout -> A layout)
#pragma unroll
            for (int nb = 0; nb < 4; ++nb)
#pragma unroll
                for (int reg = 0; reg < 4; ++reg)
                    P[w][4 * g + reg][nb * 16 + c16] = f2bf(sc[nb][reg]);

            // PV from LDS V (swizzled reads)
            __builtin_amdgcn_s_setprio(1);
#pragma unroll
            for (int ks = 0; ks < 2; ++ks) {
                bf16x8 pf = *(const bf16x8*)&P[w][c16][ks * 32 + g8];
#pragma unroll
                for (int nb = 0; nb < 8; ++nb) {
                    int row = nb * 16 + c16;
                    bf16x8 vf = *(const bf16x8*)&Vs[cur][row * 64 + (((g + 4 * ks) ^ (row & 7)) << 3)];
                    acc[nb] = __builtin_amdgcn_mfma_f32_16x16x32_bf16(pf, vf, acc[nb], 0, 0, 0);
                }
            }
            __builtin_amdgcn_s_setprio(0);

            __syncthreads();   // drains stage vmcnt + all waves done with buffers
            cur ^= 1;
        }

        // epilogue: finish deferred row-sum reduce, normalize, store
#pragma unroll
        for (int m = 1; m < 16; m <<= 1)
#pragma unroll
            for (int reg = 0; reg < 4; ++reg)
                lreg[reg] += __shfl_xor(lreg[reg], m);
        float inv[4];
#pragma unroll
        for (int reg = 0; reg < 4; ++reg) inv[reg] = 1.f / lreg[reg];
#pragma unroll
        for (int nb = 0; nb < 8; ++nb)
#pragma unroll
            for (int reg = 0; reg < 4; ++reg)
                attno[((size_t)(b * 2048 + qrow + 4 * g + reg) * 16 + h) * 128 + nb * 16 + c16] =
                    f2bf(acc[nb][reg] * inv[reg]);
    }
#undef STAGE_TILES
}

// ---------------------------------------------------------------------------
extern "C" void kernel_launch(void* const* d_in, const int* in_sizes, int n_in,
                              void* d_out, int out_size, void* d_ws, size_t ws_size,
                              hipStream_t stream) {
    const float* hidden = (const float*)d_in[0];
    const float* cosT   = (const float*)d_in[1];
    const float* sinT   = (const float*)d_in[2];
    const int*   pid    = (const int*)d_in[3];
    const float* Wq     = (const float*)d_in[4];
    const float* Wkv_a  = (const float*)d_in[5];
    const float* ln_g   = (const float*)d_in[6];
    const float* ln_b   = (const float*)d_in[7];
    const float* Wkv_b  = (const float*)d_in[8];
    const float* Wo     = (const float*)d_in[9];
    float* out = (float*)d_out;

    char* p = (char*)d_ws;
    short* hid_bf = (short*)p;               p += (size_t)NTOK * 2048 * 2;
    short* WqT    = (short*)p;               p += (size_t)3072 * 2048 * 2;
    short* WkaT   = (short*)p;               p += (size_t)640 * 2048 * 2;
    short* WkbT   = (short*)p;               p += (size_t)4096 * 512 * 2;
    short* WoT    = (short*)p;               p += (size_t)2048 * 2048 * 2;
    char*  big    = p;                       p += (size_t)NTOK * 3072 * 4;
    short* qbuf   = (short*)p;               p += (size_t)NTOK * 3072 * 2;
    short* kvcn   = (short*)p;               p += (size_t)NTOK * 512 * 2;
    short* kpe    = (short*)p;               p += (size_t)NTOK * 64 * 2;
    short* kvb    = (short*)p;               p += (size_t)NTOK * 4096 * 2;

    float* ckv   = (float*)big;
    short* Vt    = (short*)(big + (size_t)NTOK * 640 * 4);
    short* attno = (short*)(big + (size_t)NTOK * 640 * 4 + (size_t)2 * 16 * 128 * 2048 * 2);

    castk<<<8192, 256, 0, stream>>>(hidden, hid_bf);
    transpose_cast<<<dim3(96, 64), 256, 0, stream>>>(Wq, WqT, 2048, 3072);
    transpose_cast<<<dim3(20, 64), 256, 0, stream>>>(Wkv_a, WkaT, 2048, 576);
    transpose_cast<<<dim3(128, 16), 256, 0, stream>>>(Wkv_b, WkbT, 512, 4096);
    transpose_cast<<<dim3(64, 64), 256, 0, stream>>>(Wo, WoT, 2048, 2048);

    gemm_mfma<1><<<dim3(24, 32), 256, 0, stream>>>(hid_bf, WqT, qbuf, 4096, 3072, 2048);
    rope_q_ip<<<(NTOK * H_ * 32) / 256, 256, 0, stream>>>(qbuf, cosT, sinT, pid);
    gemm_mfma<0><<<dim3(5, 32), 256, 0, stream>>>(hid_bf, WkaT, ckv, 4096, 640, 2048);
    ln_rope<<<NTOK, 256, 0, stream>>>(ckv, ln_g, ln_b, cosT, sinT, pid, kvcn, kpe);
    gemm_mfma<1><<<dim3(32, 32), 256, 0, stream>>>(kvcn, WkbT, kvb, 4096, 4096, 512);
    transpose_v<<<dim3(32, 2, 32), 256, 0, stream>>>(kvb, Vt);
    flash_mfma<<<512, 256, 0, stream>>>(qbuf, kvb, kpe, Vt, attno);
    gemm_mfma<0><<<dim3(16, 32), 256, 0, stream>>>(attno, WoT, out, 4096, 2048, 2048);
}

// Round 9
// 354.594 us; speedup vs baseline: 1.5031x; 1.0042x over previous
//
#include <hip/hip_runtime.h>
#include <math.h>
#include <stdint.h>

#define B_      2
#define S_      2048
#define HID_    2048
#define H_      16
#define D_NOPE_ 128
#define D_ROPE_ 64
#define D_V_    128
#define R_      512
#define D_Q_    192
#define NTOK    (B_ * S_)
#define EPS_    1e-6f

typedef __attribute__((ext_vector_type(8))) short bf16x8;
typedef __attribute__((ext_vector_type(4))) float f32x4;

__device__ __forceinline__ short f2bf(float x) {
    union { float f; unsigned u; } un; un.f = x;
    unsigned r = (un.u + 0x7fffu + ((un.u >> 16) & 1u)) >> 16;
    return (short)r;
}
__device__ __forceinline__ float bf2f(short s) {
    union { unsigned u; float f; } un;
    un.u = ((unsigned)(unsigned short)s) << 16;
    return un.f;
}

__device__ __forceinline__ void async_ld16(const short* gsrc, short* ldst) {
    __builtin_amdgcn_global_load_lds(
        (const __attribute__((address_space(1))) void*)gsrc,
        (__attribute__((address_space(3))) void*)ldst, 16, 0, 0);
}

// ---------------------------------------------------------------------------
// cast f32 -> bf16
// ---------------------------------------------------------------------------
__global__ __launch_bounds__(256) void castk(const float* __restrict__ in, short* __restrict__ out) {
    int i = blockIdx.x * 256 + threadIdx.x;
    float4 v = ((const float4*)in)[i];
    ushort4 o;
    o.x = (unsigned short)f2bf(v.x); o.y = (unsigned short)f2bf(v.y);
    o.z = (unsigned short)f2bf(v.z); o.w = (unsigned short)f2bf(v.w);
    ((ushort4*)out)[i] = o;
}

// ---------------------------------------------------------------------------
// W[K][Nreal] f32 -> WT[Npad][K] bf16 (rows >= Nreal zero-filled).
// ---------------------------------------------------------------------------
__global__ __launch_bounds__(256) void transpose_cast(const float* __restrict__ W,
                                                      short* __restrict__ WT,
                                                      int K, int Nreal) {
    __shared__ float T[32][33];
    const int n0 = blockIdx.x * 32, k0 = blockIdx.y * 32;
    const int t = threadIdx.x;
    const int r = t >> 3, c4 = (t & 7) * 4;
    float4 v = make_float4(0.f, 0.f, 0.f, 0.f);
    if (n0 < Nreal) v = *(const float4*)&W[(size_t)(k0 + r) * Nreal + n0 + c4];
    T[r][c4 + 0] = v.x; T[r][c4 + 1] = v.y; T[r][c4 + 2] = v.z; T[r][c4 + 3] = v.w;
    __syncthreads();
    const int n = t >> 3, k4 = (t & 7) * 4;
    ushort4 o;
    o.x = (unsigned short)f2bf(T[k4 + 0][n]);
    o.y = (unsigned short)f2bf(T[k4 + 1][n]);
    o.z = (unsigned short)f2bf(T[k4 + 2][n]);
    o.w = (unsigned short)f2bf(T[k4 + 3][n]);
    *(ushort4*)&WT[(size_t)(n0 + n) * K + k0 + k4] = o;
}

// ---------------------------------------------------------------------------
// MFMA GEMM: C[M][N] = A[M][K](bf16) @ BT[N][K](bf16). 128x128 tile, 4 waves.
// ---------------------------------------------------------------------------
template <int OUTBF>
__global__ __launch_bounds__(256) void gemm_mfma(const short* __restrict__ A,
                                                 const short* __restrict__ BT,
                                                 void* __restrict__ C,
                                                 int M, int N, int K) {
    __shared__ short As[128 * 32];
    __shared__ short Bs[128 * 32];
    const int tid = threadIdx.x;
    const int lane = tid & 63, w = tid >> 6;
    const int brow = blockIdx.y * 128, bcol = blockIdx.x * 128;

    const int o0 = w * 1024 + lane * 16;
    const int r0 = o0 >> 6, q0p = (o0 >> 4) & 3;
    const int o1 = o0 + 4096;
    const int r1 = o1 >> 6, q1p = (o1 >> 4) & 3;
    const int s0 = r0 * K + 8 * (q0p ^ ((r0 >> 1) & 3));
    const int s1 = r1 * K + 8 * (q1p ^ ((r1 >> 1) & 3));
    const short* Ab = A + (size_t)brow * K;
    const short* Bb = BT + (size_t)bcol * K;
    short* AsU0 = &As[w * 512]; short* AsU1 = &As[w * 512 + 2048];
    short* BsU0 = &Bs[w * 512]; short* BsU1 = &Bs[w * 512 + 2048];

    const int wr = w >> 1, wc = w & 1;
    const int c16 = lane & 15, g = lane >> 4;
    const int qph = (g ^ ((c16 >> 1) & 3)) * 8;

    f32x4 zero = {0.f, 0.f, 0.f, 0.f};
    f32x4 acc[4][4];
#pragma unroll
    for (int i = 0; i < 4; ++i)
#pragma unroll
        for (int j = 0; j < 4; ++j) acc[i][j] = zero;

    for (int k0 = 0; k0 < K; k0 += 32) {
        async_ld16(Ab + s0 + k0, AsU0);
        async_ld16(Ab + s1 + k0, AsU1);
        async_ld16(Bb + s0 + k0, BsU0);
        async_ld16(Bb + s1 + k0, BsU1);
        __syncthreads();
        bf16x8 af[4], bf[4];
#pragma unroll
        for (int i = 0; i < 4; ++i) {
            af[i] = *(const bf16x8*)&As[(wr * 64 + i * 16 + c16) * 32 + qph];
            bf[i] = *(const bf16x8*)&Bs[(wc * 64 + i * 16 + c16) * 32 + qph];
        }
#pragma unroll
        for (int mi = 0; mi < 4; ++mi)
#pragma unroll
            for (int ni = 0; ni < 4; ++ni)
                acc[mi][ni] = __builtin_amdgcn_mfma_f32_16x16x32_bf16(af[mi], bf[ni], acc[mi][ni], 0, 0, 0);
        __syncthreads();
    }

#pragma unroll
    for (int mi = 0; mi < 4; ++mi)
#pragma unroll
        for (int ni = 0; ni < 4; ++ni)
#pragma unroll
            for (int reg = 0; reg < 4; ++reg) {
                int row = brow + wr * 64 + mi * 16 + 4 * g + reg;
                int col = bcol + wc * 64 + ni * 16 + c16;
                if (OUTBF) ((short*)C)[(size_t)row * N + col] = f2bf(acc[mi][ni][reg]);
                else       ((float*)C)[(size_t)row * N + col] = acc[mi][ni][reg];
            }
}

// ---------------------------------------------------------------------------
// Fused q+ckv GEMM: A[4096][2048] @ WqkaT[3712][2048].
// cols < 3072 -> qbuf bf16 (stride 3072); cols >= 3072 -> ckv f32 (stride 640).
// ---------------------------------------------------------------------------
__global__ __launch_bounds__(256) void gemm_qa(const short* __restrict__ A,
                                               const short* __restrict__ BT,
                                               short* __restrict__ qbuf,
                                               float* __restrict__ ckv) {
    __shared__ short As[128 * 32];
    __shared__ short Bs[128 * 32];
    const int K = 2048;
    const int tid = threadIdx.x;
    const int lane = tid & 63, w = tid >> 6;
    const int brow = blockIdx.y * 128, bcol = blockIdx.x * 128;

    const int o0 = w * 1024 + lane * 16;
    const int r0 = o0 >> 6, q0p = (o0 >> 4) & 3;
    const int o1 = o0 + 4096;
    const int r1 = o1 >> 6, q1p = (o1 >> 4) & 3;
    const int s0 = r0 * K + 8 * (q0p ^ ((r0 >> 1) & 3));
    const int s1 = r1 * K + 8 * (q1p ^ ((r1 >> 1) & 3));
    const short* Ab = A + (size_t)brow * K;
    const short* Bb = BT + (size_t)bcol * K;
    short* AsU0 = &As[w * 512]; short* AsU1 = &As[w * 512 + 2048];
    short* BsU0 = &Bs[w * 512]; short* BsU1 = &Bs[w * 512 + 2048];

    const int wr = w >> 1, wc = w & 1;
    const int c16 = lane & 15, g = lane >> 4;
    const int qph = (g ^ ((c16 >> 1) & 3)) * 8;

    f32x4 zero = {0.f, 0.f, 0.f, 0.f};
    f32x4 acc[4][4];
#pragma unroll
    for (int i = 0; i < 4; ++i)
#pragma unroll
        for (int j = 0; j < 4; ++j) acc[i][j] = zero;

    for (int k0 = 0; k0 < K; k0 += 32) {
        async_ld16(Ab + s0 + k0, AsU0);
        async_ld16(Ab + s1 + k0, AsU1);
        async_ld16(Bb + s0 + k0, BsU0);
        async_ld16(Bb + s1 + k0, BsU1);
        __syncthreads();
        bf16x8 af[4], bf[4];
#pragma unroll
        for (int i = 0; i < 4; ++i) {
            af[i] = *(const bf16x8*)&As[(wr * 64 + i * 16 + c16) * 32 + qph];
            bf[i] = *(const bf16x8*)&Bs[(wc * 64 + i * 16 + c16) * 32 + qph];
        }
#pragma unroll
        for (int mi = 0; mi < 4; ++mi)
#pragma unroll
            for (int ni = 0; ni < 4; ++ni)
                acc[mi][ni] = __builtin_amdgcn_mfma_f32_16x16x32_bf16(af[mi], bf[ni], acc[mi][ni], 0, 0, 0);
        __syncthreads();
    }

    if (bcol < 3072) {
#pragma unroll
        for (int mi = 0; mi < 4; ++mi)
#pragma unroll
            for (int ni = 0; ni < 4; ++ni)
#pragma unroll
                for (int reg = 0; reg < 4; ++reg) {
                    int row = brow + wr * 64 + mi * 16 + 4 * g + reg;
                    int col = bcol + wc * 64 + ni * 16 + c16;
                    qbuf[(size_t)row * 3072 + col] = f2bf(acc[mi][ni][reg]);
                }
    } else {
#pragma unroll
        for (int mi = 0; mi < 4; ++mi)
#pragma unroll
            for (int ni = 0; ni < 4; ++ni)
#pragma unroll
                for (int reg = 0; reg < 4; ++reg) {
                    int row = brow + wr * 64 + mi * 16 + 4 * g + reg;
                    int col = (bcol - 3072) + wc * 64 + ni * 16 + c16;
                    ckv[(size_t)row * 640 + col] = acc[mi][ni][reg];
                }
    }
}

// ---------------------------------------------------------------------------
// In-place RoPE on q_pe region of bf16 q.
// ---------------------------------------------------------------------------
__global__ __launch_bounds__(256) void rope_q_ip(short* __restrict__ qb,
                                                 const float* __restrict__ cosT,
                                                 const float* __restrict__ sinT,
                                                 const int* __restrict__ pid) {
    int gidx = blockIdx.x * 256 + threadIdx.x;
    int i = gidx & 31;
    int h = (gidx >> 5) & (H_ - 1);
    int tok = gidx >> 9;
    int pos = pid[tok];
    float c = cosT[pos * 32 + i];
    float s = sinT[pos * 32 + i];
    short* base = qb + (size_t)tok * (H_ * D_Q_) + h * D_Q_ + D_NOPE_;
    float x1 = bf2f(base[i]);
    float x2 = bf2f(base[i + 32]);
    base[i]      = f2bf(x1 * c - x2 * s);
    base[i + 32] = f2bf(x2 * c + x1 * s);
}

// ---------------------------------------------------------------------------
// LayerNorm(512) + RoPE(k_pe). ckv stride 640. Outputs bf16.
// ---------------------------------------------------------------------------
__global__ __launch_bounds__(256) void ln_rope(const float* __restrict__ ckv,
                                               const float* __restrict__ gam,
                                               const float* __restrict__ bet,
                                               const float* __restrict__ cosT,
                                               const float* __restrict__ sinT,
                                               const int* __restrict__ pid,
                                               short* __restrict__ kvcn,
                                               short* __restrict__ kpe) {
    const int tok = blockIdx.x, tid = threadIdx.x;
    const float* x = ckv + (size_t)tok * 640;
    float v0 = x[tid], v1 = x[tid + 256];
    float s = v0 + v1, sq = v0 * v0 + v1 * v1;
#pragma unroll
    for (int m = 1; m < 64; m <<= 1) { s += __shfl_xor(s, m); sq += __shfl_xor(sq, m); }
    __shared__ float ws[8];
    int wid = tid >> 6, lane = tid & 63;
    if (lane == 0) { ws[wid] = s; ws[4 + wid] = sq; }
    __syncthreads();
    s = ws[0] + ws[1] + ws[2] + ws[3];
    sq = ws[4] + ws[5] + ws[6] + ws[7];
    float mean = s * (1.f / 512.f);
    float var = sq * (1.f / 512.f) - mean * mean;
    float rstd = rsqrtf(var + EPS_);
    kvcn[(size_t)tok * 512 + tid]       = f2bf((v0 - mean) * rstd * gam[tid] + bet[tid]);
    kvcn[(size_t)tok * 512 + tid + 256] = f2bf((v1 - mean) * rstd * gam[tid + 256] + bet[tid + 256]);
    if (tid < 32) {
        int pos = pid[tok];
        float c = cosT[pos * 32 + tid], sn = sinT[pos * 32 + tid];
        float x1 = x[512 + tid], x2 = x[512 + 32 + tid];
        kpe[(size_t)tok * 64 + tid]      = f2bf(x1 * c - x2 * sn);
        kpe[(size_t)tok * 64 + 32 + tid] = f2bf(x2 * c + x1 * sn);
    }
}

// ---------------------------------------------------------------------------
// V transpose: kvb[token][h][128..255] -> Vt[b][h][d][s].
// ---------------------------------------------------------------------------
__global__ __launch_bounds__(256) void transpose_v(const short* __restrict__ kvb,
                                                   short* __restrict__ Vt) {
    __shared__ short T[64][72];
    const int s0 = blockIdx.x * 64, d0 = blockIdx.y * 64, bh = blockIdx.z;
    const int b = bh >> 4, h = bh & 15;
    const int t = threadIdx.x;
    const int r = t >> 3, c8 = (t & 7) * 8;
#pragma unroll
    for (int i = 0; i < 2; ++i) {
        int rr = r + 32 * i;
        bf16x8 v = *(const bf16x8*)&kvb[((size_t)(b * 2048 + s0 + rr) * 16 + h) * 256 + 128 + d0 + c8];
        *(bf16x8*)&T[rr][c8] = v;
    }
    __syncthreads();
#pragma unroll
    for (int i = 0; i < 2; ++i) {
        int d = r + 32 * i;
        bf16x8 o;
#pragma unroll
        for (int j = 0; j < 8; ++j) o[j] = T[c8 + j][d];
        *(bf16x8*)&Vt[((size_t)(b * 16 + h) * 128 + d0 + d) * 2048 + s0 + c8] = o;
    }
}

// ---------------------------------------------------------------------------
// MFMA flash attention. K+V LDS-staged (dbuf, swizzled source, rule 21).
// Complementary pairing (33 iters/block, 512 blocks, zero tail), XCD-pinned.
// Running stage pointers (strength-reduced addressing, reset per half).
// Softmax: raw max, exp2-FMA, defer-rescale (T13), row-sum deferred.
// ---------------------------------------------------------------------------
__global__ __launch_bounds__(256) void flash_mfma(const short* __restrict__ qb,
                                                  const short* __restrict__ kvb,
                                                  const short* __restrict__ kpe,
                                                  const short* __restrict__ Vt,
                                                  short* __restrict__ attno) {
    __shared__ short Ks[2][64 * 128];
    __shared__ short Vs[2][128 * 64];
    __shared__ short P[4][16][72];

    const int flat = blockIdx.x;              // 0..511
    const int xcd = flat & 7, idx = flat >> 3;
    const int bh = xcd + 8 * (idx >> 4);      // all 16 pairs of a bh on one XCD
    const int pair = idx & 15;
    const int b = bh >> 4, h = bh & 15;

    const int tid = threadIdx.x, lane = tid & 63, w = tid >> 6;
    const int c16 = lane & 15, g = lane >> 4, g8 = g * 8;
    const float SC2 = 0.10412063f;   // 1/sqrt(192) * log2(e)

    // staging address bases (computed once; rnd stride is 65536 shorts for
    // BOTH K (16 tokens x 4096) and V (32 d-rows x 2048))
    const int o = w * 1024 + lane * 16;
    const int rK = o >> 8, ccK = ((o >> 4) & 15) ^ (rK & 7);
    const int rV = o >> 7, ccV = ((o >> 4) & 7) ^ (rV & 7);
    const short* kB0  = kvb + ((size_t)((b * 2048 + rK) * 16 + h)) * 256 + ccK * 8;
    const short* vB0  = Vt + ((size_t)((b * 16 + h) * 128 + rV)) * 2048 + ccV * 8;
    const short* peB0 = kpe + (size_t)(b * 2048 + c16) * 64 + g8;

    f32x4 zero = {0.f, 0.f, 0.f, 0.f};

#define STAGE(BUF)                                                                  \
    {                                                                               \
        _Pragma("unroll")                                                           \
        for (int rnd = 0; rnd < 4; ++rnd)                                           \
            async_ld16(kRun + (size_t)rnd * 65536,                                  \
                       &Ks[BUF][(rnd * 4096 + w * 1024) >> 1]);                     \
        _Pragma("unroll")                                                           \
        for (int rnd = 0; rnd < 4; ++rnd)                                           \
            async_ld16(vRun + (size_t)rnd * 65536,                                  \
                       &Vs[BUF][(rnd * 4096 + w * 1024) >> 1]);                     \
        kRun += 64 * 4096;                                                          \
        vRun += 64;                                                                 \
    }

    for (int half = 0; half < 2; ++half) {
        const int qt = half ? (31 - pair) : pair;
        const int q0 = qt * 64;
        const int qrow = q0 + w * 16;

        const size_t qbase = ((size_t)(b * 2048 + qrow + c16) * 16 + h) * 192 + g8;
        bf16x8 qf[6];
#pragma unroll
        for (int ks = 0; ks < 6; ++ks) qf[ks] = *(const bf16x8*)(qb + qbase + 32 * ks);

        f32x4 acc[8];
#pragma unroll
        for (int i = 0; i < 8; ++i) acc[i] = zero;
        float mreg[4] = {-INFINITY, -INFINITY, -INFINITY, -INFINITY};
        float lreg[4] = {0.f, 0.f, 0.f, 0.f};

        const short* kRun = kB0;
        const short* vRun = vB0;
        const short* peRun = peB0;

        const int nt = qt + 1;
        STAGE(0);
        __syncthreads();
        int cur = 0;

        for (int kt = 0; kt < nt; ++kt) {
            if (kt + 1 < nt) STAGE(cur ^ 1);

            f32x4 sc[4];
#pragma unroll
            for (int i = 0; i < 4; ++i) sc[i] = zero;

            // QK^T nope from LDS (swizzled reads)
            __builtin_amdgcn_s_setprio(1);
#pragma unroll
            for (int ks = 0; ks < 4; ++ks)
#pragma unroll
                for (int nb = 0; nb < 4; ++nb) {
                    int row = nb * 16 + c16;
                    bf16x8 kf = *(const bf16x8*)&Ks[cur][row * 128 + (((g + 4 * ks) ^ (row & 7)) << 3)];
                    sc[nb] = __builtin_amdgcn_mfma_f32_16x16x32_bf16(qf[ks], kf, sc[nb], 0, 0, 0);
                }
            // pe part from global (kpe tiny, shared across heads -> L2-hot)
#pragma unroll
            for (int ks = 0; ks < 2; ++ks)
#pragma unroll
                for (int nb = 0; nb < 4; ++nb) {
                    bf16x8 kf = *(const bf16x8*)(peRun + (size_t)nb * 16 * 64 + ks * 32);
                    sc[nb] = __builtin_amdgcn_mfma_f32_16x16x32_bf16(qf[4 + ks], kf, sc[nb], 0, 0, 0);
                }
            __builtin_amdgcn_s_setprio(0);
            peRun += 64 * 64;

            // causal mask on RAW scores (last tile of this q-tile only)
            if (kt == nt - 1) {
#pragma unroll
                for (int nb = 0; nb < 4; ++nb)
#pragma unroll
                    for (int reg = 0; reg < 4; ++reg) {
                        int col = (nt - 1) * 64 + nb * 16 + c16;
                        int row = qrow + 4 * g + reg;
                        if (col > row) sc[nb][reg] = -INFINITY;
                    }
            }

            // row max (raw), 4 dependent shuffle rounds
            float rmax[4];
#pragma unroll
            for (int reg = 0; reg < 4; ++reg)
                rmax[reg] = fmaxf(fmaxf(sc[0][reg], sc[1][reg]), fmaxf(sc[2][reg], sc[3][reg]));
#pragma unroll
            for (int m = 1; m < 16; m <<= 1)
#pragma unroll
                for (int reg = 0; reg < 4; ++reg)
                    rmax[reg] = fmaxf(rmax[reg], __shfl_xor(rmax[reg], m));

            // defer-rescale (T13, THR=8 in log2 domain)
            float grow = rmax[0] * SC2 - mreg[0];
#pragma unroll
            for (int reg = 1; reg < 4; ++reg) grow = fmaxf(grow, rmax[reg] * SC2 - mreg[reg]);
            if (__any(grow > 8.f)) {
#pragma unroll
                for (int reg = 0; reg < 4; ++reg) {
                    float mnew = fmaxf(mreg[reg], rmax[reg] * SC2);
                    float alpha = exp2f(mreg[reg] - mnew);
                    mreg[reg] = mnew;
                    lreg[reg] *= alpha;
#pragma unroll
                    for (int nb = 0; nb < 8; ++nb) acc[nb][reg] *= alpha;
                }
            }

            // p = 2^(s*SC2 - m); per-lane partial row sum (reduce deferred)
#pragma unroll
            for (int reg = 0; reg < 4; ++reg) {
                float p0 = exp2f(fmaf(sc[0][reg], SC2, -mreg[reg]));
                float p1 = exp2f(fmaf(sc[1][reg], SC2, -mreg[reg]));
                float p2 = exp2f(fmaf(sc[2][reg], SC2, -mreg[reg]));
                float p3 = exp2f(fmaf(sc[3][reg], SC2, -mreg[reg]));
                sc[0][reg] = p0; sc[1][reg] = p1; sc[2][reg] = p2; sc[3][reg] = p3;
                lreg[reg] += (p0 + p1) + (p2 + p3);
            }

            // P -> LDS (C/D layout -> A layout)
#pragma unroll
            for (int nb = 0; nb < 4; ++nb)
#pragma unroll
                for (int reg = 0; reg < 4; ++reg)
                    P[w][4 * g + reg][nb * 16 + c16] = f2bf(sc[nb][reg]);

            // PV from LDS V (swizzled reads)
            __builtin_amdgcn_s_setprio(1);
#pragma unroll
            for (int ks = 0; ks < 2; ++ks) {
                bf16x8 pf = *(const bf16x8*)&P[w][c16][ks * 32 + g8];
#pragma unroll
                for (int nb = 0; nb < 8; ++nb) {
                    int row = nb * 16 + c16;
                    bf16x8 vf = *(const bf16x8*)&Vs[cur][row * 64 + (((g + 4 * ks) ^ (row & 7)) << 3)];
                    acc[nb] = __builtin_amdgcn_mfma_f32_16x16x32_bf16(pf, vf, acc[nb], 0, 0, 0);
                }
            }
            __builtin_amdgcn_s_setprio(0);

            __syncthreads();   // drains stage vmcnt + all waves done with buffers
            cur ^= 1;
        }

        // epilogue: finish deferred row-sum reduce, normalize, store
#pragma unroll
        for (int m = 1; m < 16; m <<= 1)
#pragma unroll
            for (int reg = 0; reg < 4; ++reg)
                lreg[reg] += __shfl_xor(lreg[reg], m);
        float inv[4];
#pragma unroll
        for (int reg = 0; reg < 4; ++reg) inv[reg] = 1.f / lreg[reg];
#pragma unroll
        for (int nb = 0; nb < 8; ++nb)
#pragma unroll
            for (int reg = 0; reg < 4; ++reg)
                attno[((size_t)(b * 2048 + qrow + 4 * g + reg) * 16 + h) * 128 + nb * 16 + c16] =
                    f2bf(acc[nb][reg] * inv[reg]);
    }
#undef STAGE
}

// ---------------------------------------------------------------------------
extern "C" void kernel_launch(void* const* d_in, const int* in_sizes, int n_in,
                              void* d_out, int out_size, void* d_ws, size_t ws_size,
                              hipStream_t stream) {
    const float* hidden = (const float*)d_in[0];
    const float* cosT   = (const float*)d_in[1];
    const float* sinT   = (const float*)d_in[2];
    const int*   pid    = (const int*)d_in[3];
    const float* Wq     = (const float*)d_in[4];
    const float* Wkv_a  = (const float*)d_in[5];
    const float* ln_g   = (const float*)d_in[6];
    const float* ln_b   = (const float*)d_in[7];
    const float* Wkv_b  = (const float*)d_in[8];
    const float* Wo     = (const float*)d_in[9];
    float* out = (float*)d_out;

    char* p = (char*)d_ws;
    short* hid_bf = (short*)p;               p += (size_t)NTOK * 2048 * 2;
    short* WqkaT  = (short*)p;               p += (size_t)3712 * 2048 * 2;  // WqT | WkaT
    short* WkbT   = (short*)p;               p += (size_t)4096 * 512 * 2;
    short* WoT    = (short*)p;               p += (size_t)2048 * 2048 * 2;
    char*  big    = p;                       p += (size_t)NTOK * 3072 * 4;
    short* qbuf   = (short*)p;               p += (size_t)NTOK * 3072 * 2;
    short* kvcn   = (short*)p;               p += (size_t)NTOK * 512 * 2;
    short* kpe    = (short*)p;               p += (size_t)NTOK * 64 * 2;
    short* kvb    = (short*)p;               p += (size_t)NTOK * 4096 * 2;

    float* ckv   = (float*)big;
    short* Vt    = (short*)(big + (size_t)NTOK * 640 * 4);
    short* attno = (short*)(big + (size_t)NTOK * 640 * 4 + (size_t)2 * 16 * 128 * 2048 * 2);

    castk<<<8192, 256, 0, stream>>>(hidden, hid_bf);
    transpose_cast<<<dim3(96, 64), 256, 0, stream>>>(Wq, WqkaT, 2048, 3072);
    transpose_cast<<<dim3(20, 64), 256, 0, stream>>>(Wkv_a, WqkaT + (size_t)3072 * 2048, 2048, 576);
    transpose_cast<<<dim3(128, 16), 256, 0, stream>>>(Wkv_b, WkbT, 512, 4096);
    transpose_cast<<<dim3(64, 64), 256, 0, stream>>>(Wo, WoT, 2048, 2048);

    // 1+3 fused. q -> qbuf (bf16), ckv -> f32 stride 640
    gemm_qa<<<dim3(29, 32), 256, 0, stream>>>(hid_bf, WqkaT, qbuf, ckv);
    // 2. RoPE in place on q_pe (bf16)
    rope_q_ip<<<(NTOK * H_ * 32) / 256, 256, 0, stream>>>(qbuf, cosT, sinT, pid);
    // 4. LayerNorm + RoPE(k_pe) -> bf16
    ln_rope<<<NTOK, 256, 0, stream>>>(ckv, ln_g, ln_b, cosT, sinT, pid, kvcn, kpe);
    // 5. kv = kvcn @ Wkv_b (bf16 out)
    gemm_mfma<1><<<dim3(32, 32), 256, 0, stream>>>(kvcn, WkbT, kvb, 4096, 4096, 512);
    // 6. V transpose
    transpose_v<<<dim3(32, 2, 32), 256, 0, stream>>>(kvb, Vt);
    // 7. flash attention
    flash_mfma<<<512, 256, 0, stream>>>(qbuf, kvb, kpe, Vt, attno);
    // 8. out = attno @ Wo (f32 out)
    gemm_mfma<0><<<dim3(16, 32), 256, 0, stream>>>(attno, WoT, out, 4096, 2048, 2048);
}

// Round 10
// 308.235 us; speedup vs baseline: 1.7292x; 1.1504x over previous
//
#include <hip/hip_runtime.h>
#include <math.h>
#include <stdint.h>

#define B_      2
#define S_      2048
#define HID_    2048
#define H_      16
#define D_NOPE_ 128
#define D_ROPE_ 64
#define D_V_    128
#define R_      512
#define D_Q_    192
#define NTOK    (B_ * S_)
#define EPS_    1e-6f

typedef __attribute__((ext_vector_type(8))) short bf16x8;
typedef __attribute__((ext_vector_type(4))) float f32x4;

__device__ __forceinline__ short f2bf(float x) {
    union { float f; unsigned u; } un; un.f = x;
    unsigned r = (un.u + 0x7fffu + ((un.u >> 16) & 1u)) >> 16;
    return (short)r;
}
__device__ __forceinline__ float bf2f(short s) {
    union { unsigned u; float f; } un;
    un.u = ((unsigned)(unsigned short)s) << 16;
    return un.f;
}

__device__ __forceinline__ void async_ld16(const short* gsrc, short* ldst) {
    __builtin_amdgcn_global_load_lds(
        (const __attribute__((address_space(1))) void*)gsrc,
        (__attribute__((address_space(3))) void*)ldst, 16, 0, 0);
}

#define BARX() { __builtin_amdgcn_sched_barrier(0); __builtin_amdgcn_s_barrier(); __builtin_amdgcn_sched_barrier(0); }

// ---------------------------------------------------------------------------
// cast f32 -> bf16
// ---------------------------------------------------------------------------
__global__ __launch_bounds__(256) void castk(const float* __restrict__ in, short* __restrict__ out) {
    int i = blockIdx.x * 256 + threadIdx.x;
    float4 v = ((const float4*)in)[i];
    ushort4 o;
    o.x = (unsigned short)f2bf(v.x); o.y = (unsigned short)f2bf(v.y);
    o.z = (unsigned short)f2bf(v.z); o.w = (unsigned short)f2bf(v.w);
    ((ushort4*)out)[i] = o;
}

// ---------------------------------------------------------------------------
// W[K][Nreal] f32 -> WT[Npad][K] bf16 (rows >= Nreal zero-filled).
// ---------------------------------------------------------------------------
__global__ __launch_bounds__(256) void transpose_cast(const float* __restrict__ W,
                                                      short* __restrict__ WT,
                                                      int K, int Nreal) {
    __shared__ float T[32][33];
    const int n0 = blockIdx.x * 32, k0 = blockIdx.y * 32;
    const int t = threadIdx.x;
    const int r = t >> 3, c4 = (t & 7) * 4;
    float4 v = make_float4(0.f, 0.f, 0.f, 0.f);
    if (n0 < Nreal) v = *(const float4*)&W[(size_t)(k0 + r) * Nreal + n0 + c4];
    T[r][c4 + 0] = v.x; T[r][c4 + 1] = v.y; T[r][c4 + 2] = v.z; T[r][c4 + 3] = v.w;
    __syncthreads();
    const int n = t >> 3, k4 = (t & 7) * 4;
    ushort4 o;
    o.x = (unsigned short)f2bf(T[k4 + 0][n]);
    o.y = (unsigned short)f2bf(T[k4 + 1][n]);
    o.z = (unsigned short)f2bf(T[k4 + 2][n]);
    o.w = (unsigned short)f2bf(T[k4 + 3][n]);
    *(ushort4*)&WT[(size_t)(n0 + n) * K + k0 + k4] = o;
}

// ---------------------------------------------------------------------------
// OLD 128x128 MFMA GEMM (kept for gemm_out where N=2048 favors 512 blocks)
// ---------------------------------------------------------------------------
template <int OUTBF>
__global__ __launch_bounds__(256) void gemm_mfma(const short* __restrict__ A,
                                                 const short* __restrict__ BT,
                                                 void* __restrict__ C,
                                                 int M, int N, int K) {
    __shared__ short As[128 * 32];
    __shared__ short Bs[128 * 32];
    const int tid = threadIdx.x;
    const int lane = tid & 63, w = tid >> 6;
    const int brow = blockIdx.y * 128, bcol = blockIdx.x * 128;

    const int o0 = w * 1024 + lane * 16;
    const int r0 = o0 >> 6, q0p = (o0 >> 4) & 3;
    const int o1 = o0 + 4096;
    const int r1 = o1 >> 6, q1p = (o1 >> 4) & 3;
    const int s0 = r0 * K + 8 * (q0p ^ ((r0 >> 1) & 3));
    const int s1 = r1 * K + 8 * (q1p ^ ((r1 >> 1) & 3));
    const short* Ab = A + (size_t)brow * K;
    const short* Bb = BT + (size_t)bcol * K;
    short* AsU0 = &As[w * 512]; short* AsU1 = &As[w * 512 + 2048];
    short* BsU0 = &Bs[w * 512]; short* BsU1 = &Bs[w * 512 + 2048];

    const int wr = w >> 1, wc = w & 1;
    const int c16 = lane & 15, g = lane >> 4;
    const int qph = (g ^ ((c16 >> 1) & 3)) * 8;

    f32x4 zero = {0.f, 0.f, 0.f, 0.f};
    f32x4 acc[4][4];
#pragma unroll
    for (int i = 0; i < 4; ++i)
#pragma unroll
        for (int j = 0; j < 4; ++j) acc[i][j] = zero;

    for (int k0 = 0; k0 < K; k0 += 32) {
        async_ld16(Ab + s0 + k0, AsU0);
        async_ld16(Ab + s1 + k0, AsU1);
        async_ld16(Bb + s0 + k0, BsU0);
        async_ld16(Bb + s1 + k0, BsU1);
        __syncthreads();
        bf16x8 af[4], bf[4];
#pragma unroll
        for (int i = 0; i < 4; ++i) {
            af[i] = *(const bf16x8*)&As[(wr * 64 + i * 16 + c16) * 32 + qph];
            bf[i] = *(const bf16x8*)&Bs[(wc * 64 + i * 16 + c16) * 32 + qph];
        }
#pragma unroll
        for (int mi = 0; mi < 4; ++mi)
#pragma unroll
            for (int ni = 0; ni < 4; ++ni)
                acc[mi][ni] = __builtin_amdgcn_mfma_f32_16x16x32_bf16(af[mi], bf[ni], acc[mi][ni], 0, 0, 0);
        __syncthreads();
    }

#pragma unroll
    for (int mi = 0; mi < 4; ++mi)
#pragma unroll
        for (int ni = 0; ni < 4; ++ni)
#pragma unroll
            for (int reg = 0; reg < 4; ++reg) {
                int row = brow + wr * 64 + mi * 16 + 4 * g + reg;
                int col = bcol + wc * 64 + ni * 16 + c16;
                if (OUTBF) ((short*)C)[(size_t)row * N + col] = f2bf(acc[mi][ni][reg]);
                else       ((float*)C)[(size_t)row * N + col] = acc[mi][ni][reg];
            }
}

// ---------------------------------------------------------------------------
// 256x256 8-phase GEMM (T3+T4+T5). 512 threads = 8 waves (2M x 4N).
// BK=64 as 2x [256][32] sub-buffers per operand, double-buffered: LDS 128KB.
// Phase: {ds_read frags; 2 stage loads; (vmcnt(4) at P2/P4); barrier;
//         setprio(1); 16 MFMA; setprio(0); barrier}. Counted vmcnt keeps
// 2-3 phases of load flight time; vmcnt(0) only on the final iteration.
// QA=1: dual epilogue (cols<3072 -> qbuf bf16 s3072; 3072..3711 -> ckv f32
// s640; >=3712 pad, dropped). QA=0: bf16 C with stride N.
// ---------------------------------------------------------------------------
template <int QA>
__global__ __launch_bounds__(512) void gemm8(const short* __restrict__ A,
                                             const short* __restrict__ BT,
                                             void* __restrict__ C0,
                                             float* __restrict__ C1,
                                             int N, int K, int nbx) {
    __shared__ short LB[2][4][8192];   // [buf][A0,A1,B0,B1][256 rows x 32]

    const int tid = threadIdx.x, lane = tid & 63, w = tid >> 6;
    const int c16 = lane & 15, g = lane >> 4;
    const int wr = w >> 2, wc = w & 3;
    const int qph = (g ^ ((c16 >> 1) & 3)) * 8;

    // XCD-chunked bijective swizzle (nwg % 8 == 0 at both call sites)
    const int nwg = gridDim.x;
    const int swz = (blockIdx.x & 7) * (nwg >> 3) + (blockIdx.x >> 3);
    const int brow = (swz / nbx) * 256, bcol = (swz % nbx) * 256;

    // staging precompute: thread covers LDS bytes o, o+8192 of each 16KB sub
    const int o0 = w * 1024 + lane * 16;
    const int o1 = o0 + 8192;
    const int r0 = o0 >> 6, lc0 = ((o0 >> 4) & 3) ^ ((r0 >> 1) & 3);
    const int r1 = o1 >> 6, lc1 = ((o1 >> 4) & 3) ^ ((r1 >> 1) & 3);
    const short* aS0 = A + (size_t)(brow + r0) * K + lc0 * 8;
    const short* aS1 = A + (size_t)(brow + r1) * K + lc1 * 8;
    const short* bS0 = BT + (size_t)(bcol + r0) * K + lc0 * 8;
    const short* bS1 = BT + (size_t)(bcol + r1) * K + lc1 * 8;
    const int d0 = w * 512, d1 = 4096 + w * 512;   // short offsets in a sub

    f32x4 zero = {0.f, 0.f, 0.f, 0.f};
    f32x4 acc[8][4];
#pragma unroll
    for (int i = 0; i < 8; ++i)
#pragma unroll
        for (int j = 0; j < 4; ++j) acc[i][j] = zero;

    const int NT = K >> 6;
    // prologue: stage K-tile 0 into buf0 (cold start: full drain once)
    async_ld16(aS0,      &LB[0][0][d0]);  async_ld16(aS1,      &LB[0][0][d1]);
    async_ld16(aS0 + 32, &LB[0][1][d0]);  async_ld16(aS1 + 32, &LB[0][1][d1]);
    async_ld16(bS0,      &LB[0][2][d0]);  async_ld16(bS1,      &LB[0][2][d1]);
    async_ld16(bS0 + 32, &LB[0][3][d0]);  async_ld16(bS1 + 32, &LB[0][3][d1]);
    asm volatile("s_waitcnt vmcnt(0)" ::: "memory");
    BARX();

    int cur = 0;
    const int arb = wr * 128, brb = wc * 64;
    for (int kt = 0; kt < NT; ++kt) {
        const bool stg = (kt + 1 < NT);
        const int ko = (kt + 1) * 64;
        short (*CB)[8192] = LB[cur];
        short (*NB)[8192] = LB[cur ^ 1];
        bf16x8 af[4], bf[4];

        // ---- P1: ksub0, mi0-3 (reads B0 + A0; stages A0') ----
#pragma unroll
        for (int ni = 0; ni < 4; ++ni)
            bf[ni] = *(const bf16x8*)&CB[2][(brb + ni * 16 + c16) * 32 + qph];
#pragma unroll
        for (int mi = 0; mi < 4; ++mi)
            af[mi] = *(const bf16x8*)&CB[0][(arb + mi * 16 + c16) * 32 + qph];
        if (stg) { async_ld16(aS0 + ko, &NB[0][d0]); async_ld16(aS1 + ko, &NB[0][d1]); }
        BARX();
        __builtin_amdgcn_s_setprio(1);
#pragma unroll
        for (int mi = 0; mi < 4; ++mi)
#pragma unroll
            for (int ni = 0; ni < 4; ++ni)
                acc[mi][ni] = __builtin_amdgcn_mfma_f32_16x16x32_bf16(af[mi], bf[ni], acc[mi][ni], 0, 0, 0);
        __builtin_amdgcn_s_setprio(0);
        BARX();

        // ---- P2: ksub0, mi4-7 (reads A0 hi; stages B0'; drains A1,B1) ----
#pragma unroll
        for (int mi = 0; mi < 4; ++mi)
            af[mi] = *(const bf16x8*)&CB[0][(arb + 64 + mi * 16 + c16) * 32 + qph];
        if (stg) {
            async_ld16(bS0 + ko, &NB[2][d0]); async_ld16(bS1 + ko, &NB[2][d1]);
            asm volatile("s_waitcnt vmcnt(4)" ::: "memory");
        } else {
            asm volatile("s_waitcnt vmcnt(0)" ::: "memory");
        }
        BARX();
        __builtin_amdgcn_s_setprio(1);
#pragma unroll
        for (int mi = 0; mi < 4; ++mi)
#pragma unroll
            for (int ni = 0; ni < 4; ++ni)
                acc[4 + mi][ni] = __builtin_amdgcn_mfma_f32_16x16x32_bf16(af[mi], bf[ni], acc[4 + mi][ni], 0, 0, 0);
        __builtin_amdgcn_s_setprio(0);
        BARX();

        // ---- P3: ksub1, mi0-3 (reads B1 + A1; stages A1') ----
#pragma unroll
        for (int ni = 0; ni < 4; ++ni)
            bf[ni] = *(const bf16x8*)&CB[3][(brb + ni * 16 + c16) * 32 + qph];
#pragma unroll
        for (int mi = 0; mi < 4; ++mi)
            af[mi] = *(const bf16x8*)&CB[1][(arb + mi * 16 + c16) * 32 + qph];
        if (stg) { async_ld16(aS0 + ko + 32, &NB[1][d0]); async_ld16(aS1 + ko + 32, &NB[1][d1]); }
        BARX();
        __builtin_amdgcn_s_setprio(1);
#pragma unroll
        for (int mi = 0; mi < 4; ++mi)
#pragma unroll
            for (int ni = 0; ni < 4; ++ni)
                acc[mi][ni] = __builtin_amdgcn_mfma_f32_16x16x32_bf16(af[mi], bf[ni], acc[mi][ni], 0, 0, 0);
        __builtin_amdgcn_s_setprio(0);
        BARX();

        // ---- P4: ksub1, mi4-7 (reads A1 hi; stages B1'; drains A0',B0') ----
#pragma unroll
        for (int mi = 0; mi < 4; ++mi)
            af[mi] = *(const bf16x8*)&CB[1][(arb + 64 + mi * 16 + c16) * 32 + qph];
        if (stg) {
            async_ld16(bS0 + ko + 32, &NB[3][d0]); async_ld16(bS1 + ko + 32, &NB[3][d1]);
            asm volatile("s_waitcnt vmcnt(4)" ::: "memory");
        }
        BARX();
        __builtin_amdgcn_s_setprio(1);
#pragma unroll
        for (int mi = 0; mi < 4; ++mi)
#pragma unroll
            for (int ni = 0; ni < 4; ++ni)
                acc[4 + mi][ni] = __builtin_amdgcn_mfma_f32_16x16x32_bf16(af[mi], bf[ni], acc[4 + mi][ni], 0, 0, 0);
        __builtin_amdgcn_s_setprio(0);
        BARX();

        cur ^= 1;
    }

    // epilogue
    if (QA) {
        const int wcol = bcol + wc * 64;
        if (wcol < 3072) {
            short* qb = (short*)C0;
#pragma unroll
            for (int mi = 0; mi < 8; ++mi)
#pragma unroll
                for (int ni = 0; ni < 4; ++ni)
#pragma unroll
                    for (int reg = 0; reg < 4; ++reg) {
                        int row = brow + wr * 128 + mi * 16 + 4 * g + reg;
                        int col = wcol + ni * 16 + c16;
                        qb[(size_t)row * 3072 + col] = f2bf(acc[mi][ni][reg]);
                    }
        } else if (wcol < 3712) {
#pragma unroll
            for (int mi = 0; mi < 8; ++mi)
#pragma unroll
                for (int ni = 0; ni < 4; ++ni)
#pragma unroll
                    for (int reg = 0; reg < 4; ++reg) {
                        int row = brow + wr * 128 + mi * 16 + 4 * g + reg;
                        int col = wcol - 3072 + ni * 16 + c16;
                        C1[(size_t)row * 640 + col] = acc[mi][ni][reg];
                    }
        }
    } else {
        short* cc = (short*)C0;
#pragma unroll
        for (int mi = 0; mi < 8; ++mi)
#pragma unroll
            for (int ni = 0; ni < 4; ++ni)
#pragma unroll
                for (int reg = 0; reg < 4; ++reg) {
                    int row = brow + wr * 128 + mi * 16 + 4 * g + reg;
                    int col = bcol + wc * 64 + ni * 16 + c16;
                    cc[(size_t)row * N + col] = f2bf(acc[mi][ni][reg]);
                }
    }
}

// ---------------------------------------------------------------------------
// In-place RoPE on q_pe region of bf16 q.
// ---------------------------------------------------------------------------
__global__ __launch_bounds__(256) void rope_q_ip(short* __restrict__ qb,
                                                 const float* __restrict__ cosT,
                                                 const float* __restrict__ sinT,
                                                 const int* __restrict__ pid) {
    int gidx = blockIdx.x * 256 + threadIdx.x;
    int i = gidx & 31;
    int h = (gidx >> 5) & (H_ - 1);
    int tok = gidx >> 9;
    int pos = pid[tok];
    float c = cosT[pos * 32 + i];
    float s = sinT[pos * 32 + i];
    short* base = qb + (size_t)tok * (H_ * D_Q_) + h * D_Q_ + D_NOPE_;
    float x1 = bf2f(base[i]);
    float x2 = bf2f(base[i + 32]);
    base[i]      = f2bf(x1 * c - x2 * s);
    base[i + 32] = f2bf(x2 * c + x1 * s);
}

// ---------------------------------------------------------------------------
// LayerNorm(512) + RoPE(k_pe). ckv stride 640. Outputs bf16.
// ---------------------------------------------------------------------------
__global__ __launch_bounds__(256) void ln_rope(const float* __restrict__ ckv,
                                               const float* __restrict__ gam,
                                               const float* __restrict__ bet,
                                               const float* __restrict__ cosT,
                                               const float* __restrict__ sinT,
                                               const int* __restrict__ pid,
                                               short* __restrict__ kvcn,
                                               short* __restrict__ kpe) {
    const int tok = blockIdx.x, tid = threadIdx.x;
    const float* x = ckv + (size_t)tok * 640;
    float v0 = x[tid], v1 = x[tid + 256];
    float s = v0 + v1, sq = v0 * v0 + v1 * v1;
#pragma unroll
    for (int m = 1; m < 64; m <<= 1) { s += __shfl_xor(s, m); sq += __shfl_xor(sq, m); }
    __shared__ float ws[8];
    int wid = tid >> 6, lane = tid & 63;
    if (lane == 0) { ws[wid] = s; ws[4 + wid] = sq; }
    __syncthreads();
    s = ws[0] + ws[1] + ws[2] + ws[3];
    sq = ws[4] + ws[5] + ws[6] + ws[7];
    float mean = s * (1.f / 512.f);
    float var = sq * (1.f / 512.f) - mean * mean;
    float rstd = rsqrtf(var + EPS_);
    kvcn[(size_t)tok * 512 + tid]       = f2bf((v0 - mean) * rstd * gam[tid] + bet[tid]);
    kvcn[(size_t)tok * 512 + tid + 256] = f2bf((v1 - mean) * rstd * gam[tid + 256] + bet[tid + 256]);
    if (tid < 32) {
        int pos = pid[tok];
        float c = cosT[pos * 32 + tid], sn = sinT[pos * 32 + tid];
        float x1 = x[512 + tid], x2 = x[512 + 32 + tid];
        kpe[(size_t)tok * 64 + tid]      = f2bf(x1 * c - x2 * sn);
        kpe[(size_t)tok * 64 + 32 + tid] = f2bf(x2 * c + x1 * sn);
    }
}

// ---------------------------------------------------------------------------
// V transpose: kvb[token][h][128..255] -> Vt[b][h][d][s].
// ---------------------------------------------------------------------------
__global__ __launch_bounds__(256) void transpose_v(const short* __restrict__ kvb,
                                                   short* __restrict__ Vt) {
    __shared__ short T[64][72];
    const int s0 = blockIdx.x * 64, d0 = blockIdx.y * 64, bh = blockIdx.z;
    const int b = bh >> 4, h = bh & 15;
    const int t = threadIdx.x;
    const int r = t >> 3, c8 = (t & 7) * 8;
#pragma unroll
    for (int i = 0; i < 2; ++i) {
        int rr = r + 32 * i;
        bf16x8 v = *(const bf16x8*)&kvb[((size_t)(b * 2048 + s0 + rr) * 16 + h) * 256 + 128 + d0 + c8];
        *(bf16x8*)&T[rr][c8] = v;
    }
    __syncthreads();
#pragma unroll
    for (int i = 0; i < 2; ++i) {
        int d = r + 32 * i;
        bf16x8 o;
#pragma unroll
        for (int j = 0; j < 8; ++j) o[j] = T[c8 + j][d];
        *(bf16x8*)&Vt[((size_t)(b * 16 + h) * 128 + d0 + d) * 2048 + s0 + c8] = o;
    }
}

// ---------------------------------------------------------------------------
// MFMA flash attention (R8/R9 structure, unchanged math).
// ---------------------------------------------------------------------------
__global__ __launch_bounds__(256) void flash_mfma(const short* __restrict__ qb,
                                                  const short* __restrict__ kvb,
                                                  const short* __restrict__ kpe,
                                                  const short* __restrict__ Vt,
                                                  short* __restrict__ attno) {
    __shared__ short Ks[2][64 * 128];
    __shared__ short Vs[2][128 * 64];
    __shared__ short P[4][16][72];

    const int flat = blockIdx.x;              // 0..511
    const int xcd = flat & 7, idx = flat >> 3;
    const int bh = xcd + 8 * (idx >> 4);
    const int pair = idx & 15;
    const int b = bh >> 4, h = bh & 15;

    const int tid = threadIdx.x, lane = tid & 63, w = tid >> 6;
    const int c16 = lane & 15, g = lane >> 4, g8 = g * 8;
    const float SC2 = 0.10412063f;   // 1/sqrt(192) * log2(e)

    const int o = w * 1024 + lane * 16;
    const int rK = o >> 8, ccK = ((o >> 4) & 15) ^ (rK & 7);
    const int rV = o >> 7, ccV = ((o >> 4) & 7) ^ (rV & 7);
    const short* kB0  = kvb + ((size_t)((b * 2048 + rK) * 16 + h)) * 256 + ccK * 8;
    const short* vB0  = Vt + ((size_t)((b * 16 + h) * 128 + rV)) * 2048 + ccV * 8;
    const short* peB0 = kpe + (size_t)(b * 2048 + c16) * 64 + g8;

    f32x4 zero = {0.f, 0.f, 0.f, 0.f};

#define STAGE(BUF)                                                                  \
    {                                                                               \
        _Pragma("unroll")                                                           \
        for (int rnd = 0; rnd < 4; ++rnd)                                           \
            async_ld16(kRun + (size_t)rnd * 65536,                                  \
                       &Ks[BUF][(rnd * 4096 + w * 1024) >> 1]);                     \
        _Pragma("unroll")                                                           \
        for (int rnd = 0; rnd < 4; ++rnd)                                           \
            async_ld16(vRun + (size_t)rnd * 65536,                                  \
                       &Vs[BUF][(rnd * 4096 + w * 1024) >> 1]);                     \
        kRun += 64 * 4096;                                                          \
        vRun += 64;                                                                 \
    }

    for (int half = 0; half < 2; ++half) {
        const int qt = half ? (31 - pair) : pair;
        const int q0 = qt * 64;
        const int qrow = q0 + w * 16;

        const size_t qbase = ((size_t)(b * 2048 + qrow + c16) * 16 + h) * 192 + g8;
        bf16x8 qf[6];
#pragma unroll
        for (int ks = 0; ks < 6; ++ks) qf[ks] = *(const bf16x8*)(qb + qbase + 32 * ks);

        f32x4 acc[8];
#pragma unroll
        for (int i = 0; i < 8; ++i) acc[i] = zero;
        float mreg[4] = {-INFINITY, -INFINITY, -INFINITY, -INFINITY};
        float lreg[4] = {0.f, 0.f, 0.f, 0.f};

        const short* kRun = kB0;
        const short* vRun = vB0;
        const short* peRun = peB0;

        const int nt = qt + 1;
        STAGE(0);
        __syncthreads();
        int cur = 0;

        for (int kt = 0; kt < nt; ++kt) {
            if (kt + 1 < nt) STAGE(cur ^ 1);

            f32x4 sc[4];
#pragma unroll
            for (int i = 0; i < 4; ++i) sc[i] = zero;

            __builtin_amdgcn_s_setprio(1);
#pragma unroll
            for (int ks = 0; ks < 4; ++ks)
#pragma unroll
                for (int nb = 0; nb < 4; ++nb) {
                    int row = nb * 16 + c16;
                    bf16x8 kf = *(const bf16x8*)&Ks[cur][row * 128 + (((g + 4 * ks) ^ (row & 7)) << 3)];
                    sc[nb] = __builtin_amdgcn_mfma_f32_16x16x32_bf16(qf[ks], kf, sc[nb], 0, 0, 0);
                }
#pragma unroll
            for (int ks = 0; ks < 2; ++ks)
#pragma unroll
                for (int nb = 0; nb < 4; ++nb) {
                    bf16x8 kf = *(const bf16x8*)(peRun + (size_t)nb * 16 * 64 + ks * 32);
                    sc[nb] = __builtin_amdgcn_mfma_f32_16x16x32_bf16(qf[4 + ks], kf, sc[nb], 0, 0, 0);
                }
            __builtin_amdgcn_s_setprio(0);
            peRun += 64 * 64;

            if (kt == nt - 1) {
#pragma unroll
                for (int nb = 0; nb < 4; ++nb)
#pragma unroll
                    for (int reg = 0; reg < 4; ++reg) {
                        int col = (nt - 1) * 64 + nb * 16 + c16;
                        int row = qrow + 4 * g + reg;
                        if (col > row) sc[nb][reg] = -INFINITY;
                    }
            }

            float rmax[4];
#pragma unroll
            for (int reg = 0; reg < 4; ++reg)
                rmax[reg] = fmaxf(fmaxf(sc[0][reg], sc[1][reg]), fmaxf(sc[2][reg], sc[3][reg]));
#pragma unroll
            for (int m = 1; m < 16; m <<= 1)
#pragma unroll
                for (int reg = 0; reg < 4; ++reg)
                    rmax[reg] = fmaxf(rmax[reg], __shfl_xor(rmax[reg], m));

            float grow = rmax[0] * SC2 - mreg[0];
#pragma unroll
            for (int reg = 1; reg < 4; ++reg) grow = fmaxf(grow, rmax[reg] * SC2 - mreg[reg]);
            if (__any(grow > 8.f)) {
#pragma unroll
                for (int reg = 0; reg < 4; ++reg) {
                    float mnew = fmaxf(mreg[reg], rmax[reg] * SC2);
                    float alpha = exp2f(mreg[reg] - mnew);
                    mreg[reg] = mnew;
                    lreg[reg] *= alpha;
#pragma unroll
                    for (int nb = 0; nb < 8; ++nb) acc[nb][reg] *= alpha;
                }
            }

#pragma unroll
            for (int reg = 0; reg < 4; ++reg) {
                float p0 = exp2f(fmaf(sc[0][reg], SC2, -mreg[reg]));
                float p1 = exp2f(fmaf(sc[1][reg], SC2, -mreg[reg]));
                float p2 = exp2f(fmaf(sc[2][reg], SC2, -mreg[reg]));
                float p3 = exp2f(fmaf(sc[3][reg], SC2, -mreg[reg]));
                sc[0][reg] = p0; sc[1][reg] = p1; sc[2][reg] = p2; sc[3][reg] = p3;
                lreg[reg] += (p0 + p1) + (p2 + p3);
            }

#pragma unroll
            for (int nb = 0; nb < 4; ++nb)
#pragma unroll
                for (int reg = 0; reg < 4; ++reg)
                    P[w][4 * g + reg][nb * 16 + c16] = f2bf(sc[nb][reg]);

            __builtin_amdgcn_s_setprio(1);
#pragma unroll
            for (int ks = 0; ks < 2; ++ks) {
                bf16x8 pf = *(const bf16x8*)&P[w][c16][ks * 32 + g8];
#pragma unroll
                for (int nb = 0; nb < 8; ++nb) {
                    int row = nb * 16 + c16;
                    bf16x8 vf = *(const bf16x8*)&Vs[cur][row * 64 + (((g + 4 * ks) ^ (row & 7)) << 3)];
                    acc[nb] = __builtin_amdgcn_mfma_f32_16x16x32_bf16(pf, vf, acc[nb], 0, 0, 0);
                }
            }
            __builtin_amdgcn_s_setprio(0);

            __syncthreads();
            cur ^= 1;
        }

#pragma unroll
        for (int m = 1; m < 16; m <<= 1)
#pragma unroll
            for (int reg = 0; reg < 4; ++reg)
                lreg[reg] += __shfl_xor(lreg[reg], m);
        float inv[4];
#pragma unroll
        for (int reg = 0; reg < 4; ++reg) inv[reg] = 1.f / lreg[reg];
#pragma unroll
        for (int nb = 0; nb < 8; ++nb)
#pragma unroll
            for (int reg = 0; reg < 4; ++reg)
                attno[((size_t)(b * 2048 + qrow + 4 * g + reg) * 16 + h) * 128 + nb * 16 + c16] =
                    f2bf(acc[nb][reg] * inv[reg]);
    }
#undef STAGE
}

// ---------------------------------------------------------------------------
extern "C" void kernel_launch(void* const* d_in, const int* in_sizes, int n_in,
                              void* d_out, int out_size, void* d_ws, size_t ws_size,
                              hipStream_t stream) {
    const float* hidden = (const float*)d_in[0];
    const float* cosT   = (const float*)d_in[1];
    const float* sinT   = (const float*)d_in[2];
    const int*   pid    = (const int*)d_in[3];
    const float* Wq     = (const float*)d_in[4];
    const float* Wkv_a  = (const float*)d_in[5];
    const float* ln_g   = (const float*)d_in[6];
    const float* ln_b   = (const float*)d_in[7];
    const float* Wkv_b  = (const float*)d_in[8];
    const float* Wo     = (const float*)d_in[9];
    float* out = (float*)d_out;

    char* p = (char*)d_ws;
    short* hid_bf = (short*)p;               p += (size_t)NTOK * 2048 * 2;
    short* WqkaT  = (short*)p;               p += (size_t)3840 * 2048 * 2;  // WqT | WkaT | zero pad
    short* WkbT   = (short*)p;               p += (size_t)4096 * 512 * 2;
    short* WoT    = (short*)p;               p += (size_t)2048 * 2048 * 2;
    char*  big    = p;                       p += (size_t)NTOK * 3072 * 4;
    short* qbuf   = (short*)p;               p += (size_t)NTOK * 3072 * 2;
    short* kvcn   = (short*)p;               p += (size_t)NTOK * 512 * 2;
    short* kpe    = (short*)p;               p += (size_t)NTOK * 64 * 2;
    short* kvb    = (short*)p;               p += (size_t)NTOK * 4096 * 2;

    float* ckv   = (float*)big;
    short* Vt    = (short*)(big + (size_t)NTOK * 640 * 4);
    short* attno = (short*)(big + (size_t)NTOK * 640 * 4 + (size_t)2 * 16 * 128 * 2048 * 2);

    castk<<<8192, 256, 0, stream>>>(hidden, hid_bf);
    transpose_cast<<<dim3(96, 64), 256, 0, stream>>>(Wq, WqkaT, 2048, 3072);
    // covers rows 3072..3839 (incl. zero pad 3712..3839)
    transpose_cast<<<dim3(24, 64), 256, 0, stream>>>(Wkv_a, WqkaT + (size_t)3072 * 2048, 2048, 576);
    transpose_cast<<<dim3(128, 16), 256, 0, stream>>>(Wkv_b, WkbT, 512, 4096);
    transpose_cast<<<dim3(64, 64), 256, 0, stream>>>(Wo, WoT, 2048, 2048);

    // 1+3 fused 8-phase GEMM: q -> qbuf bf16, ckv -> f32 s640 (N=3840 incl pad)
    gemm8<1><<<240, 512, 0, stream>>>(hid_bf, WqkaT, qbuf, ckv, 3840, 2048, 15);
    // 2. RoPE in place on q_pe (bf16)
    rope_q_ip<<<(NTOK * H_ * 32) / 256, 256, 0, stream>>>(qbuf, cosT, sinT, pid);
    // 4. LayerNorm + RoPE(k_pe) -> bf16
    ln_rope<<<NTOK, 256, 0, stream>>>(ckv, ln_g, ln_b, cosT, sinT, pid, kvcn, kpe);
    // 5. kv = kvcn @ Wkv_b (bf16 out), 8-phase
    gemm8<0><<<256, 512, 0, stream>>>(kvcn, WkbT, kvb, nullptr, 4096, 512, 16);
    // 6. V transpose
    transpose_v<<<dim3(32, 2, 32), 256, 0, stream>>>(kvb, Vt);
    // 7. flash attention
    flash_mfma<<<512, 256, 0, stream>>>(qbuf, kvb, kpe, Vt, attno);
    // 8. out = attno @ Wo (f32 out), old 128^2 kernel (512 blocks)
    gemm_mfma<0><<<dim3(16, 32), 256, 0, stream>>>(attno, WoT, out, 4096, 2048, 2048);
}

// Round 11
// 297.430 us; speedup vs baseline: 1.7920x; 1.0363x over previous
//
#include <hip/hip_runtime.h>
#include <math.h>
#include <stdint.h>

#define B_      2
#define S_      2048
#define HID_    2048
#define H_      16
#define D_NOPE_ 128
#define D_ROPE_ 64
#define D_V_    128
#define R_      512
#define D_Q_    192
#define NTOK    (B_ * S_)
#define EPS_    1e-6f

typedef __attribute__((ext_vector_type(8))) short bf16x8;
typedef __attribute__((ext_vector_type(4))) float f32x4;

__device__ __forceinline__ short f2bf(float x) {
    union { float f; unsigned u; } un; un.f = x;
    unsigned r = (un.u + 0x7fffu + ((un.u >> 16) & 1u)) >> 16;
    return (short)r;
}
__device__ __forceinline__ float bf2f(short s) {
    union { unsigned u; float f; } un;
    un.u = ((unsigned)(unsigned short)s) << 16;
    return un.f;
}

__device__ __forceinline__ void async_ld16(const short* gsrc, short* ldst) {
    __builtin_amdgcn_global_load_lds(
        (const __attribute__((address_space(1))) void*)gsrc,
        (__attribute__((address_space(3))) void*)ldst, 16, 0, 0);
}

#define BARX() { __builtin_amdgcn_sched_barrier(0); __builtin_amdgcn_s_barrier(); __builtin_amdgcn_sched_barrier(0); }

// ---------------------------------------------------------------------------
// cast f32 -> bf16
// ---------------------------------------------------------------------------
__global__ __launch_bounds__(256) void castk(const float* __restrict__ in, short* __restrict__ out) {
    int i = blockIdx.x * 256 + threadIdx.x;
    float4 v = ((const float4*)in)[i];
    ushort4 o;
    o.x = (unsigned short)f2bf(v.x); o.y = (unsigned short)f2bf(v.y);
    o.z = (unsigned short)f2bf(v.z); o.w = (unsigned short)f2bf(v.w);
    ((ushort4*)out)[i] = o;
}

// ---------------------------------------------------------------------------
// W[K][Nreal] f32 -> WT[Npad][K] bf16 (rows >= Nreal zero-filled).
// ---------------------------------------------------------------------------
__global__ __launch_bounds__(256) void transpose_cast(const float* __restrict__ W,
                                                      short* __restrict__ WT,
                                                      int K, int Nreal) {
    __shared__ float T[32][33];
    const int n0 = blockIdx.x * 32, k0 = blockIdx.y * 32;
    const int t = threadIdx.x;
    const int r = t >> 3, c4 = (t & 7) * 4;
    float4 v = make_float4(0.f, 0.f, 0.f, 0.f);
    if (n0 < Nreal) v = *(const float4*)&W[(size_t)(k0 + r) * Nreal + n0 + c4];
    T[r][c4 + 0] = v.x; T[r][c4 + 1] = v.y; T[r][c4 + 2] = v.z; T[r][c4 + 3] = v.w;
    __syncthreads();
    const int n = t >> 3, k4 = (t & 7) * 4;
    ushort4 o;
    o.x = (unsigned short)f2bf(T[k4 + 0][n]);
    o.y = (unsigned short)f2bf(T[k4 + 1][n]);
    o.z = (unsigned short)f2bf(T[k4 + 2][n]);
    o.w = (unsigned short)f2bf(T[k4 + 3][n]);
    *(ushort4*)&WT[(size_t)(n0 + n) * K + k0 + k4] = o;
}

// ---------------------------------------------------------------------------
// 256x256 8-phase GEMM (T3+T4+T5). 512 threads = 8 waves (2M x 4N).
// BK=64 as 2x [256][32] sub-buffers per operand, double-buffered: LDS 128KB.
// Counted vmcnt(4) at P2/P4 keeps loads in flight across barriers.
// QA=1: dual epilogue (cols<3072 -> qbuf bf16 s3072; 3072..3711 -> ckv f32
// s640; >=3712 pad, dropped). QA=0: bf16 C with stride N.
// ---------------------------------------------------------------------------
template <int QA>
__global__ __launch_bounds__(512) void gemm8(const short* __restrict__ A,
                                             const short* __restrict__ BT,
                                             void* __restrict__ C0,
                                             float* __restrict__ C1,
                                             int N, int K, int nbx) {
    __shared__ short LB[2][4][8192];   // [buf][A0,A1,B0,B1][256 rows x 32]

    const int tid = threadIdx.x, lane = tid & 63, w = tid >> 6;
    const int c16 = lane & 15, g = lane >> 4;
    const int wr = w >> 2, wc = w & 3;
    const int qph = (g ^ ((c16 >> 1) & 3)) * 8;

    // XCD-chunked bijective swizzle (nwg % 8 == 0 at both call sites)
    const int nwg = gridDim.x;
    const int swz = (blockIdx.x & 7) * (nwg >> 3) + (blockIdx.x >> 3);
    const int brow = (swz / nbx) * 256, bcol = (swz % nbx) * 256;

    const int o0 = w * 1024 + lane * 16;
    const int o1 = o0 + 8192;
    const int r0 = o0 >> 6, lc0 = ((o0 >> 4) & 3) ^ ((r0 >> 1) & 3);
    const int r1 = o1 >> 6, lc1 = ((o1 >> 4) & 3) ^ ((r1 >> 1) & 3);
    const short* aS0 = A + (size_t)(brow + r0) * K + lc0 * 8;
    const short* aS1 = A + (size_t)(brow + r1) * K + lc1 * 8;
    const short* bS0 = BT + (size_t)(bcol + r0) * K + lc0 * 8;
    const short* bS1 = BT + (size_t)(bcol + r1) * K + lc1 * 8;
    const int d0 = w * 512, d1 = 4096 + w * 512;

    f32x4 zero = {0.f, 0.f, 0.f, 0.f};
    f32x4 acc[8][4];
#pragma unroll
    for (int i = 0; i < 8; ++i)
#pragma unroll
        for (int j = 0; j < 4; ++j) acc[i][j] = zero;

    const int NT = K >> 6;
    async_ld16(aS0,      &LB[0][0][d0]);  async_ld16(aS1,      &LB[0][0][d1]);
    async_ld16(aS0 + 32, &LB[0][1][d0]);  async_ld16(aS1 + 32, &LB[0][1][d1]);
    async_ld16(bS0,      &LB[0][2][d0]);  async_ld16(bS1,      &LB[0][2][d1]);
    async_ld16(bS0 + 32, &LB[0][3][d0]);  async_ld16(bS1 + 32, &LB[0][3][d1]);
    asm volatile("s_waitcnt vmcnt(0)" ::: "memory");
    BARX();

    int cur = 0;
    const int arb = wr * 128, brb = wc * 64;
    for (int kt = 0; kt < NT; ++kt) {
        const bool stg = (kt + 1 < NT);
        const int ko = (kt + 1) * 64;
        short (*CB)[8192] = LB[cur];
        short (*NB)[8192] = LB[cur ^ 1];
        bf16x8 af[4], bf[4];

#pragma unroll
        for (int ni = 0; ni < 4; ++ni)
            bf[ni] = *(const bf16x8*)&CB[2][(brb + ni * 16 + c16) * 32 + qph];
#pragma unroll
        for (int mi = 0; mi < 4; ++mi)
            af[mi] = *(const bf16x8*)&CB[0][(arb + mi * 16 + c16) * 32 + qph];
        if (stg) { async_ld16(aS0 + ko, &NB[0][d0]); async_ld16(aS1 + ko, &NB[0][d1]); }
        BARX();
        __builtin_amdgcn_s_setprio(1);
#pragma unroll
        for (int mi = 0; mi < 4; ++mi)
#pragma unroll
            for (int ni = 0; ni < 4; ++ni)
                acc[mi][ni] = __builtin_amdgcn_mfma_f32_16x16x32_bf16(af[mi], bf[ni], acc[mi][ni], 0, 0, 0);
        __builtin_amdgcn_s_setprio(0);
        BARX();

#pragma unroll
        for (int mi = 0; mi < 4; ++mi)
            af[mi] = *(const bf16x8*)&CB[0][(arb + 64 + mi * 16 + c16) * 32 + qph];
        if (stg) {
            async_ld16(bS0 + ko, &NB[2][d0]); async_ld16(bS1 + ko, &NB[2][d1]);
            asm volatile("s_waitcnt vmcnt(4)" ::: "memory");
        } else {
            asm volatile("s_waitcnt vmcnt(0)" ::: "memory");
        }
        BARX();
        __builtin_amdgcn_s_setprio(1);
#pragma unroll
        for (int mi = 0; mi < 4; ++mi)
#pragma unroll
            for (int ni = 0; ni < 4; ++ni)
                acc[4 + mi][ni] = __builtin_amdgcn_mfma_f32_16x16x32_bf16(af[mi], bf[ni], acc[4 + mi][ni], 0, 0, 0);
        __builtin_amdgcn_s_setprio(0);
        BARX();

#pragma unroll
        for (int ni = 0; ni < 4; ++ni)
            bf[ni] = *(const bf16x8*)&CB[3][(brb + ni * 16 + c16) * 32 + qph];
#pragma unroll
        for (int mi = 0; mi < 4; ++mi)
            af[mi] = *(const bf16x8*)&CB[1][(arb + mi * 16 + c16) * 32 + qph];
        if (stg) { async_ld16(aS0 + ko + 32, &NB[1][d0]); async_ld16(aS1 + ko + 32, &NB[1][d1]); }
        BARX();
        __builtin_amdgcn_s_setprio(1);
#pragma unroll
        for (int mi = 0; mi < 4; ++mi)
#pragma unroll
            for (int ni = 0; ni < 4; ++ni)
                acc[mi][ni] = __builtin_amdgcn_mfma_f32_16x16x32_bf16(af[mi], bf[ni], acc[mi][ni], 0, 0, 0);
        __builtin_amdgcn_s_setprio(0);
        BARX();

#pragma unroll
        for (int mi = 0; mi < 4; ++mi)
            af[mi] = *(const bf16x8*)&CB[1][(arb + 64 + mi * 16 + c16) * 32 + qph];
        if (stg) {
            async_ld16(bS0 + ko + 32, &NB[3][d0]); async_ld16(bS1 + ko + 32, &NB[3][d1]);
            asm volatile("s_waitcnt vmcnt(4)" ::: "memory");
        }
        BARX();
        __builtin_amdgcn_s_setprio(1);
#pragma unroll
        for (int mi = 0; mi < 4; ++mi)
#pragma unroll
            for (int ni = 0; ni < 4; ++ni)
                acc[4 + mi][ni] = __builtin_amdgcn_mfma_f32_16x16x32_bf16(af[mi], bf[ni], acc[4 + mi][ni], 0, 0, 0);
        __builtin_amdgcn_s_setprio(0);
        BARX();

        cur ^= 1;
    }

    if (QA) {
        const int wcol = bcol + wc * 64;
        if (wcol < 3072) {
            short* qb = (short*)C0;
#pragma unroll
            for (int mi = 0; mi < 8; ++mi)
#pragma unroll
                for (int ni = 0; ni < 4; ++ni)
#pragma unroll
                    for (int reg = 0; reg < 4; ++reg) {
                        int row = brow + wr * 128 + mi * 16 + 4 * g + reg;
                        int col = wcol + ni * 16 + c16;
                        qb[(size_t)row * 3072 + col] = f2bf(acc[mi][ni][reg]);
                    }
        } else if (wcol < 3712) {
#pragma unroll
            for (int mi = 0; mi < 8; ++mi)
#pragma unroll
                for (int ni = 0; ni < 4; ++ni)
#pragma unroll
                    for (int reg = 0; reg < 4; ++reg) {
                        int row = brow + wr * 128 + mi * 16 + 4 * g + reg;
                        int col = wcol - 3072 + ni * 16 + c16;
                        C1[(size_t)row * 640 + col] = acc[mi][ni][reg];
                    }
        }
    } else {
        short* cc = (short*)C0;
#pragma unroll
        for (int mi = 0; mi < 8; ++mi)
#pragma unroll
            for (int ni = 0; ni < 4; ++ni)
#pragma unroll
                for (int reg = 0; reg < 4; ++reg) {
                    int row = brow + wr * 128 + mi * 16 + 4 * g + reg;
                    int col = bcol + wc * 64 + ni * 16 + c16;
                    cc[(size_t)row * N + col] = f2bf(acc[mi][ni][reg]);
                }
    }
}

// ---------------------------------------------------------------------------
// 128x256 counted-vmcnt GEMM for gemm_out (M=4096, N=2048 -> 256 blocks).
// 512 threads = 8 waves (2M x 4N), wave tile 64x64, acc[4][4]. BK=64 as
// 2 ksubs of 32; 2 phases/K-tile x {8 ds_read; stage A(1)+B(2); vmcnt(3);
// barrier; setprio; 16 MFMA; barrier}. Ledger: at each vmcnt 6 loads
// outstanding, oldest 3 = the sub-buffers read next phase. f32 output.
// K-accumulation order identical to the 128^2 kernel (bit-identical C).
// ---------------------------------------------------------------------------
__global__ __launch_bounds__(512) void gemm8n(const short* __restrict__ A,
                                              const short* __restrict__ BT,
                                              float* __restrict__ C,
                                              int N, int K, int nbx) {
    __shared__ short LA[2][2][4096];   // [buf][ksub][128 rows x 32]
    __shared__ short LBt[2][2][8192];  // [buf][ksub][256 rows x 32]

    const int tid = threadIdx.x, lane = tid & 63, w = tid >> 6;
    const int c16 = lane & 15, g = lane >> 4;
    const int wr = w >> 2, wc = w & 3;
    const int qph = (g ^ ((c16 >> 1) & 3)) * 8;

    const int nwg = gridDim.x;   // % 8 == 0
    const int swz = (blockIdx.x & 7) * (nwg >> 3) + (blockIdx.x >> 3);
    const int brow = (swz / nbx) * 128, bcol = (swz % nbx) * 256;

    // A staging: 1 load/thread covers the 8KB sub
    const int oA = tid * 16;
    const int rA = oA >> 6, lcA = ((oA >> 4) & 3) ^ ((rA >> 1) & 3);
    const short* aS = A + (size_t)(brow + rA) * K + lcA * 8;
    const int dA = oA >> 1;

    // B staging: 2 loads/thread cover the 16KB sub
    const int o0 = w * 1024 + lane * 16, o1 = o0 + 8192;
    const int r0 = o0 >> 6, lc0 = ((o0 >> 4) & 3) ^ ((r0 >> 1) & 3);
    const int r1 = o1 >> 6, lc1 = ((o1 >> 4) & 3) ^ ((r1 >> 1) & 3);
    const short* bS0 = BT + (size_t)(bcol + r0) * K + lc0 * 8;
    const short* bS1 = BT + (size_t)(bcol + r1) * K + lc1 * 8;
    const int d0 = o0 >> 1, d1 = o1 >> 1;

    f32x4 zero = {0.f, 0.f, 0.f, 0.f};
    f32x4 acc[4][4];
#pragma unroll
    for (int i = 0; i < 4; ++i)
#pragma unroll
        for (int j = 0; j < 4; ++j) acc[i][j] = zero;

    const int NT = K >> 6;
    // prologue: full tile 0
    async_ld16(aS,      &LA[0][0][dA]);
    async_ld16(aS + 32, &LA[0][1][dA]);
    async_ld16(bS0,      &LBt[0][0][d0]); async_ld16(bS1,      &LBt[0][0][d1]);
    async_ld16(bS0 + 32, &LBt[0][1][d0]); async_ld16(bS1 + 32, &LBt[0][1][d1]);
    asm volatile("s_waitcnt vmcnt(0)" ::: "memory");
    BARX();

    int cur = 0;
    const int arb = wr * 64, brb = wc * 64;
    for (int kt = 0; kt < NT; ++kt) {
        const bool stg = (kt + 1 < NT);
        const int ko = (kt + 1) * 64;
        bf16x8 af[4], bf[4];

        // ---- P1: ksub0 ----
#pragma unroll
        for (int mi = 0; mi < 4; ++mi)
            af[mi] = *(const bf16x8*)&LA[cur][0][(arb + mi * 16 + c16) * 32 + qph];
#pragma unroll
        for (int ni = 0; ni < 4; ++ni)
            bf[ni] = *(const bf16x8*)&LBt[cur][0][(brb + ni * 16 + c16) * 32 + qph];
        if (stg) {
            async_ld16(aS + ko, &LA[cur ^ 1][0][dA]);
            async_ld16(bS0 + ko, &LBt[cur ^ 1][0][d0]);
            async_ld16(bS1 + ko, &LBt[cur ^ 1][0][d1]);
            asm volatile("s_waitcnt vmcnt(3)" ::: "memory");
        } else {
            asm volatile("s_waitcnt vmcnt(0)" ::: "memory");
        }
        BARX();
        __builtin_amdgcn_s_setprio(1);
#pragma unroll
        for (int mi = 0; mi < 4; ++mi)
#pragma unroll
            for (int ni = 0; ni < 4; ++ni)
                acc[mi][ni] = __builtin_amdgcn_mfma_f32_16x16x32_bf16(af[mi], bf[ni], acc[mi][ni], 0, 0, 0);
        __builtin_amdgcn_s_setprio(0);
        BARX();

        // ---- P2: ksub1 ----
#pragma unroll
        for (int mi = 0; mi < 4; ++mi)
            af[mi] = *(const bf16x8*)&LA[cur][1][(arb + mi * 16 + c16) * 32 + qph];
#pragma unroll
        for (int ni = 0; ni < 4; ++ni)
            bf[ni] = *(const bf16x8*)&LBt[cur][1][(brb + ni * 16 + c16) * 32 + qph];
        if (stg) {
            async_ld16(aS + ko + 32, &LA[cur ^ 1][1][dA]);
            async_ld16(bS0 + ko + 32, &LBt[cur ^ 1][1][d0]);
            async_ld16(bS1 + ko + 32, &LBt[cur ^ 1][1][d1]);
            asm volatile("s_waitcnt vmcnt(3)" ::: "memory");
        }
        BARX();
        __builtin_amdgcn_s_setprio(1);
#pragma unroll
        for (int mi = 0; mi < 4; ++mi)
#pragma unroll
            for (int ni = 0; ni < 4; ++ni)
                acc[mi][ni] = __builtin_amdgcn_mfma_f32_16x16x32_bf16(af[mi], bf[ni], acc[mi][ni], 0, 0, 0);
        __builtin_amdgcn_s_setprio(0);
        BARX();

        cur ^= 1;
    }

#pragma unroll
    for (int mi = 0; mi < 4; ++mi)
#pragma unroll
        for (int ni = 0; ni < 4; ++ni)
#pragma unroll
            for (int reg = 0; reg < 4; ++reg) {
                int row = brow + wr * 64 + mi * 16 + 4 * g + reg;
                int col = bcol + wc * 64 + ni * 16 + c16;
                C[(size_t)row * N + col] = acc[mi][ni][reg];
            }
}

// ---------------------------------------------------------------------------
// In-place RoPE on q_pe region of bf16 q.
// ---------------------------------------------------------------------------
__global__ __launch_bounds__(256) void rope_q_ip(short* __restrict__ qb,
                                                 const float* __restrict__ cosT,
                                                 const float* __restrict__ sinT,
                                                 const int* __restrict__ pid) {
    int gidx = blockIdx.x * 256 + threadIdx.x;
    int i = gidx & 31;
    int h = (gidx >> 5) & (H_ - 1);
    int tok = gidx >> 9;
    int pos = pid[tok];
    float c = cosT[pos * 32 + i];
    float s = sinT[pos * 32 + i];
    short* base = qb + (size_t)tok * (H_ * D_Q_) + h * D_Q_ + D_NOPE_;
    float x1 = bf2f(base[i]);
    float x2 = bf2f(base[i + 32]);
    base[i]      = f2bf(x1 * c - x2 * s);
    base[i + 32] = f2bf(x2 * c + x1 * s);
}

// ---------------------------------------------------------------------------
// LayerNorm(512) + RoPE(k_pe). ckv stride 640. Outputs bf16.
// ---------------------------------------------------------------------------
__global__ __launch_bounds__(256) void ln_rope(const float* __restrict__ ckv,
                                               const float* __restrict__ gam,
                                               const float* __restrict__ bet,
                                               const float* __restrict__ cosT,
                                               const float* __restrict__ sinT,
                                               const int* __restrict__ pid,
                                               short* __restrict__ kvcn,
                                               short* __restrict__ kpe) {
    const int tok = blockIdx.x, tid = threadIdx.x;
    const float* x = ckv + (size_t)tok * 640;
    float v0 = x[tid], v1 = x[tid + 256];
    float s = v0 + v1, sq = v0 * v0 + v1 * v1;
#pragma unroll
    for (int m = 1; m < 64; m <<= 1) { s += __shfl_xor(s, m); sq += __shfl_xor(sq, m); }
    __shared__ float ws[8];
    int wid = tid >> 6, lane = tid & 63;
    if (lane == 0) { ws[wid] = s; ws[4 + wid] = sq; }
    __syncthreads();
    s = ws[0] + ws[1] + ws[2] + ws[3];
    sq = ws[4] + ws[5] + ws[6] + ws[7];
    float mean = s * (1.f / 512.f);
    float var = sq * (1.f / 512.f) - mean * mean;
    float rstd = rsqrtf(var + EPS_);
    kvcn[(size_t)tok * 512 + tid]       = f2bf((v0 - mean) * rstd * gam[tid] + bet[tid]);
    kvcn[(size_t)tok * 512 + tid + 256] = f2bf((v1 - mean) * rstd * gam[tid + 256] + bet[tid + 256]);
    if (tid < 32) {
        int pos = pid[tok];
        float c = cosT[pos * 32 + tid], sn = sinT[pos * 32 + tid];
        float x1 = x[512 + tid], x2 = x[512 + 32 + tid];
        kpe[(size_t)tok * 64 + tid]      = f2bf(x1 * c - x2 * sn);
        kpe[(size_t)tok * 64 + 32 + tid] = f2bf(x2 * c + x1 * sn);
    }
}

// ---------------------------------------------------------------------------
// V transpose: kvb[token][h][128..255] -> Vt[b][h][d][s].
// ---------------------------------------------------------------------------
__global__ __launch_bounds__(256) void transpose_v(const short* __restrict__ kvb,
                                                   short* __restrict__ Vt) {
    __shared__ short T[64][72];
    const int s0 = blockIdx.x * 64, d0 = blockIdx.y * 64, bh = blockIdx.z;
    const int b = bh >> 4, h = bh & 15;
    const int t = threadIdx.x;
    const int r = t >> 3, c8 = (t & 7) * 8;
#pragma unroll
    for (int i = 0; i < 2; ++i) {
        int rr = r + 32 * i;
        bf16x8 v = *(const bf16x8*)&kvb[((size_t)(b * 2048 + s0 + rr) * 16 + h) * 256 + 128 + d0 + c8];
        *(bf16x8*)&T[rr][c8] = v;
    }
    __syncthreads();
#pragma unroll
    for (int i = 0; i < 2; ++i) {
        int d = r + 32 * i;
        bf16x8 o;
#pragma unroll
        for (int j = 0; j < 8; ++j) o[j] = T[c8 + j][d];
        *(bf16x8*)&Vt[((size_t)(b * 16 + h) * 128 + d0 + d) * 2048 + s0 + c8] = o;
    }
}

// ---------------------------------------------------------------------------
// MFMA flash attention (R8/R9 structure, unchanged math).
// ---------------------------------------------------------------------------
__global__ __launch_bounds__(256) void flash_mfma(const short* __restrict__ qb,
                                                  const short* __restrict__ kvb,
                                                  const short* __restrict__ kpe,
                                                  const short* __restrict__ Vt,
                                                  short* __restrict__ attno) {
    __shared__ short Ks[2][64 * 128];
    __shared__ short Vs[2][128 * 64];
    __shared__ short P[4][16][72];

    const int flat = blockIdx.x;              // 0..511
    const int xcd = flat & 7, idx = flat >> 3;
    const int bh = xcd + 8 * (idx >> 4);
    const int pair = idx & 15;
    const int b = bh >> 4, h = bh & 15;

    const int tid = threadIdx.x, lane = tid & 63, w = tid >> 6;
    const int c16 = lane & 15, g = lane >> 4, g8 = g * 8;
    const float SC2 = 0.10412063f;   // 1/sqrt(192) * log2(e)

    const int o = w * 1024 + lane * 16;
    const int rK = o >> 8, ccK = ((o >> 4) & 15) ^ (rK & 7);
    const int rV = o >> 7, ccV = ((o >> 4) & 7) ^ (rV & 7);
    const short* kB0  = kvb + ((size_t)((b * 2048 + rK) * 16 + h)) * 256 + ccK * 8;
    const short* vB0  = Vt + ((size_t)((b * 16 + h) * 128 + rV)) * 2048 + ccV * 8;
    const short* peB0 = kpe + (size_t)(b * 2048 + c16) * 64 + g8;

    f32x4 zero = {0.f, 0.f, 0.f, 0.f};

#define STAGE(BUF)                                                                  \
    {                                                                               \
        _Pragma("unroll")                                                           \
        for (int rnd = 0; rnd < 4; ++rnd)                                           \
            async_ld16(kRun + (size_t)rnd * 65536,                                  \
                       &Ks[BUF][(rnd * 4096 + w * 1024) >> 1]);                     \
        _Pragma("unroll")                                                           \
        for (int rnd = 0; rnd < 4; ++rnd)                                           \
            async_ld16(vRun + (size_t)rnd * 65536,                                  \
                       &Vs[BUF][(rnd * 4096 + w * 1024) >> 1]);                     \
        kRun += 64 * 4096;                                                          \
        vRun += 64;                                                                 \
    }

    for (int half = 0; half < 2; ++half) {
        const int qt = half ? (31 - pair) : pair;
        const int q0 = qt * 64;
        const int qrow = q0 + w * 16;

        const size_t qbase = ((size_t)(b * 2048 + qrow + c16) * 16 + h) * 192 + g8;
        bf16x8 qf[6];
#pragma unroll
        for (int ks = 0; ks < 6; ++ks) qf[ks] = *(const bf16x8*)(qb + qbase + 32 * ks);

        f32x4 acc[8];
#pragma unroll
        for (int i = 0; i < 8; ++i) acc[i] = zero;
        float mreg[4] = {-INFINITY, -INFINITY, -INFINITY, -INFINITY};
        float lreg[4] = {0.f, 0.f, 0.f, 0.f};

        const short* kRun = kB0;
        const short* vRun = vB0;
        const short* peRun = peB0;

        const int nt = qt + 1;
        STAGE(0);
        __syncthreads();
        int cur = 0;

        for (int kt = 0; kt < nt; ++kt) {
            if (kt + 1 < nt) STAGE(cur ^ 1);

            f32x4 sc[4];
#pragma unroll
            for (int i = 0; i < 4; ++i) sc[i] = zero;

            __builtin_amdgcn_s_setprio(1);
#pragma unroll
            for (int ks = 0; ks < 4; ++ks)
#pragma unroll
                for (int nb = 0; nb < 4; ++nb) {
                    int row = nb * 16 + c16;
                    bf16x8 kf = *(const bf16x8*)&Ks[cur][row * 128 + (((g + 4 * ks) ^ (row & 7)) << 3)];
                    sc[nb] = __builtin_amdgcn_mfma_f32_16x16x32_bf16(qf[ks], kf, sc[nb], 0, 0, 0);
                }
#pragma unroll
            for (int ks = 0; ks < 2; ++ks)
#pragma unroll
                for (int nb = 0; nb < 4; ++nb) {
                    bf16x8 kf = *(const bf16x8*)(peRun + (size_t)nb * 16 * 64 + ks * 32);
                    sc[nb] = __builtin_amdgcn_mfma_f32_16x16x32_bf16(qf[4 + ks], kf, sc[nb], 0, 0, 0);
                }
            __builtin_amdgcn_s_setprio(0);
            peRun += 64 * 64;

            if (kt == nt - 1) {
#pragma unroll
                for (int nb = 0; nb < 4; ++nb)
#pragma unroll
                    for (int reg = 0; reg < 4; ++reg) {
                        int col = (nt - 1) * 64 + nb * 16 + c16;
                        int row = qrow + 4 * g + reg;
                        if (col > row) sc[nb][reg] = -INFINITY;
                    }
            }

            float rmax[4];
#pragma unroll
            for (int reg = 0; reg < 4; ++reg)
                rmax[reg] = fmaxf(fmaxf(sc[0][reg], sc[1][reg]), fmaxf(sc[2][reg], sc[3][reg]));
#pragma unroll
            for (int m = 1; m < 16; m <<= 1)
#pragma unroll
                for (int reg = 0; reg < 4; ++reg)
                    rmax[reg] = fmaxf(rmax[reg], __shfl_xor(rmax[reg], m));

            float grow = rmax[0] * SC2 - mreg[0];
#pragma unroll
            for (int reg = 1; reg < 4; ++reg) grow = fmaxf(grow, rmax[reg] * SC2 - mreg[reg]);
            if (__any(grow > 8.f)) {
#pragma unroll
                for (int reg = 0; reg < 4; ++reg) {
                    float mnew = fmaxf(mreg[reg], rmax[reg] * SC2);
                    float alpha = exp2f(mreg[reg] - mnew);
                    mreg[reg] = mnew;
                    lreg[reg] *= alpha;
#pragma unroll
                    for (int nb = 0; nb < 8; ++nb) acc[nb][reg] *= alpha;
                }
            }

#pragma unroll
            for (int reg = 0; reg < 4; ++reg) {
                float p0 = exp2f(fmaf(sc[0][reg], SC2, -mreg[reg]));
                float p1 = exp2f(fmaf(sc[1][reg], SC2, -mreg[reg]));
                float p2 = exp2f(fmaf(sc[2][reg], SC2, -mreg[reg]));
                float p3 = exp2f(fmaf(sc[3][reg], SC2, -mreg[reg]));
                sc[0][reg] = p0; sc[1][reg] = p1; sc[2][reg] = p2; sc[3][reg] = p3;
                lreg[reg] += (p0 + p1) + (p2 + p3);
            }

#pragma unroll
            for (int nb = 0; nb < 4; ++nb)
#pragma unroll
                for (int reg = 0; reg < 4; ++reg)
                    P[w][4 * g + reg][nb * 16 + c16] = f2bf(sc[nb][reg]);

            __builtin_amdgcn_s_setprio(1);
#pragma unroll
            for (int ks = 0; ks < 2; ++ks) {
                bf16x8 pf = *(const bf16x8*)&P[w][c16][ks * 32 + g8];
#pragma unroll
                for (int nb = 0; nb < 8; ++nb) {
                    int row = nb * 16 + c16;
                    bf16x8 vf = *(const bf16x8*)&Vs[cur][row * 64 + (((g + 4 * ks) ^ (row & 7)) << 3)];
                    acc[nb] = __builtin_amdgcn_mfma_f32_16x16x32_bf16(pf, vf, acc[nb], 0, 0, 0);
                }
            }
            __builtin_amdgcn_s_setprio(0);

            __syncthreads();
            cur ^= 1;
        }

#pragma unroll
        for (int m = 1; m < 16; m <<= 1)
#pragma unroll
            for (int reg = 0; reg < 4; ++reg)
                lreg[reg] += __shfl_xor(lreg[reg], m);
        float inv[4];
#pragma unroll
        for (int reg = 0; reg < 4; ++reg) inv[reg] = 1.f / lreg[reg];
#pragma unroll
        for (int nb = 0; nb < 8; ++nb)
#pragma unroll
            for (int reg = 0; reg < 4; ++reg)
                attno[((size_t)(b * 2048 + qrow + 4 * g + reg) * 16 + h) * 128 + nb * 16 + c16] =
                    f2bf(acc[nb][reg] * inv[reg]);
    }
#undef STAGE
}

// ---------------------------------------------------------------------------
extern "C" void kernel_launch(void* const* d_in, const int* in_sizes, int n_in,
                              void* d_out, int out_size, void* d_ws, size_t ws_size,
                              hipStream_t stream) {
    const float* hidden = (const float*)d_in[0];
    const float* cosT   = (const float*)d_in[1];
    const float* sinT   = (const float*)d_in[2];
    const int*   pid    = (const int*)d_in[3];
    const float* Wq     = (const float*)d_in[4];
    const float* Wkv_a  = (const float*)d_in[5];
    const float* ln_g   = (const float*)d_in[6];
    const float* ln_b   = (const float*)d_in[7];
    const float* Wkv_b  = (const float*)d_in[8];
    const float* Wo     = (const float*)d_in[9];
    float* out = (float*)d_out;

    char* p = (char*)d_ws;
    short* hid_bf = (short*)p;               p += (size_t)NTOK * 2048 * 2;
    short* WqkaT  = (short*)p;               p += (size_t)3840 * 2048 * 2;  // WqT | WkaT | zero pad
    short* WkbT   = (short*)p;               p += (size_t)4096 * 512 * 2;
    short* WoT    = (short*)p;               p += (size_t)2048 * 2048 * 2;
    char*  big    = p;                       p += (size_t)NTOK * 3072 * 4;
    short* qbuf   = (short*)p;               p += (size_t)NTOK * 3072 * 2;
    short* kvcn   = (short*)p;               p += (size_t)NTOK * 512 * 2;
    short* kpe    = (short*)p;               p += (size_t)NTOK * 64 * 2;
    short* kvb    = (short*)p;               p += (size_t)NTOK * 4096 * 2;

    float* ckv   = (float*)big;
    short* Vt    = (short*)(big + (size_t)NTOK * 640 * 4);
    short* attno = (short*)(big + (size_t)NTOK * 640 * 4 + (size_t)2 * 16 * 128 * 2048 * 2);

    castk<<<8192, 256, 0, stream>>>(hidden, hid_bf);
    transpose_cast<<<dim3(96, 64), 256, 0, stream>>>(Wq, WqkaT, 2048, 3072);
    transpose_cast<<<dim3(24, 64), 256, 0, stream>>>(Wkv_a, WqkaT + (size_t)3072 * 2048, 2048, 576);
    transpose_cast<<<dim3(128, 16), 256, 0, stream>>>(Wkv_b, WkbT, 512, 4096);
    transpose_cast<<<dim3(64, 64), 256, 0, stream>>>(Wo, WoT, 2048, 2048);

    // 1+3 fused 8-phase GEMM: q -> qbuf bf16, ckv -> f32 s640 (N=3840 incl pad)
    gemm8<1><<<240, 512, 0, stream>>>(hid_bf, WqkaT, qbuf, ckv, 3840, 2048, 15);
    // 2. RoPE in place on q_pe (bf16)
    rope_q_ip<<<(NTOK * H_ * 32) / 256, 256, 0, stream>>>(qbuf, cosT, sinT, pid);
    // 4. LayerNorm + RoPE(k_pe) -> bf16
    ln_rope<<<NTOK, 256, 0, stream>>>(ckv, ln_g, ln_b, cosT, sinT, pid, kvcn, kpe);
    // 5. kv = kvcn @ Wkv_b (bf16 out), 8-phase
    gemm8<0><<<256, 512, 0, stream>>>(kvcn, WkbT, kvb, nullptr, 4096, 512, 16);
    // 6. V transpose
    transpose_v<<<dim3(32, 2, 32), 256, 0, stream>>>(kvb, Vt);
    // 7. flash attention
    flash_mfma<<<512, 256, 0, stream>>>(qbuf, kvb, kpe, Vt, attno);
    // 8. out = attno @ Wo (f32 out), 128x256 counted-vmcnt kernel (256 blocks)
    gemm8n<<<256, 512, 0, stream>>>(attno, WoT, out, 2048, 2048, 8);
}

// Round 12
// 276.698 us; speedup vs baseline: 1.9263x; 1.0749x over previous
//
#include <hip/hip_runtime.h>
#include <math.h>
#include <stdint.h>

#define B_      2
#define S_      2048
#define HID_    2048
#define H_      16
#define D_NOPE_ 128
#define D_ROPE_ 64
#define D_V_    128
#define R_      512
#define D_Q_    192
#define NTOK    (B_ * S_)
#define EPS_    1e-6f

typedef __attribute__((ext_vector_type(8))) short bf16x8;
typedef __attribute__((ext_vector_type(4))) float f32x4;

__device__ __forceinline__ short f2bf(float x) {
    union { float f; unsigned u; } un; un.f = x;
    unsigned r = (un.u + 0x7fffu + ((un.u >> 16) & 1u)) >> 16;
    return (short)r;
}
__device__ __forceinline__ float bf2f(short s) {
    union { unsigned u; float f; } un;
    un.u = ((unsigned)(unsigned short)s) << 16;
    return un.f;
}

__device__ __forceinline__ void async_ld16(const short* gsrc, short* ldst) {
    __builtin_amdgcn_global_load_lds(
        (const __attribute__((address_space(1))) void*)gsrc,
        (__attribute__((address_space(3))) void*)ldst, 16, 0, 0);
}

#define BARX() { __builtin_amdgcn_sched_barrier(0); __builtin_amdgcn_s_barrier(); __builtin_amdgcn_sched_barrier(0); }

// ---------------------------------------------------------------------------
// prep: castk (8192 blocks) + 4 transpose_cast regions, one launch.
//   tc: W[K][Nreal] f32 -> WT[Npad][K] bf16 (rows >= Nreal zero-filled)
// ---------------------------------------------------------------------------
__device__ __forceinline__ void tc_body(const float* __restrict__ W,
                                        short* __restrict__ WT,
                                        int K, int Nreal, int bx, int by, int t) {
    __shared__ float T[32][33];
    const int n0 = bx * 32, k0 = by * 32;
    const int r = t >> 3, c4 = (t & 7) * 4;
    float4 v = make_float4(0.f, 0.f, 0.f, 0.f);
    if (n0 < Nreal) v = *(const float4*)&W[(size_t)(k0 + r) * Nreal + n0 + c4];
    T[r][c4 + 0] = v.x; T[r][c4 + 1] = v.y; T[r][c4 + 2] = v.z; T[r][c4 + 3] = v.w;
    __syncthreads();
    const int n = t >> 3, k4 = (t & 7) * 4;
    ushort4 o;
    o.x = (unsigned short)f2bf(T[k4 + 0][n]);
    o.y = (unsigned short)f2bf(T[k4 + 1][n]);
    o.z = (unsigned short)f2bf(T[k4 + 2][n]);
    o.w = (unsigned short)f2bf(T[k4 + 3][n]);
    *(ushort4*)&WT[(size_t)(n0 + n) * K + k0 + k4] = o;
}

__global__ __launch_bounds__(256) void prep(const float* __restrict__ hidden,
                                            short* __restrict__ hid_bf,
                                            const float* __restrict__ Wq,
                                            const float* __restrict__ Wkv_a,
                                            const float* __restrict__ Wkv_b,
                                            const float* __restrict__ Wo,
                                            short* __restrict__ WqkaT,
                                            short* __restrict__ WkbT,
                                            short* __restrict__ WoT) {
    const int bid = blockIdx.x, t = threadIdx.x;
    if (bid < 8192) {
        int i = bid * 256 + t;
        float4 v = ((const float4*)hidden)[i];
        ushort4 o;
        o.x = (unsigned short)f2bf(v.x); o.y = (unsigned short)f2bf(v.y);
        o.z = (unsigned short)f2bf(v.z); o.w = (unsigned short)f2bf(v.w);
        ((ushort4*)hid_bf)[i] = o;
    } else if (bid < 8192 + 6144) {
        int idx = bid - 8192;
        tc_body(Wq, WqkaT, 2048, 3072, idx % 96, idx / 96, t);
    } else if (bid < 8192 + 6144 + 1536) {
        int idx = bid - (8192 + 6144);
        tc_body(Wkv_a, WqkaT + (size_t)3072 * 2048, 2048, 576, idx % 24, idx / 24, t);
    } else if (bid < 8192 + 6144 + 1536 + 2048) {
        int idx = bid - (8192 + 6144 + 1536);
        tc_body(Wkv_b, WkbT, 512, 4096, idx % 128, idx / 128, t);
    } else {
        int idx = bid - (8192 + 6144 + 1536 + 2048);
        tc_body(Wo, WoT, 2048, 2048, idx % 64, idx / 64, t);
    }
}

// ---------------------------------------------------------------------------
// 256x256 8-phase GEMM (T3+T4+T5). 512 threads = 8 waves (2M x 4N).
// BK=64 as 2x [256][32] sub-buffers per operand, double-buffered: LDS 128KB.
// Counted vmcnt(4) at P2/P4 keeps loads in flight across barriers.
// QA=1 (q+ckv): cols<3072 -> qbuf bf16 s3072 with FUSED RoPE on pe windows
//   (wcol%192==128; rotation pairs are lane-local: acc[.][0..1] vs [2..3]);
//   3072..3711 -> ckv f32 s640; >=3712 pad dropped.
// QA=0 (kvb): K-nope half (wc<2) -> kvb bf16 global; V half (wc>=2) ->
//   FUSED TRANSPOSE via LDS (reuse LB) -> Vt[b][h][d][s]. V never hits kvb.
// ---------------------------------------------------------------------------
template <int QA>
__global__ __launch_bounds__(512) void gemm8(const short* __restrict__ A,
                                             const short* __restrict__ BT,
                                             void* __restrict__ C0,
                                             float* __restrict__ C1,
                                             short* __restrict__ VtOut,
                                             const float* __restrict__ cosT,
                                             const float* __restrict__ sinT,
                                             const int* __restrict__ pid,
                                             int N, int K, int nbx) {
    __shared__ short LB[2][4][8192];   // [buf][A0,A1,B0,B1][256 rows x 32]

    const int tid = threadIdx.x, lane = tid & 63, w = tid >> 6;
    const int c16 = lane & 15, g = lane >> 4;
    const int wr = w >> 2, wc = w & 3;
    const int qph = (g ^ ((c16 >> 1) & 3)) * 8;

    const int nwg = gridDim.x;   // % 8 == 0
    const int swz = (blockIdx.x & 7) * (nwg >> 3) + (blockIdx.x >> 3);
    const int brow = (swz / nbx) * 256, bcol = (swz % nbx) * 256;

    const int o0 = w * 1024 + lane * 16;
    const int o1 = o0 + 8192;
    const int r0 = o0 >> 6, lc0 = ((o0 >> 4) & 3) ^ ((r0 >> 1) & 3);
    const int r1 = o1 >> 6, lc1 = ((o1 >> 4) & 3) ^ ((r1 >> 1) & 3);
    const short* aS0 = A + (size_t)(brow + r0) * K + lc0 * 8;
    const short* aS1 = A + (size_t)(brow + r1) * K + lc1 * 8;
    const short* bS0 = BT + (size_t)(bcol + r0) * K + lc0 * 8;
    const short* bS1 = BT + (size_t)(bcol + r1) * K + lc1 * 8;
    const int d0 = w * 512, d1 = 4096 + w * 512;

    f32x4 zero = {0.f, 0.f, 0.f, 0.f};
    f32x4 acc[8][4];
#pragma unroll
    for (int i = 0; i < 8; ++i)
#pragma unroll
        for (int j = 0; j < 4; ++j) acc[i][j] = zero;

    const int NT = K >> 6;
    async_ld16(aS0,      &LB[0][0][d0]);  async_ld16(aS1,      &LB[0][0][d1]);
    async_ld16(aS0 + 32, &LB[0][1][d0]);  async_ld16(aS1 + 32, &LB[0][1][d1]);
    async_ld16(bS0,      &LB[0][2][d0]);  async_ld16(bS1,      &LB[0][2][d1]);
    async_ld16(bS0 + 32, &LB[0][3][d0]);  async_ld16(bS1 + 32, &LB[0][3][d1]);
    asm volatile("s_waitcnt vmcnt(0)" ::: "memory");
    BARX();

    int cur = 0;
    const int arb = wr * 128, brb = wc * 64;
    for (int kt = 0; kt < NT; ++kt) {
        const bool stg = (kt + 1 < NT);
        const int ko = (kt + 1) * 64;
        short (*CB)[8192] = LB[cur];
        short (*NB)[8192] = LB[cur ^ 1];
        bf16x8 af[4], bf[4];

#pragma unroll
        for (int ni = 0; ni < 4; ++ni)
            bf[ni] = *(const bf16x8*)&CB[2][(brb + ni * 16 + c16) * 32 + qph];
#pragma unroll
        for (int mi = 0; mi < 4; ++mi)
            af[mi] = *(const bf16x8*)&CB[0][(arb + mi * 16 + c16) * 32 + qph];
        if (stg) { async_ld16(aS0 + ko, &NB[0][d0]); async_ld16(aS1 + ko, &NB[0][d1]); }
        BARX();
        __builtin_amdgcn_s_setprio(1);
#pragma unroll
        for (int mi = 0; mi < 4; ++mi)
#pragma unroll
            for (int ni = 0; ni < 4; ++ni)
                acc[mi][ni] = __builtin_amdgcn_mfma_f32_16x16x32_bf16(af[mi], bf[ni], acc[mi][ni], 0, 0, 0);
        __builtin_amdgcn_s_setprio(0);
        BARX();

#pragma unroll
        for (int mi = 0; mi < 4; ++mi)
            af[mi] = *(const bf16x8*)&CB[0][(arb + 64 + mi * 16 + c16) * 32 + qph];
        if (stg) {
            async_ld16(bS0 + ko, &NB[2][d0]); async_ld16(bS1 + ko, &NB[2][d1]);
            asm volatile("s_waitcnt vmcnt(4)" ::: "memory");
        } else {
            asm volatile("s_waitcnt vmcnt(0)" ::: "memory");
        }
        BARX();
        __builtin_amdgcn_s_setprio(1);
#pragma unroll
        for (int mi = 0; mi < 4; ++mi)
#pragma unroll
            for (int ni = 0; ni < 4; ++ni)
                acc[4 + mi][ni] = __builtin_amdgcn_mfma_f32_16x16x32_bf16(af[mi], bf[ni], acc[4 + mi][ni], 0, 0, 0);
        __builtin_amdgcn_s_setprio(0);
        BARX();

#pragma unroll
        for (int ni = 0; ni < 4; ++ni)
            bf[ni] = *(const bf16x8*)&CB[3][(brb + ni * 16 + c16) * 32 + qph];
#pragma unroll
        for (int mi = 0; mi < 4; ++mi)
            af[mi] = *(const bf16x8*)&CB[1][(arb + mi * 16 + c16) * 32 + qph];
        if (stg) { async_ld16(aS0 + ko + 32, &NB[1][d0]); async_ld16(aS1 + ko + 32, &NB[1][d1]); }
        BARX();
        __builtin_amdgcn_s_setprio(1);
#pragma unroll
        for (int mi = 0; mi < 4; ++mi)
#pragma unroll
            for (int ni = 0; ni < 4; ++ni)
                acc[mi][ni] = __builtin_amdgcn_mfma_f32_16x16x32_bf16(af[mi], bf[ni], acc[mi][ni], 0, 0, 0);
        __builtin_amdgcn_s_setprio(0);
        BARX();

#pragma unroll
        for (int mi = 0; mi < 4; ++mi)
            af[mi] = *(const bf16x8*)&CB[1][(arb + 64 + mi * 16 + c16) * 32 + qph];
        if (stg) {
            async_ld16(bS0 + ko + 32, &NB[3][d0]); async_ld16(bS1 + ko + 32, &NB[3][d1]);
            asm volatile("s_waitcnt vmcnt(4)" ::: "memory");
        }
        BARX();
        __builtin_amdgcn_s_setprio(1);
#pragma unroll
        for (int mi = 0; mi < 4; ++mi)
#pragma unroll
            for (int ni = 0; ni < 4; ++ni)
                acc[4 + mi][ni] = __builtin_amdgcn_mfma_f32_16x16x32_bf16(af[mi], bf[ni], acc[4 + mi][ni], 0, 0, 0);
        __builtin_amdgcn_s_setprio(0);
        BARX();

        cur ^= 1;
    }

    if (QA) {
        const int wcol = bcol + wc * 64;
        if (wcol < 3072) {
            short* qb = (short*)C0;
            if ((wcol % 192) == 128) {
                // pe window: fused RoPE (pairs are lane-local)
#pragma unroll
                for (int mi = 0; mi < 8; ++mi)
#pragma unroll
                    for (int reg = 0; reg < 4; ++reg) {
                        int row = brow + wr * 128 + mi * 16 + 4 * g + reg;
                        int pos = pid[row];
                        float cc1 = cosT[pos * 32 + c16],      ss1 = sinT[pos * 32 + c16];
                        float cc2 = cosT[pos * 32 + 16 + c16], ss2 = sinT[pos * 32 + 16 + c16];
                        float a0 = acc[mi][0][reg], a1 = acc[mi][1][reg];
                        float a2 = acc[mi][2][reg], a3 = acc[mi][3][reg];
                        size_t rb = (size_t)row * 3072 + wcol;
                        qb[rb + c16]      = f2bf(a0 * cc1 - a2 * ss1);
                        qb[rb + 16 + c16] = f2bf(a1 * cc2 - a3 * ss2);
                        qb[rb + 32 + c16] = f2bf(a2 * cc1 + a0 * ss1);
                        qb[rb + 48 + c16] = f2bf(a3 * cc2 + a1 * ss2);
                    }
            } else {
#pragma unroll
                for (int mi = 0; mi < 8; ++mi)
#pragma unroll
                    for (int ni = 0; ni < 4; ++ni)
#pragma unroll
                        for (int reg = 0; reg < 4; ++reg) {
                            int row = brow + wr * 128 + mi * 16 + 4 * g + reg;
                            qb[(size_t)row * 3072 + wcol + ni * 16 + c16] = f2bf(acc[mi][ni][reg]);
                        }
            }
        } else if (wcol < 3712) {
#pragma unroll
            for (int mi = 0; mi < 8; ++mi)
#pragma unroll
                for (int ni = 0; ni < 4; ++ni)
#pragma unroll
                    for (int reg = 0; reg < 4; ++reg) {
                        int row = brow + wr * 128 + mi * 16 + 4 * g + reg;
                        int col = wcol - 3072 + ni * 16 + c16;
                        C1[(size_t)row * 640 + col] = acc[mi][ni][reg];
                    }
        }
    } else {
        // kvb mode: K-nope half -> global; V half -> LDS transpose -> Vt
        short* cc = (short*)C0;
        short* LT = &LB[0][0][0];          // 64KB reuse, safe after final BARX
        const int wcol = bcol + wc * 64;
        if (wc < 2) {
#pragma unroll
            for (int mi = 0; mi < 8; ++mi)
#pragma unroll
                for (int ni = 0; ni < 4; ++ni)
#pragma unroll
                    for (int reg = 0; reg < 4; ++reg) {
                        int row = brow + wr * 128 + mi * 16 + 4 * g + reg;
                        cc[(size_t)row * N + wcol + ni * 16 + c16] = f2bf(acc[mi][ni][reg]);
                    }
        } else {
#pragma unroll
            for (int mi = 0; mi < 8; ++mi)
#pragma unroll
                for (int ni = 0; ni < 4; ++ni)
#pragma unroll
                    for (int reg = 0; reg < 4; ++reg) {
                        int d = wc * 64 - 128 + ni * 16 + c16;
                        int s = wr * 128 + mi * 16 + 4 * g + reg;
                        LT[d * 256 + (s ^ ((d & 15) << 3))] = f2bf(acc[mi][ni][reg]);
                    }
        }
        __syncthreads();
        const int bb = brow >> 11, hh = bcol >> 8, sbase = brow & 2047;
#pragma unroll
        for (int j = 0; j < 8; ++j) {
            int d = j * 16 + (tid >> 5);
            int s0 = (tid & 31) * 8;
            bf16x8 v = *(const bf16x8*)&LT[d * 256 + (s0 ^ ((d & 15) << 3))];
            *(bf16x8*)&VtOut[((size_t)((bb * 16 + hh) * 128 + d)) * 2048 + sbase + s0] = v;
        }
    }
}

// ---------------------------------------------------------------------------
// 128x256 counted-vmcnt GEMM for gemm_out (M=4096, N=2048 -> 256 blocks).
// ---------------------------------------------------------------------------
__global__ __launch_bounds__(512) void gemm8n(const short* __restrict__ A,
                                              const short* __restrict__ BT,
                                              float* __restrict__ C,
                                              int N, int K, int nbx) {
    __shared__ short LA[2][2][4096];
    __shared__ short LBt[2][2][8192];

    const int tid = threadIdx.x, lane = tid & 63, w = tid >> 6;
    const int c16 = lane & 15, g = lane >> 4;
    const int wr = w >> 2, wc = w & 3;
    const int qph = (g ^ ((c16 >> 1) & 3)) * 8;

    const int nwg = gridDim.x;
    const int swz = (blockIdx.x & 7) * (nwg >> 3) + (blockIdx.x >> 3);
    const int brow = (swz / nbx) * 128, bcol = (swz % nbx) * 256;

    const int oA = tid * 16;
    const int rA = oA >> 6, lcA = ((oA >> 4) & 3) ^ ((rA >> 1) & 3);
    const short* aS = A + (size_t)(brow + rA) * K + lcA * 8;
    const int dA = oA >> 1;

    const int o0 = w * 1024 + lane * 16, o1 = o0 + 8192;
    const int r0 = o0 >> 6, lc0 = ((o0 >> 4) & 3) ^ ((r0 >> 1) & 3);
    const int r1 = o1 >> 6, lc1 = ((o1 >> 4) & 3) ^ ((r1 >> 1) & 3);
    const short* bS0 = BT + (size_t)(bcol + r0) * K + lc0 * 8;
    const short* bS1 = BT + (size_t)(bcol + r1) * K + lc1 * 8;
    const int d0 = o0 >> 1, d1 = o1 >> 1;

    f32x4 zero = {0.f, 0.f, 0.f, 0.f};
    f32x4 acc[4][4];
#pragma unroll
    for (int i = 0; i < 4; ++i)
#pragma unroll
        for (int j = 0; j < 4; ++j) acc[i][j] = zero;

    const int NT = K >> 6;
    async_ld16(aS,      &LA[0][0][dA]);
    async_ld16(aS + 32, &LA[0][1][dA]);
    async_ld16(bS0,      &LBt[0][0][d0]); async_ld16(bS1,      &LBt[0][0][d1]);
    async_ld16(bS0 + 32, &LBt[0][1][d0]); async_ld16(bS1 + 32, &LBt[0][1][d1]);
    asm volatile("s_waitcnt vmcnt(0)" ::: "memory");
    BARX();

    int cur = 0;
    const int arb = wr * 64, brb = wc * 64;
    for (int kt = 0; kt < NT; ++kt) {
        const bool stg = (kt + 1 < NT);
        const int ko = (kt + 1) * 64;
        bf16x8 af[4], bf[4];

#pragma unroll
        for (int mi = 0; mi < 4; ++mi)
            af[mi] = *(const bf16x8*)&LA[cur][0][(arb + mi * 16 + c16) * 32 + qph];
#pragma unroll
        for (int ni = 0; ni < 4; ++ni)
            bf[ni] = *(const bf16x8*)&LBt[cur][0][(brb + ni * 16 + c16) * 32 + qph];
        if (stg) {
            async_ld16(aS + ko, &LA[cur ^ 1][0][dA]);
            async_ld16(bS0 + ko, &LBt[cur ^ 1][0][d0]);
            async_ld16(bS1 + ko, &LBt[cur ^ 1][0][d1]);
            asm volatile("s_waitcnt vmcnt(3)" ::: "memory");
        } else {
            asm volatile("s_waitcnt vmcnt(0)" ::: "memory");
        }
        BARX();
        __builtin_amdgcn_s_setprio(1);
#pragma unroll
        for (int mi = 0; mi < 4; ++mi)
#pragma unroll
            for (int ni = 0; ni < 4; ++ni)
                acc[mi][ni] = __builtin_amdgcn_mfma_f32_16x16x32_bf16(af[mi], bf[ni], acc[mi][ni], 0, 0, 0);
        __builtin_amdgcn_s_setprio(0);
        BARX();

#pragma unroll
        for (int mi = 0; mi < 4; ++mi)
            af[mi] = *(const bf16x8*)&LA[cur][1][(arb + mi * 16 + c16) * 32 + qph];
#pragma unroll
        for (int ni = 0; ni < 4; ++ni)
            bf[ni] = *(const bf16x8*)&LBt[cur][1][(brb + ni * 16 + c16) * 32 + qph];
        if (stg) {
            async_ld16(aS + ko + 32, &LA[cur ^ 1][1][dA]);
            async_ld16(bS0 + ko + 32, &LBt[cur ^ 1][1][d0]);
            async_ld16(bS1 + ko + 32, &LBt[cur ^ 1][1][d1]);
            asm volatile("s_waitcnt vmcnt(3)" ::: "memory");
        }
        BARX();
        __builtin_amdgcn_s_setprio(1);
#pragma unroll
        for (int mi = 0; mi < 4; ++mi)
#pragma unroll
            for (int ni = 0; ni < 4; ++ni)
                acc[mi][ni] = __builtin_amdgcn_mfma_f32_16x16x32_bf16(af[mi], bf[ni], acc[mi][ni], 0, 0, 0);
        __builtin_amdgcn_s_setprio(0);
        BARX();

        cur ^= 1;
    }

#pragma unroll
    for (int mi = 0; mi < 4; ++mi)
#pragma unroll
        for (int ni = 0; ni < 4; ++ni)
#pragma unroll
            for (int reg = 0; reg < 4; ++reg) {
                int row = brow + wr * 64 + mi * 16 + 4 * g + reg;
                int col = bcol + wc * 64 + ni * 16 + c16;
                C[(size_t)row * N + col] = acc[mi][ni][reg];
            }
}

// ---------------------------------------------------------------------------
// LayerNorm(512) + RoPE(k_pe). ckv stride 640. Outputs bf16.
// ---------------------------------------------------------------------------
__global__ __launch_bounds__(256) void ln_rope(const float* __restrict__ ckv,
                                               const float* __restrict__ gam,
                                               const float* __restrict__ bet,
                                               const float* __restrict__ cosT,
                                               const float* __restrict__ sinT,
                                               const int* __restrict__ pid,
                                               short* __restrict__ kvcn,
                                               short* __restrict__ kpe) {
    const int tok = blockIdx.x, tid = threadIdx.x;
    const float* x = ckv + (size_t)tok * 640;
    float v0 = x[tid], v1 = x[tid + 256];
    float s = v0 + v1, sq = v0 * v0 + v1 * v1;
#pragma unroll
    for (int m = 1; m < 64; m <<= 1) { s += __shfl_xor(s, m); sq += __shfl_xor(sq, m); }
    __shared__ float ws[8];
    int wid = tid >> 6, lane = tid & 63;
    if (lane == 0) { ws[wid] = s; ws[4 + wid] = sq; }
    __syncthreads();
    s = ws[0] + ws[1] + ws[2] + ws[3];
    sq = ws[4] + ws[5] + ws[6] + ws[7];
    float mean = s * (1.f / 512.f);
    float var = sq * (1.f / 512.f) - mean * mean;
    float rstd = rsqrtf(var + EPS_);
    kvcn[(size_t)tok * 512 + tid]       = f2bf((v0 - mean) * rstd * gam[tid] + bet[tid]);
    kvcn[(size_t)tok * 512 + tid + 256] = f2bf((v1 - mean) * rstd * gam[tid + 256] + bet[tid + 256]);
    if (tid < 32) {
        int pos = pid[tok];
        float c = cosT[pos * 32 + tid], sn = sinT[pos * 32 + tid];
        float x1 = x[512 + tid], x2 = x[512 + 32 + tid];
        kpe[(size_t)tok * 64 + tid]      = f2bf(x1 * c - x2 * sn);
        kpe[(size_t)tok * 64 + 32 + tid] = f2bf(x2 * c + x1 * sn);
    }
}

// ---------------------------------------------------------------------------
// MFMA flash attention (R8/R9 structure, unchanged math).
// ---------------------------------------------------------------------------
__global__ __launch_bounds__(256) void flash_mfma(const short* __restrict__ qb,
                                                  const short* __restrict__ kvb,
                                                  const short* __restrict__ kpe,
                                                  const short* __restrict__ Vt,
                                                  short* __restrict__ attno) {
    __shared__ short Ks[2][64 * 128];
    __shared__ short Vs[2][128 * 64];
    __shared__ short P[4][16][72];

    const int flat = blockIdx.x;              // 0..511
    const int xcd = flat & 7, idx = flat >> 3;
    const int bh = xcd + 8 * (idx >> 4);
    const int pair = idx & 15;
    const int b = bh >> 4, h = bh & 15;

    const int tid = threadIdx.x, lane = tid & 63, w = tid >> 6;
    const int c16 = lane & 15, g = lane >> 4, g8 = g * 8;
    const float SC2 = 0.10412063f;   // 1/sqrt(192) * log2(e)

    const int o = w * 1024 + lane * 16;
    const int rK = o >> 8, ccK = ((o >> 4) & 15) ^ (rK & 7);
    const int rV = o >> 7, ccV = ((o >> 4) & 7) ^ (rV & 7);
    const short* kB0  = kvb + ((size_t)((b * 2048 + rK) * 16 + h)) * 256 + ccK * 8;
    const short* vB0  = Vt + ((size_t)((b * 16 + h) * 128 + rV)) * 2048 + ccV * 8;
    const short* peB0 = kpe + (size_t)(b * 2048 + c16) * 64 + g8;

    f32x4 zero = {0.f, 0.f, 0.f, 0.f};

#define STAGE(BUF)                                                                  \
    {                                                                               \
        _Pragma("unroll")                                                           \
        for (int rnd = 0; rnd < 4; ++rnd)                                           \
            async_ld16(kRun + (size_t)rnd * 65536,                                  \
                       &Ks[BUF][(rnd * 4096 + w * 1024) >> 1]);                     \
        _Pragma("unroll")                                                           \
        for (int rnd = 0; rnd < 4; ++rnd)                                           \
            async_ld16(vRun + (size_t)rnd * 65536,                                  \
                       &Vs[BUF][(rnd * 4096 + w * 1024) >> 1]);                     \
        kRun += 64 * 4096;                                                          \
        vRun += 64;                                                                 \
    }

    for (int half = 0; half < 2; ++half) {
        const int qt = half ? (31 - pair) : pair;
        const int q0 = qt * 64;
        const int qrow = q0 + w * 16;

        const size_t qbase = ((size_t)(b * 2048 + qrow + c16) * 16 + h) * 192 + g8;
        bf16x8 qf[6];
#pragma unroll
        for (int ks = 0; ks < 6; ++ks) qf[ks] = *(const bf16x8*)(qb + qbase + 32 * ks);

        f32x4 acc[8];
#pragma unroll
        for (int i = 0; i < 8; ++i) acc[i] = zero;
        float mreg[4] = {-INFINITY, -INFINITY, -INFINITY, -INFINITY};
        float lreg[4] = {0.f, 0.f, 0.f, 0.f};

        const short* kRun = kB0;
        const short* vRun = vB0;
        const short* peRun = peB0;

        const int nt = qt + 1;
        STAGE(0);
        __syncthreads();
        int cur = 0;

        for (int kt = 0; kt < nt; ++kt) {
            if (kt + 1 < nt) STAGE(cur ^ 1);

            f32x4 sc[4];
#pragma unroll
            for (int i = 0; i < 4; ++i) sc[i] = zero;

            __builtin_amdgcn_s_setprio(1);
#pragma unroll
            for (int ks = 0; ks < 4; ++ks)
#pragma unroll
                for (int nb = 0; nb < 4; ++nb) {
                    int row = nb * 16 + c16;
                    bf16x8 kf = *(const bf16x8*)&Ks[cur][row * 128 + (((g + 4 * ks) ^ (row & 7)) << 3)];
                    sc[nb] = __builtin_amdgcn_mfma_f32_16x16x32_bf16(qf[ks], kf, sc[nb], 0, 0, 0);
                }
#pragma unroll
            for (int ks = 0; ks < 2; ++ks)
#pragma unroll
                for (int nb = 0; nb < 4; ++nb) {
                    bf16x8 kf = *(const bf16x8*)(peRun + (size_t)nb * 16 * 64 + ks * 32);
                    sc[nb] = __builtin_amdgcn_mfma_f32_16x16x32_bf16(qf[4 + ks], kf, sc[nb], 0, 0, 0);
                }
            __builtin_amdgcn_s_setprio(0);
            peRun += 64 * 64;

            if (kt == nt - 1) {
#pragma unroll
                for (int nb = 0; nb < 4; ++nb)
#pragma unroll
                    for (int reg = 0; reg < 4; ++reg) {
                        int col = (nt - 1) * 64 + nb * 16 + c16;
                        int row = qrow + 4 * g + reg;
                        if (col > row) sc[nb][reg] = -INFINITY;
                    }
            }

            float rmax[4];
#pragma unroll
            for (int reg = 0; reg < 4; ++reg)
                rmax[reg] = fmaxf(fmaxf(sc[0][reg], sc[1][reg]), fmaxf(sc[2][reg], sc[3][reg]));
#pragma unroll
            for (int m = 1; m < 16; m <<= 1)
#pragma unroll
                for (int reg = 0; reg < 4; ++reg)
                    rmax[reg] = fmaxf(rmax[reg], __shfl_xor(rmax[reg], m));

            float grow = rmax[0] * SC2 - mreg[0];
#pragma unroll
            for (int reg = 1; reg < 4; ++reg) grow = fmaxf(grow, rmax[reg] * SC2 - mreg[reg]);
            if (__any(grow > 8.f)) {
#pragma unroll
                for (int reg = 0; reg < 4; ++reg) {
                    float mnew = fmaxf(mreg[reg], rmax[reg] * SC2);
                    float alpha = exp2f(mreg[reg] - mnew);
                    mreg[reg] = mnew;
                    lreg[reg] *= alpha;
#pragma unroll
                    for (int nb = 0; nb < 8; ++nb) acc[nb][reg] *= alpha;
                }
            }

#pragma unroll
            for (int reg = 0; reg < 4; ++reg) {
                float p0 = exp2f(fmaf(sc[0][reg], SC2, -mreg[reg]));
                float p1 = exp2f(fmaf(sc[1][reg], SC2, -mreg[reg]));
                float p2 = exp2f(fmaf(sc[2][reg], SC2, -mreg[reg]));
                float p3 = exp2f(fmaf(sc[3][reg], SC2, -mreg[reg]));
                sc[0][reg] = p0; sc[1][reg] = p1; sc[2][reg] = p2; sc[3][reg] = p3;
                lreg[reg] += (p0 + p1) + (p2 + p3);
            }

#pragma unroll
            for (int nb = 0; nb < 4; ++nb)
#pragma unroll
                for (int reg = 0; reg < 4; ++reg)
                    P[w][4 * g + reg][nb * 16 + c16] = f2bf(sc[nb][reg]);

            __builtin_amdgcn_s_setprio(1);
#pragma unroll
            for (int ks = 0; ks < 2; ++ks) {
                bf16x8 pf = *(const bf16x8*)&P[w][c16][ks * 32 + g8];
#pragma unroll
                for (int nb = 0; nb < 8; ++nb) {
                    int row = nb * 16 + c16;
                    bf16x8 vf = *(const bf16x8*)&Vs[cur][row * 64 + (((g + 4 * ks) ^ (row & 7)) << 3)];
                    acc[nb] = __builtin_amdgcn_mfma_f32_16x16x32_bf16(pf, vf, acc[nb], 0, 0, 0);
                }
            }
            __builtin_amdgcn_s_setprio(0);

            __syncthreads();
            cur ^= 1;
        }

#pragma unroll
        for (int m = 1; m < 16; m <<= 1)
#pragma unroll
            for (int reg = 0; reg < 4; ++reg)
                lreg[reg] += __shfl_xor(lreg[reg], m);
        float inv[4];
#pragma unroll
        for (int reg = 0; reg < 4; ++reg) inv[reg] = 1.f / lreg[reg];
#pragma unroll
        for (int nb = 0; nb < 8; ++nb)
#pragma unroll
            for (int reg = 0; reg < 4; ++reg)
                attno[((size_t)(b * 2048 + qrow + 4 * g + reg) * 16 + h) * 128 + nb * 16 + c16] =
                    f2bf(acc[nb][reg] * inv[reg]);
    }
#undef STAGE
}

// ---------------------------------------------------------------------------
extern "C" void kernel_launch(void* const* d_in, const int* in_sizes, int n_in,
                              void* d_out, int out_size, void* d_ws, size_t ws_size,
                              hipStream_t stream) {
    const float* hidden = (const float*)d_in[0];
    const float* cosT   = (const float*)d_in[1];
    const float* sinT   = (const float*)d_in[2];
    const int*   pid    = (const int*)d_in[3];
    const float* Wq     = (const float*)d_in[4];
    const float* Wkv_a  = (const float*)d_in[5];
    const float* ln_g   = (const float*)d_in[6];
    const float* ln_b   = (const float*)d_in[7];
    const float* Wkv_b  = (const float*)d_in[8];
    const float* Wo     = (const float*)d_in[9];
    float* out = (float*)d_out;

    char* p = (char*)d_ws;
    short* hid_bf = (short*)p;               p += (size_t)NTOK * 2048 * 2;
    short* WqkaT  = (short*)p;               p += (size_t)3840 * 2048 * 2;  // WqT | WkaT | zero pad
    short* WkbT   = (short*)p;               p += (size_t)4096 * 512 * 2;
    short* WoT    = (short*)p;               p += (size_t)2048 * 2048 * 2;
    char*  big    = p;                       p += (size_t)NTOK * 3072 * 4;
    short* qbuf   = (short*)p;               p += (size_t)NTOK * 3072 * 2;
    short* kvcn   = (short*)p;               p += (size_t)NTOK * 512 * 2;
    short* kpe    = (short*)p;               p += (size_t)NTOK * 64 * 2;
    short* kvb    = (short*)p;               p += (size_t)NTOK * 4096 * 2;

    float* ckv   = (float*)big;
    short* Vt    = (short*)(big + (size_t)NTOK * 640 * 4);
    short* attno = (short*)(big + (size_t)NTOK * 640 * 4 + (size_t)2 * 16 * 128 * 2048 * 2);

    // 0. merged cast + weight transposes (was 5 launches)
    prep<<<22016, 256, 0, stream>>>(hidden, hid_bf, Wq, Wkv_a, Wkv_b, Wo, WqkaT, WkbT, WoT);
    // 1. fused q+ckv 8-phase GEMM with fused q-RoPE epilogue
    gemm8<1><<<240, 512, 0, stream>>>(hid_bf, WqkaT, qbuf, ckv, nullptr,
                                      cosT, sinT, pid, 3840, 2048, 15);
    // 2. LayerNorm + RoPE(k_pe) -> bf16
    ln_rope<<<NTOK, 256, 0, stream>>>(ckv, ln_g, ln_b, cosT, sinT, pid, kvcn, kpe);
    // 3. kv = kvcn @ Wkv_b (K-nope -> kvb; V -> fused transpose -> Vt)
    gemm8<0><<<256, 512, 0, stream>>>(kvcn, WkbT, kvb, nullptr, Vt,
                                      nullptr, nullptr, nullptr, 4096, 512, 16);
    // 4. flash attention
    flash_mfma<<<512, 256, 0, stream>>>(qbuf, kvb, kpe, Vt, attno);
    // 5. out = attno @ Wo (f32 out)
    gemm8n<<<256, 512, 0, stream>>>(attno, WoT, out, 2048, 2048, 8);
}

// Round 13
// 273.655 us; speedup vs baseline: 1.9477x; 1.0111x over previous
//
#include <hip/hip_runtime.h>
#include <math.h>
#include <stdint.h>

#define B_      2
#define S_      2048
#define HID_    2048
#define H_      16
#define D_NOPE_ 128
#define D_ROPE_ 64
#define D_V_    128
#define R_      512
#define D_Q_    192
#define NTOK    (B_ * S_)
#define EPS_    1e-6f

typedef __attribute__((ext_vector_type(8))) short bf16x8;
typedef __attribute__((ext_vector_type(4))) float f32x4;

__device__ __forceinline__ short f2bf(float x) {
    union { float f; unsigned u; } un; un.f = x;
    unsigned r = (un.u + 0x7fffu + ((un.u >> 16) & 1u)) >> 16;
    return (short)r;
}
__device__ __forceinline__ float bf2f(short s) {
    union { unsigned u; float f; } un;
    un.u = ((unsigned)(unsigned short)s) << 16;
    return un.f;
}

__device__ __forceinline__ void async_ld16(const short* gsrc, short* ldst) {
    __builtin_amdgcn_global_load_lds(
        (const __attribute__((address_space(1))) void*)gsrc,
        (__attribute__((address_space(3))) void*)ldst, 16, 0, 0);
}

#define BARX() { __builtin_amdgcn_sched_barrier(0); __builtin_amdgcn_s_barrier(); __builtin_amdgcn_sched_barrier(0); }

// ---------------------------------------------------------------------------
// prep: castk (8192 blocks) + 4 transpose_cast regions, one launch.
// ---------------------------------------------------------------------------
__device__ __forceinline__ void tc_body(const float* __restrict__ W,
                                        short* __restrict__ WT,
                                        int K, int Nreal, int bx, int by, int t) {
    __shared__ float T[32][33];
    const int n0 = bx * 32, k0 = by * 32;
    const int r = t >> 3, c4 = (t & 7) * 4;
    float4 v = make_float4(0.f, 0.f, 0.f, 0.f);
    if (n0 < Nreal) v = *(const float4*)&W[(size_t)(k0 + r) * Nreal + n0 + c4];
    T[r][c4 + 0] = v.x; T[r][c4 + 1] = v.y; T[r][c4 + 2] = v.z; T[r][c4 + 3] = v.w;
    __syncthreads();
    const int n = t >> 3, k4 = (t & 7) * 4;
    ushort4 o;
    o.x = (unsigned short)f2bf(T[k4 + 0][n]);
    o.y = (unsigned short)f2bf(T[k4 + 1][n]);
    o.z = (unsigned short)f2bf(T[k4 + 2][n]);
    o.w = (unsigned short)f2bf(T[k4 + 3][n]);
    *(ushort4*)&WT[(size_t)(n0 + n) * K + k0 + k4] = o;
}

__global__ __launch_bounds__(256) void prep(const float* __restrict__ hidden,
                                            short* __restrict__ hid_bf,
                                            const float* __restrict__ Wq,
                                            const float* __restrict__ Wkv_a,
                                            const float* __restrict__ Wkv_b,
                                            const float* __restrict__ Wo,
                                            short* __restrict__ WqkaT,
                                            short* __restrict__ WkbT,
                                            short* __restrict__ WoT) {
    const int bid = blockIdx.x, t = threadIdx.x;
    if (bid < 8192) {
        int i = bid * 256 + t;
        float4 v = ((const float4*)hidden)[i];
        ushort4 o;
        o.x = (unsigned short)f2bf(v.x); o.y = (unsigned short)f2bf(v.y);
        o.z = (unsigned short)f2bf(v.z); o.w = (unsigned short)f2bf(v.w);
        ((ushort4*)hid_bf)[i] = o;
    } else if (bid < 8192 + 6144) {
        int idx = bid - 8192;
        tc_body(Wq, WqkaT, 2048, 3072, idx % 96, idx / 96, t);
    } else if (bid < 8192 + 6144 + 1536) {
        int idx = bid - (8192 + 6144);
        tc_body(Wkv_a, WqkaT + (size_t)3072 * 2048, 2048, 576, idx % 24, idx / 24, t);
    } else if (bid < 8192 + 6144 + 1536 + 2048) {
        int idx = bid - (8192 + 6144 + 1536);
        tc_body(Wkv_b, WkbT, 512, 4096, idx % 128, idx / 128, t);
    } else {
        int idx = bid - (8192 + 6144 + 1536 + 2048);
        tc_body(Wo, WoT, 2048, 2048, idx % 64, idx / 64, t);
    }
}

// ---------------------------------------------------------------------------
// 256x256 8-phase GEMM (T3+T4+T5). 512 threads = 8 waves (2M x 4N).
// ---------------------------------------------------------------------------
template <int QA>
__global__ __launch_bounds__(512) void gemm8(const short* __restrict__ A,
                                             const short* __restrict__ BT,
                                             void* __restrict__ C0,
                                             float* __restrict__ C1,
                                             short* __restrict__ VtOut,
                                             const float* __restrict__ cosT,
                                             const float* __restrict__ sinT,
                                             const int* __restrict__ pid,
                                             int N, int K, int nbx) {
    __shared__ short LB[2][4][8192];   // [buf][A0,A1,B0,B1][256 rows x 32]

    const int tid = threadIdx.x, lane = tid & 63, w = tid >> 6;
    const int c16 = lane & 15, g = lane >> 4;
    const int wr = w >> 2, wc = w & 3;
    const int qph = (g ^ ((c16 >> 1) & 3)) * 8;

    const int nwg = gridDim.x;   // % 8 == 0
    const int swz = (blockIdx.x & 7) * (nwg >> 3) + (blockIdx.x >> 3);
    const int brow = (swz / nbx) * 256, bcol = (swz % nbx) * 256;

    const int o0 = w * 1024 + lane * 16;
    const int o1 = o0 + 8192;
    const int r0 = o0 >> 6, lc0 = ((o0 >> 4) & 3) ^ ((r0 >> 1) & 3);
    const int r1 = o1 >> 6, lc1 = ((o1 >> 4) & 3) ^ ((r1 >> 1) & 3);
    const short* aS0 = A + (size_t)(brow + r0) * K + lc0 * 8;
    const short* aS1 = A + (size_t)(brow + r1) * K + lc1 * 8;
    const short* bS0 = BT + (size_t)(bcol + r0) * K + lc0 * 8;
    const short* bS1 = BT + (size_t)(bcol + r1) * K + lc1 * 8;
    const int d0 = w * 512, d1 = 4096 + w * 512;

    f32x4 zero = {0.f, 0.f, 0.f, 0.f};
    f32x4 acc[8][4];
#pragma unroll
    for (int i = 0; i < 8; ++i)
#pragma unroll
        for (int j = 0; j < 4; ++j) acc[i][j] = zero;

    const int NT = K >> 6;
    async_ld16(aS0,      &LB[0][0][d0]);  async_ld16(aS1,      &LB[0][0][d1]);
    async_ld16(aS0 + 32, &LB[0][1][d0]);  async_ld16(aS1 + 32, &LB[0][1][d1]);
    async_ld16(bS0,      &LB[0][2][d0]);  async_ld16(bS1,      &LB[0][2][d1]);
    async_ld16(bS0 + 32, &LB[0][3][d0]);  async_ld16(bS1 + 32, &LB[0][3][d1]);
    asm volatile("s_waitcnt vmcnt(0)" ::: "memory");
    BARX();

    int cur = 0;
    const int arb = wr * 128, brb = wc * 64;
    for (int kt = 0; kt < NT; ++kt) {
        const bool stg = (kt + 1 < NT);
        const int ko = (kt + 1) * 64;
        short (*CB)[8192] = LB[cur];
        short (*NB)[8192] = LB[cur ^ 1];
        bf16x8 af[4], bf[4];

#pragma unroll
        for (int ni = 0; ni < 4; ++ni)
            bf[ni] = *(const bf16x8*)&CB[2][(brb + ni * 16 + c16) * 32 + qph];
#pragma unroll
        for (int mi = 0; mi < 4; ++mi)
            af[mi] = *(const bf16x8*)&CB[0][(arb + mi * 16 + c16) * 32 + qph];
        if (stg) { async_ld16(aS0 + ko, &NB[0][d0]); async_ld16(aS1 + ko, &NB[0][d1]); }
        BARX();
        __builtin_amdgcn_s_setprio(1);
#pragma unroll
        for (int mi = 0; mi < 4; ++mi)
#pragma unroll
            for (int ni = 0; ni < 4; ++ni)
                acc[mi][ni] = __builtin_amdgcn_mfma_f32_16x16x32_bf16(af[mi], bf[ni], acc[mi][ni], 0, 0, 0);
        __builtin_amdgcn_s_setprio(0);
        BARX();

#pragma unroll
        for (int mi = 0; mi < 4; ++mi)
            af[mi] = *(const bf16x8*)&CB[0][(arb + 64 + mi * 16 + c16) * 32 + qph];
        if (stg) {
            async_ld16(bS0 + ko, &NB[2][d0]); async_ld16(bS1 + ko, &NB[2][d1]);
            asm volatile("s_waitcnt vmcnt(4)" ::: "memory");
        } else {
            asm volatile("s_waitcnt vmcnt(0)" ::: "memory");
        }
        BARX();
        __builtin_amdgcn_s_setprio(1);
#pragma unroll
        for (int mi = 0; mi < 4; ++mi)
#pragma unroll
            for (int ni = 0; ni < 4; ++ni)
                acc[4 + mi][ni] = __builtin_amdgcn_mfma_f32_16x16x32_bf16(af[mi], bf[ni], acc[4 + mi][ni], 0, 0, 0);
        __builtin_amdgcn_s_setprio(0);
        BARX();

#pragma unroll
        for (int ni = 0; ni < 4; ++ni)
            bf[ni] = *(const bf16x8*)&CB[3][(brb + ni * 16 + c16) * 32 + qph];
#pragma unroll
        for (int mi = 0; mi < 4; ++mi)
            af[mi] = *(const bf16x8*)&CB[1][(arb + mi * 16 + c16) * 32 + qph];
        if (stg) { async_ld16(aS0 + ko + 32, &NB[1][d0]); async_ld16(aS1 + ko + 32, &NB[1][d1]); }
        BARX();
        __builtin_amdgcn_s_setprio(1);
#pragma unroll
        for (int mi = 0; mi < 4; ++mi)
#pragma unroll
            for (int ni = 0; ni < 4; ++ni)
                acc[mi][ni] = __builtin_amdgcn_mfma_f32_16x16x32_bf16(af[mi], bf[ni], acc[mi][ni], 0, 0, 0);
        __builtin_amdgcn_s_setprio(0);
        BARX();

#pragma unroll
        for (int mi = 0; mi < 4; ++mi)
            af[mi] = *(const bf16x8*)&CB[1][(arb + 64 + mi * 16 + c16) * 32 + qph];
        if (stg) {
            async_ld16(bS0 + ko + 32, &NB[3][d0]); async_ld16(bS1 + ko + 32, &NB[3][d1]);
            asm volatile("s_waitcnt vmcnt(4)" ::: "memory");
        }
        BARX();
        __builtin_amdgcn_s_setprio(1);
#pragma unroll
        for (int mi = 0; mi < 4; ++mi)
#pragma unroll
            for (int ni = 0; ni < 4; ++ni)
                acc[4 + mi][ni] = __builtin_amdgcn_mfma_f32_16x16x32_bf16(af[mi], bf[ni], acc[4 + mi][ni], 0, 0, 0);
        __builtin_amdgcn_s_setprio(0);
        BARX();

        cur ^= 1;
    }

    if (QA) {
        const int wcol = bcol + wc * 64;
        if (wcol < 3072) {
            short* qb = (short*)C0;
            if ((wcol % 192) == 128) {
#pragma unroll
                for (int mi = 0; mi < 8; ++mi)
#pragma unroll
                    for (int reg = 0; reg < 4; ++reg) {
                        int row = brow + wr * 128 + mi * 16 + 4 * g + reg;
                        int pos = pid[row];
                        float cc1 = cosT[pos * 32 + c16],      ss1 = sinT[pos * 32 + c16];
                        float cc2 = cosT[pos * 32 + 16 + c16], ss2 = sinT[pos * 32 + 16 + c16];
                        float a0 = acc[mi][0][reg], a1 = acc[mi][1][reg];
                        float a2 = acc[mi][2][reg], a3 = acc[mi][3][reg];
                        size_t rb = (size_t)row * 3072 + wcol;
                        qb[rb + c16]      = f2bf(a0 * cc1 - a2 * ss1);
                        qb[rb + 16 + c16] = f2bf(a1 * cc2 - a3 * ss2);
                        qb[rb + 32 + c16] = f2bf(a2 * cc1 + a0 * ss1);
                        qb[rb + 48 + c16] = f2bf(a3 * cc2 + a1 * ss2);
                    }
            } else {
#pragma unroll
                for (int mi = 0; mi < 8; ++mi)
#pragma unroll
                    for (int ni = 0; ni < 4; ++ni)
#pragma unroll
                        for (int reg = 0; reg < 4; ++reg) {
                            int row = brow + wr * 128 + mi * 16 + 4 * g + reg;
                            qb[(size_t)row * 3072 + wcol + ni * 16 + c16] = f2bf(acc[mi][ni][reg]);
                        }
            }
        } else if (wcol < 3712) {
#pragma unroll
            for (int mi = 0; mi < 8; ++mi)
#pragma unroll
                for (int ni = 0; ni < 4; ++ni)
#pragma unroll
                    for (int reg = 0; reg < 4; ++reg) {
                        int row = brow + wr * 128 + mi * 16 + 4 * g + reg;
                        int col = wcol - 3072 + ni * 16 + c16;
                        C1[(size_t)row * 640 + col] = acc[mi][ni][reg];
                    }
        }
    } else {
        short* cc = (short*)C0;
        short* LT = &LB[0][0][0];
        const int wcol = bcol + wc * 64;
        if (wc < 2) {
#pragma unroll
            for (int mi = 0; mi < 8; ++mi)
#pragma unroll
                for (int ni = 0; ni < 4; ++ni)
#pragma unroll
                    for (int reg = 0; reg < 4; ++reg) {
                        int row = brow + wr * 128 + mi * 16 + 4 * g + reg;
                        cc[(size_t)row * N + wcol + ni * 16 + c16] = f2bf(acc[mi][ni][reg]);
                    }
        } else {
#pragma unroll
            for (int mi = 0; mi < 8; ++mi)
#pragma unroll
                for (int ni = 0; ni < 4; ++ni)
#pragma unroll
                    for (int reg = 0; reg < 4; ++reg) {
                        int d = wc * 64 - 128 + ni * 16 + c16;
                        int s = wr * 128 + mi * 16 + 4 * g + reg;
                        LT[d * 256 + (s ^ ((d & 15) << 3))] = f2bf(acc[mi][ni][reg]);
                    }
        }
        __syncthreads();
        const int bb = brow >> 11, hh = bcol >> 8, sbase = brow & 2047;
#pragma unroll
        for (int j = 0; j < 8; ++j) {
            int d = j * 16 + (tid >> 5);
            int s0 = (tid & 31) * 8;
            bf16x8 v = *(const bf16x8*)&LT[d * 256 + (s0 ^ ((d & 15) << 3))];
            *(bf16x8*)&VtOut[((size_t)((bb * 16 + hh) * 128 + d)) * 2048 + sbase + s0] = v;
        }
    }
}

// ---------------------------------------------------------------------------
// 128x256 counted-vmcnt GEMM for gemm_out.
// ---------------------------------------------------------------------------
__global__ __launch_bounds__(512) void gemm8n(const short* __restrict__ A,
                                              const short* __restrict__ BT,
                                              float* __restrict__ C,
                                              int N, int K, int nbx) {
    __shared__ short LA[2][2][4096];
    __shared__ short LBt[2][2][8192];

    const int tid = threadIdx.x, lane = tid & 63, w = tid >> 6;
    const int c16 = lane & 15, g = lane >> 4;
    const int wr = w >> 2, wc = w & 3;
    const int qph = (g ^ ((c16 >> 1) & 3)) * 8;

    const int nwg = gridDim.x;
    const int swz = (blockIdx.x & 7) * (nwg >> 3) + (blockIdx.x >> 3);
    const int brow = (swz / nbx) * 128, bcol = (swz % nbx) * 256;

    const int oA = tid * 16;
    const int rA = oA >> 6, lcA = ((oA >> 4) & 3) ^ ((rA >> 1) & 3);
    const short* aS = A + (size_t)(brow + rA) * K + lcA * 8;
    const int dA = oA >> 1;

    const int o0 = w * 1024 + lane * 16, o1 = o0 + 8192;
    const int r0 = o0 >> 6, lc0 = ((o0 >> 4) & 3) ^ ((r0 >> 1) & 3);
    const int r1 = o1 >> 6, lc1 = ((o1 >> 4) & 3) ^ ((r1 >> 1) & 3);
    const short* bS0 = BT + (size_t)(bcol + r0) * K + lc0 * 8;
    const short* bS1 = BT + (size_t)(bcol + r1) * K + lc1 * 8;
    const int d0 = o0 >> 1, d1 = o1 >> 1;

    f32x4 zero = {0.f, 0.f, 0.f, 0.f};
    f32x4 acc[4][4];
#pragma unroll
    for (int i = 0; i < 4; ++i)
#pragma unroll
        for (int j = 0; j < 4; ++j) acc[i][j] = zero;

    const int NT = K >> 6;
    async_ld16(aS,      &LA[0][0][dA]);
    async_ld16(aS + 32, &LA[0][1][dA]);
    async_ld16(bS0,      &LBt[0][0][d0]); async_ld16(bS1,      &LBt[0][0][d1]);
    async_ld16(bS0 + 32, &LBt[0][1][d0]); async_ld16(bS1 + 32, &LBt[0][1][d1]);
    asm volatile("s_waitcnt vmcnt(0)" ::: "memory");
    BARX();

    int cur = 0;
    const int arb = wr * 64, brb = wc * 64;
    for (int kt = 0; kt < NT; ++kt) {
        const bool stg = (kt + 1 < NT);
        const int ko = (kt + 1) * 64;
        bf16x8 af[4], bf[4];

#pragma unroll
        for (int mi = 0; mi < 4; ++mi)
            af[mi] = *(const bf16x8*)&LA[cur][0][(arb + mi * 16 + c16) * 32 + qph];
#pragma unroll
        for (int ni = 0; ni < 4; ++ni)
            bf[ni] = *(const bf16x8*)&LBt[cur][0][(brb + ni * 16 + c16) * 32 + qph];
        if (stg) {
            async_ld16(aS + ko, &LA[cur ^ 1][0][dA]);
            async_ld16(bS0 + ko, &LBt[cur ^ 1][0][d0]);
            async_ld16(bS1 + ko, &LBt[cur ^ 1][0][d1]);
            asm volatile("s_waitcnt vmcnt(3)" ::: "memory");
        } else {
            asm volatile("s_waitcnt vmcnt(0)" ::: "memory");
        }
        BARX();
        __builtin_amdgcn_s_setprio(1);
#pragma unroll
        for (int mi = 0; mi < 4; ++mi)
#pragma unroll
            for (int ni = 0; ni < 4; ++ni)
                acc[mi][ni] = __builtin_amdgcn_mfma_f32_16x16x32_bf16(af[mi], bf[ni], acc[mi][ni], 0, 0, 0);
        __builtin_amdgcn_s_setprio(0);
        BARX();

#pragma unroll
        for (int mi = 0; mi < 4; ++mi)
            af[mi] = *(const bf16x8*)&LA[cur][1][(arb + mi * 16 + c16) * 32 + qph];
#pragma unroll
        for (int ni = 0; ni < 4; ++ni)
            bf[ni] = *(const bf16x8*)&LBt[cur][1][(brb + ni * 16 + c16) * 32 + qph];
        if (stg) {
            async_ld16(aS + ko + 32, &LA[cur ^ 1][1][dA]);
            async_ld16(bS0 + ko + 32, &LBt[cur ^ 1][1][d0]);
            async_ld16(bS1 + ko + 32, &LBt[cur ^ 1][1][d1]);
            asm volatile("s_waitcnt vmcnt(3)" ::: "memory");
        }
        BARX();
        __builtin_amdgcn_s_setprio(1);
#pragma unroll
        for (int mi = 0; mi < 4; ++mi)
#pragma unroll
            for (int ni = 0; ni < 4; ++ni)
                acc[mi][ni] = __builtin_amdgcn_mfma_f32_16x16x32_bf16(af[mi], bf[ni], acc[mi][ni], 0, 0, 0);
        __builtin_amdgcn_s_setprio(0);
        BARX();

        cur ^= 1;
    }

#pragma unroll
    for (int mi = 0; mi < 4; ++mi)
#pragma unroll
        for (int ni = 0; ni < 4; ++ni)
#pragma unroll
            for (int reg = 0; reg < 4; ++reg) {
                int row = brow + wr * 64 + mi * 16 + 4 * g + reg;
                int col = bcol + wc * 64 + ni * 16 + c16;
                C[(size_t)row * N + col] = acc[mi][ni][reg];
            }
}

// ---------------------------------------------------------------------------
// LayerNorm(512) + RoPE(k_pe). ckv stride 640. Outputs bf16.
// ---------------------------------------------------------------------------
__global__ __launch_bounds__(256) void ln_rope(const float* __restrict__ ckv,
                                               const float* __restrict__ gam,
                                               const float* __restrict__ bet,
                                               const float* __restrict__ cosT,
                                               const float* __restrict__ sinT,
                                               const int* __restrict__ pid,
                                               short* __restrict__ kvcn,
                                               short* __restrict__ kpe) {
    const int tok = blockIdx.x, tid = threadIdx.x;
    const float* x = ckv + (size_t)tok * 640;
    float v0 = x[tid], v1 = x[tid + 256];
    float s = v0 + v1, sq = v0 * v0 + v1 * v1;
#pragma unroll
    for (int m = 1; m < 64; m <<= 1) { s += __shfl_xor(s, m); sq += __shfl_xor(sq, m); }
    __shared__ float ws[8];
    int wid = tid >> 6, lane = tid & 63;
    if (lane == 0) { ws[wid] = s; ws[4 + wid] = sq; }
    __syncthreads();
    s = ws[0] + ws[1] + ws[2] + ws[3];
    sq = ws[4] + ws[5] + ws[6] + ws[7];
    float mean = s * (1.f / 512.f);
    float var = sq * (1.f / 512.f) - mean * mean;
    float rstd = rsqrtf(var + EPS_);
    kvcn[(size_t)tok * 512 + tid]       = f2bf((v0 - mean) * rstd * gam[tid] + bet[tid]);
    kvcn[(size_t)tok * 512 + tid + 256] = f2bf((v1 - mean) * rstd * gam[tid + 256] + bet[tid + 256]);
    if (tid < 32) {
        int pos = pid[tok];
        float c = cosT[pos * 32 + tid], sn = sinT[pos * 32 + tid];
        float x1 = x[512 + tid], x2 = x[512 + 32 + tid];
        kpe[(size_t)tok * 64 + tid]      = f2bf(x1 * c - x2 * sn);
        kpe[(size_t)tok * 64 + 32 + tid] = f2bf(x2 * c + x1 * sn);
    }
}

// ---------------------------------------------------------------------------
// MFMA flash attention. SWAPPED QK^T: sc = mfma(K_frag, Q_frag) -> S[kv][q]
// with q = c16 (lane-local row!), kv = 16nb + 4g + reg.
//  - row-max: 15-op local tree + 2 shuffle rounds (was 3 + 4 rounds)
//  - mreg/lreg scalar per lane; alpha/l transposed to PV domain via
//    __shfl(x, 4g+reg) (rescale-path / epilogue only)
//  - P write: P[w][c16][16nb+4g+reg] == P[q][kv], PV reads unchanged
// Everything else identical to R12.
// ---------------------------------------------------------------------------
__global__ __launch_bounds__(256) void flash_mfma(const short* __restrict__ qb,
                                                  const short* __restrict__ kvb,
                                                  const short* __restrict__ kpe,
                                                  const short* __restrict__ Vt,
                                                  short* __restrict__ attno) {
    __shared__ short Ks[2][64 * 128];
    __shared__ short Vs[2][128 * 64];
    __shared__ short P[4][16][72];

    const int flat = blockIdx.x;              // 0..511
    const int xcd = flat & 7, idx = flat >> 3;
    const int bh = xcd + 8 * (idx >> 4);
    const int pair = idx & 15;
    const int b = bh >> 4, h = bh & 15;

    const int tid = threadIdx.x, lane = tid & 63, w = tid >> 6;
    const int c16 = lane & 15, g = lane >> 4, g8 = g * 8;
    const float SC2 = 0.10412063f;   // 1/sqrt(192) * log2(e)

    const int o = w * 1024 + lane * 16;
    const int rK = o >> 8, ccK = ((o >> 4) & 15) ^ (rK & 7);
    const int rV = o >> 7, ccV = ((o >> 4) & 7) ^ (rV & 7);
    const short* kB0  = kvb + ((size_t)((b * 2048 + rK) * 16 + h)) * 256 + ccK * 8;
    const short* vB0  = Vt + ((size_t)((b * 16 + h) * 128 + rV)) * 2048 + ccV * 8;
    const short* peB0 = kpe + (size_t)(b * 2048 + c16) * 64 + g8;

    f32x4 zero = {0.f, 0.f, 0.f, 0.f};

#define STAGE(BUF)                                                                  \
    {                                                                               \
        _Pragma("unroll")                                                           \
        for (int rnd = 0; rnd < 4; ++rnd)                                           \
            async_ld16(kRun + (size_t)rnd * 65536,                                  \
                       &Ks[BUF][(rnd * 4096 + w * 1024) >> 1]);                     \
        _Pragma("unroll")                                                           \
        for (int rnd = 0; rnd < 4; ++rnd)                                           \
            async_ld16(vRun + (size_t)rnd * 65536,                                  \
                       &Vs[BUF][(rnd * 4096 + w * 1024) >> 1]);                     \
        kRun += 64 * 4096;                                                          \
        vRun += 64;                                                                 \
    }

    for (int half = 0; half < 2; ++half) {
        const int qt = half ? (31 - pair) : pair;
        const int q0 = qt * 64;
        const int qrow = q0 + w * 16;

        const size_t qbase = ((size_t)(b * 2048 + qrow + c16) * 16 + h) * 192 + g8;
        bf16x8 qf[6];
#pragma unroll
        for (int ks = 0; ks < 6; ++ks) qf[ks] = *(const bf16x8*)(qb + qbase + 32 * ks);

        f32x4 acc[8];
#pragma unroll
        for (int i = 0; i < 8; ++i) acc[i] = zero;
        float mreg = -INFINITY;   // running max for q-row c16 (lane-local)
        float lreg = 0.f;         // per-lane partial row sum (deferred reduce)

        const short* kRun = kB0;
        const short* vRun = vB0;
        const short* peRun = peB0;

        const int nt = qt + 1;
        STAGE(0);
        __syncthreads();
        int cur = 0;

        for (int kt = 0; kt < nt; ++kt) {
            if (kt + 1 < nt) STAGE(cur ^ 1);

            f32x4 sc[4];
#pragma unroll
            for (int i = 0; i < 4; ++i) sc[i] = zero;

            // QK^T swapped: A = K fragment, B = Q fragment -> S[kv][q=c16]
            __builtin_amdgcn_s_setprio(1);
#pragma unroll
            for (int ks = 0; ks < 4; ++ks)
#pragma unroll
                for (int nb = 0; nb < 4; ++nb) {
                    int row = nb * 16 + c16;
                    bf16x8 kf = *(const bf16x8*)&Ks[cur][row * 128 + (((g + 4 * ks) ^ (row & 7)) << 3)];
                    sc[nb] = __builtin_amdgcn_mfma_f32_16x16x32_bf16(kf, qf[ks], sc[nb], 0, 0, 0);
                }
#pragma unroll
            for (int ks = 0; ks < 2; ++ks)
#pragma unroll
                for (int nb = 0; nb < 4; ++nb) {
                    bf16x8 kf = *(const bf16x8*)(peRun + (size_t)nb * 16 * 64 + ks * 32);
                    sc[nb] = __builtin_amdgcn_mfma_f32_16x16x32_bf16(kf, qf[4 + ks], sc[nb], 0, 0, 0);
                }
            __builtin_amdgcn_s_setprio(0);
            peRun += 64 * 64;

            // causal mask (last tile): kv_rel = 16nb+4g+reg > w*16 + c16
            if (kt == nt - 1) {
#pragma unroll
                for (int nb = 0; nb < 4; ++nb)
#pragma unroll
                    for (int reg = 0; reg < 4; ++reg)
                        if (nb * 16 + 4 * g + reg > w * 16 + c16) sc[nb][reg] = -INFINITY;
            }

            // row max: local tree (16 values) + 2 shuffle rounds (xor16, xor32)
            float m01 = fmaxf(fmaxf(sc[0][0], sc[0][1]), fmaxf(sc[0][2], sc[0][3]));
            float m23 = fmaxf(fmaxf(sc[1][0], sc[1][1]), fmaxf(sc[1][2], sc[1][3]));
            float m45 = fmaxf(fmaxf(sc[2][0], sc[2][1]), fmaxf(sc[2][2], sc[2][3]));
            float m67 = fmaxf(fmaxf(sc[3][0], sc[3][1]), fmaxf(sc[3][2], sc[3][3]));
            float rmax = fmaxf(fmaxf(m01, m23), fmaxf(m45, m67));
            rmax = fmaxf(rmax, __shfl_xor(rmax, 16));
            rmax = fmaxf(rmax, __shfl_xor(rmax, 32));

            // defer-rescale (T13, THR=8 in log2 domain)
            if (__any(rmax * SC2 - mreg > 8.f)) {
                float mnew = fmaxf(mreg, rmax * SC2);
                float alpha = exp2f(mreg - mnew);
                mreg = mnew;
                lreg *= alpha;
                float ar[4];
#pragma unroll
                for (int reg = 0; reg < 4; ++reg) ar[reg] = __shfl(alpha, 4 * g + reg);
#pragma unroll
                for (int nb = 0; nb < 8; ++nb)
#pragma unroll
                    for (int reg = 0; reg < 4; ++reg) acc[nb][reg] *= ar[reg];
            }

            // p = 2^(s*SC2 - m); per-lane partial sum; write P[q=c16][kv]
#pragma unroll
            for (int nb = 0; nb < 4; ++nb) {
                float p0 = exp2f(fmaf(sc[nb][0], SC2, -mreg));
                float p1 = exp2f(fmaf(sc[nb][1], SC2, -mreg));
                float p2 = exp2f(fmaf(sc[nb][2], SC2, -mreg));
                float p3 = exp2f(fmaf(sc[nb][3], SC2, -mreg));
                lreg += (p0 + p1) + (p2 + p3);
                short* pr = &P[w][c16][nb * 16 + 4 * g];
                pr[0] = f2bf(p0); pr[1] = f2bf(p1); pr[2] = f2bf(p2); pr[3] = f2bf(p3);
            }

            // PV from LDS V (unchanged)
            __builtin_amdgcn_s_setprio(1);
#pragma unroll
            for (int ks = 0; ks < 2; ++ks) {
                bf16x8 pf = *(const bf16x8*)&P[w][c16][ks * 32 + g8];
#pragma unroll
                for (int nb = 0; nb < 8; ++nb) {
                    int row = nb * 16 + c16;
                    bf16x8 vf = *(const bf16x8*)&Vs[cur][row * 64 + (((g + 4 * ks) ^ (row & 7)) << 3)];
                    acc[nb] = __builtin_amdgcn_mfma_f32_16x16x32_bf16(pf, vf, acc[nb], 0, 0, 0);
                }
            }
            __builtin_amdgcn_s_setprio(0);

            __syncthreads();
            cur ^= 1;
        }

        // epilogue: finish deferred row-sum (2 rounds), transpose to PV domain
        lreg += __shfl_xor(lreg, 16);
        lreg += __shfl_xor(lreg, 32);
        float linv[4];
#pragma unroll
        for (int reg = 0; reg < 4; ++reg) linv[reg] = 1.f / __shfl(lreg, 4 * g + reg);
#pragma unroll
        for (int nb = 0; nb < 8; ++nb)
#pragma unroll
            for (int reg = 0; reg < 4; ++reg)
                attno[((size_t)(b * 2048 + qrow + 4 * g + reg) * 16 + h) * 128 + nb * 16 + c16] =
                    f2bf(acc[nb][reg] * linv[reg]);
    }
#undef STAGE
}

// ---------------------------------------------------------------------------
extern "C" void kernel_launch(void* const* d_in, const int* in_sizes, int n_in,
                              void* d_out, int out_size, void* d_ws, size_t ws_size,
                              hipStream_t stream) {
    const float* hidden = (const float*)d_in[0];
    const float* cosT   = (const float*)d_in[1];
    const float* sinT   = (const float*)d_in[2];
    const int*   pid    = (const int*)d_in[3];
    const float* Wq     = (const float*)d_in[4];
    const float* Wkv_a  = (const float*)d_in[5];
    const float* ln_g   = (const float*)d_in[6];
    const float* ln_b   = (const float*)d_in[7];
    const float* Wkv_b  = (const float*)d_in[8];
    const float* Wo     = (const float*)d_in[9];
    float* out = (float*)d_out;

    char* p = (char*)d_ws;
    short* hid_bf = (short*)p;               p += (size_t)NTOK * 2048 * 2;
    short* WqkaT  = (short*)p;               p += (size_t)3840 * 2048 * 2;
    short* WkbT   = (short*)p;               p += (size_t)4096 * 512 * 2;
    short* WoT    = (short*)p;               p += (size_t)2048 * 2048 * 2;
    char*  big    = p;                       p += (size_t)NTOK * 3072 * 4;
    short* qbuf   = (short*)p;               p += (size_t)NTOK * 3072 * 2;
    short* kvcn   = (short*)p;               p += (size_t)NTOK * 512 * 2;
    short* kpe    = (short*)p;               p += (size_t)NTOK * 64 * 2;
    short* kvb    = (short*)p;               p += (size_t)NTOK * 4096 * 2;

    float* ckv   = (float*)big;
    short* Vt    = (short*)(big + (size_t)NTOK * 640 * 4);
    short* attno = (short*)(big + (size_t)NTOK * 640 * 4 + (size_t)2 * 16 * 128 * 2048 * 2);

    prep<<<22016, 256, 0, stream>>>(hidden, hid_bf, Wq, Wkv_a, Wkv_b, Wo, WqkaT, WkbT, WoT);
    gemm8<1><<<240, 512, 0, stream>>>(hid_bf, WqkaT, qbuf, ckv, nullptr,
                                      cosT, sinT, pid, 3840, 2048, 15);
    ln_rope<<<NTOK, 256, 0, stream>>>(ckv, ln_g, ln_b, cosT, sinT, pid, kvcn, kpe);
    gemm8<0><<<256, 512, 0, stream>>>(kvcn, WkbT, kvb, nullptr, Vt,
                                      nullptr, nullptr, nullptr, 4096, 512, 16);
    flash_mfma<<<512, 256, 0, stream>>>(qbuf, kvb, kpe, Vt, attno);
    gemm8n<<<256, 512, 0, stream>>>(attno, WoT, out, 2048, 2048, 8);
}